// Round 4
// baseline (2457.472 us; speedup 1.0000x reference)
//
#include <hip/hip_runtime.h>

typedef unsigned short ushort_t;
typedef unsigned int   uint_t;
typedef __attribute__((ext_vector_type(8))) short short8;
typedef __attribute__((ext_vector_type(4))) float floatx4;

#define NEGV -1000000000.0f

__device__ __forceinline__ float bf2f(ushort_t h){ return __uint_as_float(((uint_t)h)<<16); }
__device__ __forceinline__ ushort_t f2bf(float f){
  uint_t u = __float_as_uint(f);
  uint_t r = u + 0x7fffu + ((u>>16)&1u);
  return (ushort_t)(r>>16);
}
__device__ __forceinline__ float wredsum(float v){ for(int o=32;o;o>>=1) v += __shfl_xor(v,o); return v; }
__device__ __forceinline__ float wredmax(float v){ for(int o=32;o;o>>=1) v = fmaxf(v,__shfl_xor(v,o)); return v; }
__device__ __forceinline__ int   wredsumi(int v){ for(int o=32;o;o>>=1) v += __shfl_xor(v,o); return v; }

// coherent (cross-XCD) 16B load: bypasses L1/L2 via sc0 sc1 -> reads L3/IF.
template<int OFF>
__device__ __forceinline__ short8 ldg_b128_cohr(const ushort_t* p){
  short8 r;
  asm volatile("global_load_dwordx4 %0, %1, off offset:%2 sc0 sc1"
               : "=&v"(r) : "v"(p), "n"(OFF) : "memory");
  return r;
}
#define LD10C(dst, p) \
  dst[0]=ldg_b128_cohr<0>(p);   dst[1]=ldg_b128_cohr<64>(p);  \
  dst[2]=ldg_b128_cohr<128>(p); dst[3]=ldg_b128_cohr<192>(p); \
  dst[4]=ldg_b128_cohr<256>(p); dst[5]=ldg_b128_cohr<320>(p); \
  dst[6]=ldg_b128_cohr<384>(p); dst[7]=ldg_b128_cohr<448>(p); \
  dst[8]=ldg_b128_cohr<512>(p); dst[9]=ldg_b128_cohr<576>(p);

// coherent 2B store: write-through past the XCD L2 (sc0 sc1).
__device__ __forceinline__ void stg_b16_cohr(ushort_t* p, ushort_t v){
  uint_t u = v;
  asm volatile("global_store_short %0, %1, off sc0 sc1" :: "v"(p), "v"(u) : "memory");
}

// ---------------------------------------------------------------------------
// dtype-adaptive conversion, vectorized x8. Probe once per block in wave 0.
// ---------------------------------------------------------------------------
__global__ void k_cvt8(const void* __restrict__ src, ushort_t* __restrict__ dst,
                       long n, const ushort_t* __restrict__ probe_src){
  __shared__ int sflag;
  if (threadIdx.x < 64){
    ushort_t u = probe_src[2*threadIdx.x];
    int e = (u>>7)&0xFF;
    int c = (e>=100 && e<=140) ? 1 : 0;
    c = wredsumi(c);
    if (threadIdx.x==0) sflag = (c>32) ? 1 : 0;
  }
  __syncthreads();
  bool isbf = (sflag!=0);
  long base = (blockIdx.x*256L + threadIdx.x)*8;
  if (base>=n) return;
  if (isbf){
    if (base+8<=n) *(uint4*)(dst+base) = *(const uint4*)((const ushort_t*)src+base);
    else for (long i=base;i<n;i++) dst[i]=((const ushort_t*)src)[i];
  } else {
    const float* s = (const float*)src;
    if (base+8<=n){
      float4 v0 = *(const float4*)(s+base);
      float4 v1 = *(const float4*)(s+base+4);
      ushort_t o[8] = {f2bf(v0.x),f2bf(v0.y),f2bf(v0.z),f2bf(v0.w),
                       f2bf(v1.x),f2bf(v1.y),f2bf(v1.z),f2bf(v1.w)};
      *(uint4*)(dst+base) = *(uint4*)o;
    } else {
      for (long i=base;i<n;i++) dst[i]=f2bf(s[i]);
    }
  }
}

__device__ __forceinline__ bool probe_is_bf16(const ushort_t* probe_src){
  int c=0;
  #pragma unroll 1
  for (int i=0;i<64;i++){
    ushort_t u = probe_src[2*i];
    int e = (u>>7)&0xFF;
    c += (e>=100 && e<=140) ? 1 : 0;
  }
  return c>32;
}

// ---------------------------------------------------------------------------
// small prep kernels
// ---------------------------------------------------------------------------
__global__ void k_lens(const int* __restrict__ ti, const int* __restrict__ li,
                       int* __restrict__ nonpad, int* __restrict__ text_len,
                       int* __restrict__ left_len){
  int b = blockIdx.x, t = threadIdx.x;
  nonpad[b*128+t] = (ti[b*128+t]!=0) ? 1 : 0;
  if (t==0){
    int c=0; for (int k2=0;k2<128;k2++) c += (ti[b*128+k2]!=0);
    text_len[b]=c;
    int l=0; for (int k2=0;k2<24;k2++) l += (li[b*24+k2]!=0);
    left_len[b]=l;
  }
}

__global__ void k_aspmean(const int* __restrict__ ai, const ushort_t* __restrict__ em,
                          float* __restrict__ asp_mean){
  int b = blockIdx.x;
  int idxs[5]; int cnt=0;
  for (int a=0;a<5;a++){ int ix=ai[b*5+a]; idxs[a]=ix; cnt += (ix!=0); }
  float inv = 1.0f/(float)cnt;
  for (int d=threadIdx.x; d<300; d+=128){
    float s=0.f;
    for (int a=0;a<5;a++) if (idxs[a]) s += bf2f(em[(long)idxs[a]*300+d]);
    asp_mean[b*300+d] = s*inv;
  }
}

__global__ void k_embs(const int* __restrict__ ti, const int* __restrict__ pi,
                       const int* __restrict__ asp_post,
                       const ushort_t* __restrict__ em, const ushort_t* __restrict__ pe,
                       const float* __restrict__ asp_mean, ushort_t* __restrict__ embs){
  int blk = blockIdx.x;
  int b = blk>>7, t = blk&127;
  int ap = asp_post[b];
  int tix = ti[b*128+t];
  int pix = pi[b*128+t];
  for (int col=threadIdx.x; col<336; col+=128){
    ushort_t v;
    if (col<300) v = (t==ap) ? f2bf(asp_mean[b*300+col]) : em[(long)tix*300+col];
    else if (col<330) v = pe[pix*30 + (col-300)];
    else v = 0;
    embs[(long)(b*128+t)*336 + col] = v;
  }
}

// Wih repack for gate-packed gi: dst[1280][336], row' = j*4+gate
// (j padded 300->320, K 330->336). src row = gate*300+j, 330 cols.
__global__ void k_padwih2(const ushort_t* __restrict__ src, ushort_t* __restrict__ dst){
  int i = blockIdx.x*blockDim.x + threadIdx.x;
  if (i >= 1280*336) return;
  int r = i/336, k = i - r*336;
  int j = r>>2, gate = r&3;
  ushort_t v = 0;
  if (j<300 && k<330) v = src[(long)(gate*300+j)*330 + k];
  dst[i] = v;
}

// Whh repack for reg-resident LSTM: dst[1280][320] bf16, row' = j*4 + gate
// (j padded 300->320, K 300->320, zeros elsewhere). src row = gate*300 + j.
__global__ void k_padwhh2(const ushort_t* __restrict__ src, ushort_t* __restrict__ dst){
  int i = blockIdx.x*blockDim.x + threadIdx.x;
  if (i >= 1280*320) return;
  int r = i/320, k = i - r*320;
  int j = r>>2, gate = r&3;
  ushort_t v = 0;
  if (j<300 && k<300) v = src[(long)(gate*300+j)*300 + k];
  dst[i] = v;
}

// gate-packed bias: dst[j*4+gate] = bih[gate*300+j] + bhh[gate*300+j]
__global__ void k_biassum2(const ushort_t* __restrict__ a, const ushort_t* __restrict__ b,
                           float* __restrict__ dst){
  int i = blockIdx.x*blockDim.x + threadIdx.x;
  if (i>=1280) return;
  int j = i>>2, g = i&3;
  dst[i] = (j<300) ? (bf2f(a[g*300+j]) + bf2f(b[g*300+j])) : 0.f;
}

__global__ void k_biascvt(const ushort_t* __restrict__ a, float* __restrict__ dst, int n){
  int i = blockIdx.x*blockDim.x + threadIdx.x;
  if (i<n) dst[i] = bf2f(a[i]);
}

// ---------------------------------------------------------------------------
// generic bf16 MFMA GEMM: 128x128 tile, 4 waves (2x2), each 64x64 via 4x4
// frags of 16x16x32.  TB=1: C = A * B^T.  TB=0: C = A * B.
// MODE 1: bf16 store (opt bias/relu/rowscale)
// MODE 2: qk head-scatter bf16 store (bias), T=128, dk=100->104
// MODE 3: f32 store, *0.1 and nonpad column mask (attention scores)
// ---------------------------------------------------------------------------
template<int TB, int MODE>
__global__ __launch_bounds__(256) void gemm_k(
    int M, int N, int K,
    const ushort_t* __restrict__ A, long lda, long sAz,
    const ushort_t* __restrict__ B, long ldb, long sBz,
    float* __restrict__ Cf, ushort_t* __restrict__ Cb, long ldc, long sCz,
    const float* __restrict__ bias, int relu,
    const float* __restrict__ rowscale,
    const int* __restrict__ nonpad)
{
  __shared__ ushort_t As[128*40];
  __shared__ ushort_t Bs[128*40];
  const int tid = threadIdx.x;
  const int m0 = blockIdx.x*128, n0 = blockIdx.y*128;
  const int z = blockIdx.z;
  const ushort_t* Ap = A + (long)z*sAz;
  const ushort_t* Bp = B + (long)z*sBz;
  floatx4 acc[4][4];
  #pragma unroll
  for (int i=0;i<4;i++)
    #pragma unroll
    for (int j=0;j<4;j++){ acc[i][j][0]=0.f; acc[i][j][1]=0.f; acc[i][j][2]=0.f; acc[i][j][3]=0.f; }
  const int w = tid>>6, wm = w&1, wn = w>>1;
  const int lane = tid&63, lr = lane&15, lq = lane>>4;

  for (int k0=0;k0<K;k0+=32){
    #pragma unroll
    for (int c2=0;c2<2;c2++){
      int ch = tid + 256*c2;
      int row = ch>>2, kc = (ch&3)*8;
      int gr = m0+row, gk = k0+kc;
      uint4 v{};
      if (gr<M && gk<K) v = *(const uint4*)(Ap + (long)gr*lda + gk);
      *(uint4*)(&As[row*40+kc]) = v;
    }
    if (TB){
      #pragma unroll
      for (int c2=0;c2<2;c2++){
        int ch = tid + 256*c2;
        int row = ch>>2, kc = (ch&3)*8;
        int gn = n0+row, gk = k0+kc;
        uint4 v{};
        if (gn<N && gk<K) v = *(const uint4*)(Bp + (long)gn*ldb + gk);
        int sw = kc ^ (((row>>3)&3)<<3);
        *(uint4*)(&Bs[row*40+sw]) = v;
      }
    } else {
      #pragma unroll
      for (int c2=0;c2<2;c2++){
        int ch = tid + 256*c2;
        int kk = ch>>4, nc = (ch&15)*8;
        int gk = k0+kk, gn = n0+nc;
        uint4 v{};
        if (gk<K && gn<N) v = *(const uint4*)(Bp + (long)gk*ldb + gn);
        uint_t wsv[4] = {v.x, v.y, v.z, v.w};
        #pragma unroll
        for (int e=0;e<8;e++){
          ushort_t hv = (e&1) ? (ushort_t)(wsv[e>>1]>>16) : (ushort_t)(wsv[e>>1]&0xffffu);
          int n = nc+e;
          int sw = kk ^ (((n>>3)&3)<<3);
          Bs[n*40+sw] = hv;
        }
      }
    }
    __syncthreads();
    short8 af[4], bfv[4];
    #pragma unroll
    for (int i=0;i<4;i++) af[i] = *(const short8*)(&As[(wm*64+i*16+lr)*40 + lq*8]);
    #pragma unroll
    for (int j=0;j<4;j++){
      int n = wn*64+j*16+lr;
      int sw = (lq*8) ^ (((n>>3)&3)<<3);
      bfv[j] = *(const short8*)(&Bs[n*40+sw]);
    }
    #pragma unroll
    for (int i=0;i<4;i++)
      #pragma unroll
      for (int j=0;j<4;j++)
        acc[i][j] = __builtin_amdgcn_mfma_f32_16x16x32_bf16(af[i], bfv[j], acc[i][j], 0,0,0);
    __syncthreads();
  }

  #pragma unroll
  for (int i=0;i<4;i++){
    #pragma unroll
    for (int j=0;j<4;j++){
      #pragma unroll
      for (int r=0;r<4;r++){
        int row = m0 + wm*64 + i*16 + lq*4 + r;
        int col = n0 + wn*64 + j*16 + lr;
        if (row<M && col<N){
          float v = acc[i][j][r];
          if (rowscale) v *= rowscale[(long)z*M + row];
          if (bias) v += bias[col];
          if (relu && v<0.f) v = 0.f;
          if (MODE==1){
            Cb[(long)z*sCz + (long)row*ldc + col] = f2bf(v);
          } else if (MODE==2){
            int b = row>>7, t = row&127;
            int h = col/100, d = col - h*100;
            Cb[ ((long)((b*6+h)*128+t))*104 + d ] = f2bf(v);
          } else if (MODE==3){
            v *= 0.1f;
            if (!nonpad[(z/6)*128 + col]) v = NEGV;
            Cf[(long)z*sCz + (long)row*ldc + col] = v;
          }
        }
      }
    }
  }
}

// ---------------------------------------------------------------------------
// Register-resident BiLSTM, fence-free cross-XCD h exchange.
// Grid: 40 blocks = 2 dirs x 10 j-slices(32 hidden) x 2 batch-halves(64).
// Block: 512 threads = 8 waves, wave grid 4M x 2N.
// KEY (round-4 fix): the A (Whh) fragments are PINNED with empty
// asm volatile("" : "+v") after the one-time load. Rounds 1-3 the compiler
// rematerialized these loop-invariant plain loads EVERY step (VGPR_Count
// 148/180/104 vs ~200 required -> ~20 global_load_dwordx4 per wave per step
// chained into the MFMAs = the 15-20k cycle/step parasite). A volatile-asm
// result cannot be re-executed, so the allocator must keep it live.
// Peak live ~200 < 256 cap (launch_bounds 512,2) -> no scratch.
// Cell update lane-local (A rows packed j*4+gate); c,h persist in registers.
// h ping-pongs through global sc0|sc1 accesses; per-step 10-block barrier
// via agent-scope atomic; no __threadfence (no L2 wb/inv).
// ---------------------------------------------------------------------------
__global__ __launch_bounds__(512,2) void lstm2_k(
    const ushort_t* __restrict__ whh2f, const ushort_t* __restrict__ whh2b,
    const ushort_t* __restrict__ gipf, const ushort_t* __restrict__ gipb,
    ushort_t* __restrict__ hbuf,          // [2 dir][2 buf][128 b][320] bf16
    int* __restrict__ barr,               // [4 grp][128 step]
    ushort_t* __restrict__ text_out, const int* __restrict__ text_len)
{
  const int bx = blockIdx.x;
  const int slice = bx % 10;
  const int grp   = bx / 10;              // 0..3 = (bh<<1)|dir
  const int dir = grp & 1, bh = grp >> 1;
  const ushort_t* __restrict__ whh = dir ? whh2b : whh2f;
  const ushort_t* __restrict__ gip = dir ? gipb : gipf;
  ushort_t* hb = hbuf + (long)dir * (2L*128*320);
  int* bar = barr + grp*128;

  const int tid = threadIdx.x;
  const int w = tid>>6, lane = tid&63, lr = lane&15, lq = lane>>4;
  const int wm = w&3, wn = w>>2;          // wave grid: 4 Mgroups x 2 Ngroups

  // ---- Whh slice -> registers (once): 2 Mtiles x 10 kfrags = 80 VGPRs ----
  short8 a[2][10];
  #pragma unroll
  for (int mi=0;mi<2;mi++){
    const ushort_t* ar = whh + (long)(slice*128 + (wm*2+mi)*16 + lr)*320 + lq*8;
    #pragma unroll
    for (int kf=0;kf<10;kf++) a[mi][kf] = *(const short8*)(ar + kf*32);
  }
  // pin: forbid rematerialization of the A fragments (see header comment)
  #pragma unroll
  for (int mi=0;mi<2;mi++)
    #pragma unroll
    for (int kf=0;kf<10;kf++)
      asm volatile("" : "+v"(a[mi][kf]));

  // ---- lane-owned (jj, b) pairs ----
  int jj_[2], b_[2], tl_[2];
  #pragma unroll
  for (int mi=0;mi<2;mi++) jj_[mi] = slice*32 + wm*8 + mi*4 + lq;
  #pragma unroll
  for (int ni=0;ni<2;ni++){ b_[ni] = bh*64 + wn*32 + ni*16 + lr; tl_[ni] = text_len[b_[ni]]; }

  float    c_st[2][2];
  ushort_t h_st[2][2];
  #pragma unroll
  for (int mi=0;mi<2;mi++){ c_st[mi][0]=0.f; c_st[mi][1]=0.f; h_st[mi][0]=0; h_st[mi][1]=0; }

  for (int s=0; s<128; s++){
    const int t = dir ? (127-s) : s;
    const ushort_t* rb = hb + (long)(s&1)*(128L*320);
    ushort_t*       wb = hb + (long)((s+1)&1)*(128L*320);

    // gi loads (plain; read-once stream); 8B per (jj,b)
    uint2 gp[2][2];
    #pragma unroll
    for (int mi=0;mi<2;mi++)
      #pragma unroll
      for (int ni=0;ni<2;ni++)
        gp[mi][ni] = *(const uint2*)(gip + ((long)(b_[ni]*128 + t))*1280 + jj_[mi]*4);

    // h B-fragments: coherent loads (bypass stale L1/L2, read L3)
    short8 bfr[2][10];
    {
      const ushort_t* pa0 = rb + (long)b_[0]*320 + lq*8;
      const ushort_t* pa1 = rb + (long)b_[1]*320 + lq*8;
      LD10C(bfr[0], pa0);
      LD10C(bfr[1], pa1);
    }
    asm volatile("s_waitcnt vmcnt(0)" ::: "memory");
    __builtin_amdgcn_sched_barrier(0);

    floatx4 acc[2][2];
    #pragma unroll
    for (int mi=0;mi<2;mi++)
      #pragma unroll
      for (int ni=0;ni<2;ni++){ acc[mi][ni][0]=0.f; acc[mi][ni][1]=0.f; acc[mi][ni][2]=0.f; acc[mi][ni][3]=0.f; }

    #pragma unroll
    for (int kf=0;kf<10;kf++)
      #pragma unroll
      for (int mi=0;mi<2;mi++)
        #pragma unroll
        for (int ni=0;ni<2;ni++)
          acc[mi][ni] = __builtin_amdgcn_mfma_f32_16x16x32_bf16(a[mi][kf], bfr[ni][kf], acc[mi][ni], 0,0,0);

    // lane-local cell update
    #pragma unroll
    for (int mi=0;mi<2;mi++){
      #pragma unroll
      for (int ni=0;ni<2;ni++){
        float g_i = acc[mi][ni][0] + bf2f((ushort_t)(gp[mi][ni].x & 0xffffu));
        float g_f = acc[mi][ni][1] + bf2f((ushort_t)(gp[mi][ni].x >> 16));
        float g_g = acc[mi][ni][2] + bf2f((ushort_t)(gp[mi][ni].y & 0xffffu));
        float g_o = acc[mi][ni][3] + bf2f((ushort_t)(gp[mi][ni].y >> 16));
        float ig = 1.f/(1.f+expf(-g_i));
        float fg = 1.f/(1.f+expf(-g_f));
        float gg = tanhf(g_g);
        float og = 1.f/(1.f+expf(-g_o));
        float cn = fg*c_st[mi][ni] + ig*gg;
        float hn = og*tanhf(cn);
        bool m = (t < tl_[ni]);
        if (m) c_st[mi][ni] = cn;
        ushort_t hv = m ? f2bf(hn) : h_st[mi][ni];
        h_st[mi][ni] = hv;
        if (jj_[mi] < 300){
          stg_b16_cohr(wb + (long)b_[ni]*320 + jj_[mi], hv);
          text_out[((long)(b_[ni]*128 + t))*600 + dir*300 + jj_[mi]] = m ? f2bf(hn) : (ushort_t)0;
        }
      }
    }

    // drain stores (sc1 -> visible at coherent point once vmcnt==0)
    asm volatile("s_waitcnt vmcnt(0)" ::: "memory");
    __syncthreads();
    if (tid==0){
      __hip_atomic_fetch_add(&bar[s], 1, __ATOMIC_RELAXED, __HIP_MEMORY_SCOPE_AGENT);
      while (__hip_atomic_load(&bar[s], __ATOMIC_RELAXED, __HIP_MEMORY_SCOPE_AGENT) < 10)
        __builtin_amdgcn_s_sleep(1);
    }
    __syncthreads();
  }
}

// ---------------------------------------------------------------------------
// entmax15 over rows of 128 (in-place on f32 scores). 1 wave per row.
// ---------------------------------------------------------------------------
__global__ __launch_bounds__(64) void k_entmax(float* __restrict__ p){
  long row = blockIdx.x;
  float* base = p + row*128;
  __shared__ float xo[128], xs[128], c1[128], c2[128];
  int t = threadIdx.x;
  float a = base[t]*0.5f, b = base[t+64]*0.5f;
  float m = wredmax(fmaxf(a,b));
  a -= m; b -= m;
  xo[t]=a; xo[t+64]=b; xs[t]=a; xs[t+64]=b;
  __syncthreads();
  for (int k2=2;k2<=128;k2<<=1){
    for (int j=k2>>1;j>0;j>>=1){
      int i = ((t & ~(j-1))<<1) | (t & (j-1));
      int ixj = i | j;
      float vi = xs[i], vj = xs[ixj];
      bool blk = (i & k2)==0;
      bool sw = blk ? (vi < vj) : (vi > vj);
      __syncthreads();
      if (sw){ xs[i]=vj; xs[ixj]=vi; }
      __syncthreads();
    }
  }
  c1[t]=xs[t];       c2[t]=xs[t]*xs[t];
  c1[t+64]=xs[t+64]; c2[t+64]=xs[t+64]*xs[t+64];
  __syncthreads();
  for (int d=1; d<128; d<<=1){
    float a1 = (t>=d)     ? c1[t-d]    : 0.f;
    float a2 = (t>=d)     ? c2[t-d]    : 0.f;
    float b1 = (t+64>=d)  ? c1[t+64-d] : 0.f;
    float b2 = (t+64>=d)  ? c2[t+64-d] : 0.f;
    float x1=c1[t], y1=c2[t], x2=c1[t+64], y2=c2[t+64];
    __syncthreads();
    c1[t]=x1+a1; c2[t]=y1+a2; c1[t+64]=x2+b1; c2[t+64]=y2+b2;
    __syncthreads();
  }
  float tau_a, tau_b; int cnt=0;
  {
    float rho = (float)(t+1);
    float mean = c1[t]/rho, msq = c2[t]/rho;
    float ss = rho*(msq-mean*mean);
    float delta = (1.f-ss)/rho;
    tau_a = mean - sqrtf(fmaxf(delta,0.f));
    cnt += (tau_a <= xs[t]) ? 1 : 0;
  }
  {
    float rho = (float)(t+65);
    float mean = c1[t+64]/rho, msq = c2[t+64]/rho;
    float ss = rho*(msq-mean*mean);
    float delta = (1.f-ss)/rho;
    tau_b = mean - sqrtf(fmaxf(delta,0.f));
    cnt += (tau_b <= xs[t+64]) ? 1 : 0;
  }
  __syncthreads();
  c1[t]=tau_a; c1[t+64]=tau_b;
  __syncthreads();
  int support = wredsumi(cnt);
  support = (support<1) ? 1 : ((support>128) ? 128 : support);
  float tau_star = c1[support-1];
  float oa = fmaxf(xo[t]-tau_star, 0.f);
  float ob = fmaxf(xo[t+64]-tau_star, 0.f);
  base[t] = oa*oa; base[t+64] = ob*ob;
}

// ---------------------------------------------------------------------------
__global__ void k_adjsem(const float* __restrict__ p, const int* __restrict__ nonpad,
                         ushort_t* __restrict__ adj_sem){
  int idx = blockIdx.x*blockDim.x + threadIdx.x;
  if (idx >= 128*128*128) return;
  int b = idx>>14, rem = idx&16383, i = rem>>7, j = rem&127;
  float s = 0.f;
  for (int h=0;h<6;h++) s += p[(long)b*98304 + h*16384 + i*128 + j];
  float v = s/6.0f;
  if (i==j) v = 1.0f;
  if (!nonpad[b*128+i]) v = 0.f;
  adj_sem[idx] = f2bf(v);
}

__global__ __launch_bounds__(64) void k_dn(const ushort_t* __restrict__ src, float* __restrict__ dnv){
  long row = blockIdx.x;
  int l = threadIdx.x;
  float s = bf2f(src[row*128+l]) + bf2f(src[row*128+l+64]);
  s = wredsum(s);
  if (l==0) dnv[row] = 1.0f/sqrtf(s+1.0f);
}

__global__ __launch_bounds__(64) void k_mean(const ushort_t* __restrict__ X, float* __restrict__ ymean){
  long row = blockIdx.x;
  float s=0.f;
  for (int d=threadIdx.x; d<600; d+=64) s += bf2f(X[row*600+d]);
  s = wredsum(s);
  if (threadIdx.x==0) ymean[row] = s/600.0f;
}

__global__ void k_senet(const float* __restrict__ ymean,
                        const ushort_t* __restrict__ w1, const ushort_t* __restrict__ b1,
                        const ushort_t* __restrict__ w2, const ushort_t* __restrict__ b2,
                        const int* __restrict__ nonpad, float* __restrict__ ysoft){
  int b = blockIdx.x, t = threadIdx.x;
  __shared__ float yv[128], z1[12], red[128];
  yv[t] = ymean[b*128+t];
  __syncthreads();
  if (t<12){
    float s = bf2f(b1[t]);
    for (int k2=0;k2<128;k2++) s += yv[k2]*bf2f(w1[t*128+k2]);
    z1[t] = fmaxf(s,0.f);
  }
  __syncthreads();
  float v = bf2f(b2[t]);
  for (int r=0;r<12;r++) v += z1[r]*bf2f(w2[t*12+r]);
  if (!nonpad[b*128+t]) v += NEGV;
  red[t]=v; __syncthreads();
  for (int s2=64;s2>0;s2>>=1){ if (t<s2) red[t]=fmaxf(red[t],red[t+s2]); __syncthreads(); }
  float mx = red[0]; __syncthreads();
  float e = expf(v-mx);
  red[t]=e; __syncthreads();
  for (int s2=64;s2>0;s2>>=1){ if (t<s2) red[t]+=red[t+s2]; __syncthreads(); }
  float sm = red[0];
  ysoft[b*128+t] = e/sm;
}

__global__ void k_scale2(const ushort_t* __restrict__ X, const float* __restrict__ ysoft,
                         const float* __restrict__ dnv, ushort_t* __restrict__ out){
  int i = blockIdx.x*blockDim.x + threadIdx.x;
  if (i >= 128*128*600) return;
  int row = i/600;
  out[i] = f2bf(bf2f(X[i])*ysoft[row]*dnv[row]);
}

__global__ void k_gather(const ushort_t* __restrict__ X, const int* __restrict__ left_len,
                         ushort_t* __restrict__ dst){
  int b = blockIdx.x;
  int lb = left_len[b];
  for (int d=threadIdx.x; d<600; d+=128)
    dst[b*600+d] = X[(long)(b*128+lb)*600+d];
}

__global__ __launch_bounds__(256) void k_pool(const ushort_t* __restrict__ g,
                                              const ushort_t* __restrict__ X,
                                              float* __restrict__ pooled, int poff){
  int b = blockIdx.x, tid = threadIdx.x;
  __shared__ float gs[600], sbuf[128], red[256];
  for (int d=tid; d<600; d+=256) gs[d] = bf2f(g[b*600+d]);
  __syncthreads();
  int wv = tid>>6, lane = tid&63;
  for (int jj=wv; jj<128; jj+=4){
    float s=0.f;
    for (int d=lane; d<600; d+=64) s += gs[d]*bf2f(X[(long)(b*128+jj)*600+d]);
    s = wredsum(s);
    if (lane==0) sbuf[jj]=s;
  }
  __syncthreads();
  float v = (tid<128) ? sbuf[tid] : -3.4e38f;
  red[tid]=v; __syncthreads();
  for (int s2=128;s2>0;s2>>=1){ if (tid<s2) red[tid]=fmaxf(red[tid],red[tid+s2]); __syncthreads(); }
  float mx = red[0]; __syncthreads();
  float e = (tid<128) ? expf(v-mx) : 0.f;
  red[tid]=e; __syncthreads();
  for (int s2=128;s2>0;s2>>=1){ if (tid<s2) red[tid]+=red[tid+s2]; __syncthreads(); }
  float sm = red[0]; __syncthreads();
  if (tid<128) sbuf[tid] = e/sm;
  __syncthreads();
  for (int d=tid; d<600; d+=256){
    float acc=0.f;
    for (int j=0;j<128;j++) acc += sbuf[j]*bf2f(X[(long)(b*128+j)*600+d]);
    pooled[(long)b*1200 + poff + d] = acc;
  }
}

__global__ __launch_bounds__(64) void k_final(const float* __restrict__ pooled,
                                              const ushort_t* __restrict__ fcw,
                                              const ushort_t* __restrict__ fcb,
                                              void* __restrict__ out,
                                              const ushort_t* __restrict__ probe_src){
  bool isbf = probe_is_bf16(probe_src);
  int b = blockIdx.x, lane = threadIdx.x;
  for (int p=0;p<3;p++){
    float s=0.f;
    for (int d=lane; d<1200; d+=64) s += pooled[(long)b*1200+d]*bf2f(fcw[d*3+p]);
    s = wredsum(s);
    if (lane==0){
      float r = s + bf2f(fcb[p]);
      if (isbf) ((ushort_t*)out)[b*3+p] = f2bf(r);
      else      ((float*)out)[b*3+p] = r;
    }
  }
}

// ---------------------------------------------------------------------------
extern "C" void kernel_launch(void* const* d_in, const int* in_sizes, int n_in,
                              void* d_out, int out_size, void* d_ws, size_t ws_size,
                              hipStream_t stream) {
  const int*      ti   = (const int*)d_in[0];
  const int*      ai   = (const int*)d_in[1];
  const int*      li   = (const int*)d_in[2];
  const int*      pi   = (const int*)d_in[3];
  const int*      aps  = (const int*)d_in[4];
  const ushort_t* probe = (const ushort_t*)d_in[7];

  char* w = (char*)d_ws; size_t off = 0;
  auto alloc = [&](size_t bytes)->char*{ char* p = w+off; off = (off+bytes+255)&~(size_t)255; return p; };

  int*   text_len = (int*)alloc(512);
  int*   left_len = (int*)alloc(512);
  int*   nonpad   = (int*)alloc(65536);
  float* asp_mean = (float*)alloc(153600);
  float* dn1      = (float*)alloc(65536);
  float* dn2      = (float*)alloc(65536);
  float* ymean    = (float*)alloc(65536);
  float* ysoft    = (float*)alloc(65536);
  ushort_t* wihpf = (ushort_t*)alloc(860160);   // [1280][336] row=j*4+gate
  ushort_t* wihpb = (ushort_t*)alloc(860160);
  ushort_t* whh2f = (ushort_t*)alloc(819200);   // [1280][320] row=j*4+gate
  ushort_t* whh2b = (ushort_t*)alloc(819200);
  ushort_t* hbuf  = (ushort_t*)alloc(327680);   // [2 dir][2 buf][128][320]
  int*      barr  = (int*)alloc(2048);          // [4][128]
  float* biasgf   = (float*)alloc(5120);        // [1280] gate-packed
  float* biasgb   = (float*)alloc(5120);
  float* bqf      = (float*)alloc(2400);
  float* bkf      = (float*)alloc(2400);
  float* gc1bf    = (float*)alloc(2400);
  float* gc2bf    = (float*)alloc(2400);
  ushort_t* g1    = (ushort_t*)alloc(153600);
  ushort_t* g2    = (ushort_t*)alloc(153600);
  ushort_t* xr    = (ushort_t*)alloc(153600);
  ushort_t* xsr   = (ushort_t*)alloc(153600);
  float* pooled   = (float*)alloc(614400);
  ushort_t* adj_c  = (ushort_t*)alloc(4194304);
  ushort_t* pe_c   = (ushort_t*)alloc(2048);
  ushort_t* wihf_c = (ushort_t*)alloc(792000);
  ushort_t* wihb_c = (ushort_t*)alloc(792000);
  ushort_t* whhf_c = (ushort_t*)alloc(720000);
  ushort_t* whhb_c = (ushort_t*)alloc(720000);
  ushort_t* bihf_c = (ushort_t*)alloc(2400);
  ushort_t* bhhf_c = (ushort_t*)alloc(2400);
  ushort_t* bihb_c = (ushort_t*)alloc(2400);
  ushort_t* bhhb_c = (ushort_t*)alloc(2400);
  ushort_t* wq_c   = (ushort_t*)alloc(720000);
  ushort_t* bq_c   = (ushort_t*)alloc(1200);
  ushort_t* wk_c   = (ushort_t*)alloc(720000);
  ushort_t* bk_c   = (ushort_t*)alloc(1200);
  ushort_t* sw1_c  = (ushort_t*)alloc(3072);
  ushort_t* sb1_c  = (ushort_t*)alloc(256);
  ushort_t* sw2_c  = (ushort_t*)alloc(3072);
  ushort_t* sb2_c  = (ushort_t*)alloc(256);
  ushort_t* g1w_c  = (ushort_t*)alloc(720000);
  ushort_t* g1b_c  = (ushort_t*)alloc(1200);
  ushort_t* g2w_c  = (ushort_t*)alloc(720000);
  ushort_t* g2b_c  = (ushort_t*)alloc(1200);
  ushort_t* af1_c  = (ushort_t*)alloc(720000);
  ushort_t* af2_c  = (ushort_t*)alloc(720000);
  ushort_t* fcw_c  = (ushort_t*)alloc(7200);
  ushort_t* fcb_c  = (ushort_t*)alloc(256);
  ushort_t* embs  = (ushort_t*)alloc(11010048);
  ushort_t* textout = (ushort_t*)alloc(19660800);
  char* R = alloc(95420416);
  ushort_t* em_c    = (ushort_t*)(R);            // 18 MB; dead after k_embs
  ushort_t* gip_f   = (ushort_t*)(R);            // 41.9 MB [b,t][1280] gate-packed
  ushort_t* gip_b   = (ushort_t*)(R+41943040);   // 41.9 MB; both dead after lstm2
  ushort_t* qh      = (ushort_t*)(R);
  ushort_t* kh      = (ushort_t*)(R+20447232);
  float*    scores  = (float*)(R+40894464);
  ushort_t* adj_sem = (ushort_t*)(R+91226112);
  ushort_t* se_x    = (ushort_t*)(R+40894464);
  ushort_t* Zb      = (ushort_t*)(R+60555264);
  ushort_t* x_sem   = (ushort_t*)(R);
  ushort_t* xb      = (ushort_t*)(R+20447232);
  (void)ws_size; (void)n_in; (void)in_sizes; (void)out_size;

  // --- normalize all float inputs to bf16 (cheap per-block probe, x8 vec) ---
  {
    const int idx[27] = {7,6, 8,9,13,10,14,11,12,15,16,17,18,19,20,21,22,23,24,25,26,27,28,29,30,31,32};
    ushort_t* dl[27] = {em_c,adj_c, pe_c,wihf_c,wihb_c,whhf_c,whhb_c,bihf_c,bhhf_c,bihb_c,bhhb_c,
                        wq_c,bq_c,wk_c,bk_c,sw1_c,sb1_c,sw2_c,sb2_c,
                        g1w_c,g1b_c,g2w_c,g2b_c,af1_c,af2_c,fcw_c,fcb_c};
    const long nl[27] = {9000000L,2097152L, 900,396000,396000,360000,360000,1200,1200,1200,1200,
                         360000,600,360000,600,1536,12,1536,128,
                         360000,600,360000,600,360000,360000,3600,3};
    for (int i=0;i<27;i++){
      long nb = ((nl[i]+7)/8 + 255)/256;
      k_cvt8<<<(int)nb,256,0,stream>>>(d_in[idx[i]], dl[i], nl[i], probe);
    }
  }

  // --- prep ---
  k_lens<<<128,128,0,stream>>>(ti, li, nonpad, text_len, left_len);
  k_aspmean<<<128,128,0,stream>>>(ai, em_c, asp_mean);
  k_embs<<<16384,128,0,stream>>>(ti, pi, aps, em_c, pe_c, asp_mean, embs);
  k_padwih2<<<(1280*336+255)/256,256,0,stream>>>(wihf_c, wihpf);
  k_padwih2<<<(1280*336+255)/256,256,0,stream>>>(wihb_c, wihpb);
  k_padwhh2<<<(1280*320+255)/256,256,0,stream>>>(whhf_c, whh2f);
  k_padwhh2<<<(1280*320+255)/256,256,0,stream>>>(whhb_c, whh2b);
  k_biassum2<<<(1280+255)/256,256,0,stream>>>(bihf_c, bhhf_c, biasgf);
  k_biassum2<<<(1280+255)/256,256,0,stream>>>(bihb_c, bhhb_c, biasgb);
  k_biascvt<<<3,256,0,stream>>>(bq_c, bqf, 600);
  k_biascvt<<<3,256,0,stream>>>(bk_c, bkf, 600);
  k_biascvt<<<3,256,0,stream>>>(g1b_c, gc1bf, 600);
  k_biascvt<<<3,256,0,stream>>>(g2b_c, gc2bf, 600);

  // --- input projections (embs @ Wih2^T + bias), gate-packed cols, MODE 1 ---
  gemm_k<1,1><<<dim3(128,10,1),256,0,stream>>>(16384,1280,336, embs,336,0, wihpf,336,0,
        nullptr, gip_f,1280,0, biasgf,0,nullptr,nullptr);
  gemm_k<1,1><<<dim3(128,10,1),256,0,stream>>>(16384,1280,336, embs,336,0, wihpb,336,0,
        nullptr, gip_b,1280,0, biasgb,0,nullptr,nullptr);

  // --- BiLSTM: register-resident Whh, fence-free coherent h exchange ---
  hipMemsetAsync(hbuf, 0, 327680, stream);
  hipMemsetAsync(barr, 0, 2048, stream);
  lstm2_k<<<40,512,0,stream>>>(whh2f, whh2b, gip_f, gip_b, hbuf, barr, textout, text_len);

  // --- q/k projections, head-scattered (dk padded 100->104) ---
  hipMemsetAsync(qh, 0, 20447232, stream);
  hipMemsetAsync(kh, 0, 20447232, stream);
  gemm_k<1,2><<<dim3(128,5,1),256,0,stream>>>(16384,600,600, textout,600,0, wq_c,600,0,
        nullptr, qh,0,0, bqf,0,nullptr,nullptr);
  gemm_k<1,2><<<dim3(128,5,1),256,0,stream>>>(16384,600,600, textout,600,0, wk_c,600,0,
        nullptr, kh,0,0, bkf,0,nullptr,nullptr);

  // --- attention scores + mask ---
  gemm_k<1,3><<<dim3(1,1,768),256,0,stream>>>(128,128,104, qh,104,13312, kh,104,13312,
        scores, nullptr, 128, 16384, nullptr,0,nullptr, nonpad);

  // --- entmax15 (in place) ---
  k_entmax<<<98304,64,0,stream>>>(scores);

  // --- adjacency: head-mean + eye + valid; degree norms ---
  k_adjsem<<<(2097152+255)/256,256,0,stream>>>(scores, nonpad, adj_sem);
  k_dn<<<16384,64,0,stream>>>(adj_sem, dn1);
  k_dn<<<16384,64,0,stream>>>(adj_c, dn2);

  // --- SE #1 + GCN #1 (norm folded: Z = D (A (D * se * X))) ---
  k_mean<<<16384,64,0,stream>>>(textout, ymean);
  k_senet<<<128,128,0,stream>>>(ymean, sw1_c,sb1_c,sw2_c,sb2_c, nonpad, ysoft);
  k_scale2<<<(9830400+255)/256,256,0,stream>>>(textout, ysoft, dn1, se_x);
  gemm_k<0,1><<<dim3(1,5,128),256,0,stream>>>(128,600,128, adj_sem,128,16384, se_x,600,76800,
        nullptr, Zb,600,76800, nullptr,0, dn1, nullptr);
  gemm_k<0,1><<<dim3(128,5,1),256,0,stream>>>(16384,600,600, Zb,600,0, g1w_c,600,0,
        nullptr, x_sem,600,0, gc1bf,1,nullptr,nullptr);

  // --- SE #2 + GCN #2 (uses input adj) ---
  k_mean<<<16384,64,0,stream>>>(x_sem, ymean);
  k_senet<<<128,128,0,stream>>>(ymean, sw1_c,sb1_c,sw2_c,sb2_c, nonpad, ysoft);
  k_scale2<<<(9830400+255)/256,256,0,stream>>>(x_sem, ysoft, dn2, se_x);
  gemm_k<0,1><<<dim3(1,5,128),256,0,stream>>>(128,600,128, adj_c,128,16384, se_x,600,76800,
        nullptr, Zb,600,76800, nullptr,0, dn2, nullptr);
  gemm_k<0,1><<<dim3(128,5,1),256,0,stream>>>(16384,600,600, Zb,600,0, g2w_c,600,0,
        nullptr, xb,600,0, gc2bf,1,nullptr,nullptr);

  // --- biaffine pooling (only row left_len[b] of A1/A2 is ever used) ---
  k_gather<<<128,128,0,stream>>>(xb, left_len, xr);
  k_gather<<<128,128,0,stream>>>(x_sem, left_len, xsr);
  gemm_k<0,1><<<dim3(1,5,1),256,0,stream>>>(128,600,600, xr,600,0, af1_c,600,0,
        nullptr, g1,600,0, nullptr,0,nullptr,nullptr);
  gemm_k<0,1><<<dim3(1,5,1),256,0,stream>>>(128,600,600, xsr,600,0, af2_c,600,0,
        nullptr, g2,600,0, nullptr,0,nullptr,nullptr);
  k_pool<<<128,256,0,stream>>>(g1, x_sem, pooled, 0);
  k_pool<<<128,256,0,stream>>>(g2, xb, pooled, 600);

  // --- final FC (dtype-adaptive output) ---
  k_final<<<128,64,0,stream>>>(pooled, fcw_c, fcb_c, d_out, probe);
}

// Round 5
// 2406.914 us; speedup vs baseline: 1.0210x; 1.0210x over previous
//
#include <hip/hip_runtime.h>

typedef unsigned short ushort_t;
typedef unsigned int   uint_t;
typedef __attribute__((ext_vector_type(8))) short short8;
typedef __attribute__((ext_vector_type(4))) float floatx4;

#define NEGV -1000000000.0f

__device__ __forceinline__ float bf2f(ushort_t h){ return __uint_as_float(((uint_t)h)<<16); }
__device__ __forceinline__ ushort_t f2bf(float f){
  uint_t u = __float_as_uint(f);
  uint_t r = u + 0x7fffu + ((u>>16)&1u);
  return (ushort_t)(r>>16);
}
__device__ __forceinline__ float wredsum(float v){ for(int o=32;o;o>>=1) v += __shfl_xor(v,o); return v; }
__device__ __forceinline__ float wredmax(float v){ for(int o=32;o;o>>=1) v = fmaxf(v,__shfl_xor(v,o)); return v; }
__device__ __forceinline__ int   wredsumi(int v){ for(int o=32;o;o>>=1) v += __shfl_xor(v,o); return v; }

// coherent (cross-XCD) 16B load: bypasses L1/L2 via sc0 sc1 -> reads L3/IF.
template<int OFF>
__device__ __forceinline__ short8 ldg_b128_cohr(const ushort_t* p){
  short8 r;
  asm volatile("global_load_dwordx4 %0, %1, off offset:%2 sc0 sc1"
               : "=&v"(r) : "v"(p), "n"(OFF) : "memory");
  return r;
}
#define LD10C(dst, p) \
  dst[0]=ldg_b128_cohr<0>(p);   dst[1]=ldg_b128_cohr<64>(p);  \
  dst[2]=ldg_b128_cohr<128>(p); dst[3]=ldg_b128_cohr<192>(p); \
  dst[4]=ldg_b128_cohr<256>(p); dst[5]=ldg_b128_cohr<320>(p); \
  dst[6]=ldg_b128_cohr<384>(p); dst[7]=ldg_b128_cohr<448>(p); \
  dst[8]=ldg_b128_cohr<512>(p); dst[9]=ldg_b128_cohr<576>(p);

// coherent 2B store: write-through past the XCD L2 (sc0 sc1).
__device__ __forceinline__ void stg_b16_cohr(ushort_t* p, ushort_t v){
  uint_t u = v;
  asm volatile("global_store_short %0, %1, off sc0 sc1" :: "v"(p), "v"(u) : "memory");
}

// ---------------------------------------------------------------------------
// dtype-adaptive conversion, vectorized x8. Probe once per block in wave 0.
// ---------------------------------------------------------------------------
__global__ void k_cvt8(const void* __restrict__ src, ushort_t* __restrict__ dst,
                       long n, const ushort_t* __restrict__ probe_src){
  __shared__ int sflag;
  if (threadIdx.x < 64){
    ushort_t u = probe_src[2*threadIdx.x];
    int e = (u>>7)&0xFF;
    int c = (e>=100 && e<=140) ? 1 : 0;
    c = wredsumi(c);
    if (threadIdx.x==0) sflag = (c>32) ? 1 : 0;
  }
  __syncthreads();
  bool isbf = (sflag!=0);
  long base = (blockIdx.x*256L + threadIdx.x)*8;
  if (base>=n) return;
  if (isbf){
    if (base+8<=n) *(uint4*)(dst+base) = *(const uint4*)((const ushort_t*)src+base);
    else for (long i=base;i<n;i++) dst[i]=((const ushort_t*)src)[i];
  } else {
    const float* s = (const float*)src;
    if (base+8<=n){
      float4 v0 = *(const float4*)(s+base);
      float4 v1 = *(const float4*)(s+base+4);
      ushort_t o[8] = {f2bf(v0.x),f2bf(v0.y),f2bf(v0.z),f2bf(v0.w),
                       f2bf(v1.x),f2bf(v1.y),f2bf(v1.z),f2bf(v1.w)};
      *(uint4*)(dst+base) = *(uint4*)o;
    } else {
      for (long i=base;i<n;i++) dst[i]=f2bf(s[i]);
    }
  }
}

__device__ __forceinline__ bool probe_is_bf16(const ushort_t* probe_src){
  int c=0;
  #pragma unroll 1
  for (int i=0;i<64;i++){
    ushort_t u = probe_src[2*i];
    int e = (u>>7)&0xFF;
    c += (e>=100 && e<=140) ? 1 : 0;
  }
  return c>32;
}

// ---------------------------------------------------------------------------
// small prep kernels
// ---------------------------------------------------------------------------
__global__ void k_lens(const int* __restrict__ ti, const int* __restrict__ li,
                       int* __restrict__ nonpad, int* __restrict__ text_len,
                       int* __restrict__ left_len){
  int b = blockIdx.x, t = threadIdx.x;
  nonpad[b*128+t] = (ti[b*128+t]!=0) ? 1 : 0;
  if (t==0){
    int c=0; for (int k2=0;k2<128;k2++) c += (ti[b*128+k2]!=0);
    text_len[b]=c;
    int l=0; for (int k2=0;k2<24;k2++) l += (li[b*24+k2]!=0);
    left_len[b]=l;
  }
}

__global__ void k_aspmean(const int* __restrict__ ai, const ushort_t* __restrict__ em,
                          float* __restrict__ asp_mean){
  int b = blockIdx.x;
  int idxs[5]; int cnt=0;
  for (int a=0;a<5;a++){ int ix=ai[b*5+a]; idxs[a]=ix; cnt += (ix!=0); }
  float inv = 1.0f/(float)cnt;
  for (int d=threadIdx.x; d<300; d+=128){
    float s=0.f;
    for (int a=0;a<5;a++) if (idxs[a]) s += bf2f(em[(long)idxs[a]*300+d]);
    asp_mean[b*300+d] = s*inv;
  }
}

__global__ void k_embs(const int* __restrict__ ti, const int* __restrict__ pi,
                       const int* __restrict__ asp_post,
                       const ushort_t* __restrict__ em, const ushort_t* __restrict__ pe,
                       const float* __restrict__ asp_mean, ushort_t* __restrict__ embs){
  int blk = blockIdx.x;
  int b = blk>>7, t = blk&127;
  int ap = asp_post[b];
  int tix = ti[b*128+t];
  int pix = pi[b*128+t];
  for (int col=threadIdx.x; col<336; col+=128){
    ushort_t v;
    if (col<300) v = (t==ap) ? f2bf(asp_mean[b*300+col]) : em[(long)tix*300+col];
    else if (col<330) v = pe[pix*30 + (col-300)];
    else v = 0;
    embs[(long)(b*128+t)*336 + col] = v;
  }
}

// Wih repack for gate-packed gi: dst[1280][336], row' = j*4+gate
// (j padded 300->320, K 330->336). src row = gate*300+j, 330 cols.
__global__ void k_padwih2(const ushort_t* __restrict__ src, ushort_t* __restrict__ dst){
  int i = blockIdx.x*blockDim.x + threadIdx.x;
  if (i >= 1280*336) return;
  int r = i/336, k = i - r*336;
  int j = r>>2, gate = r&3;
  ushort_t v = 0;
  if (j<300 && k<330) v = src[(long)(gate*300+j)*330 + k];
  dst[i] = v;
}

// Whh repack for reg-resident LSTM: dst[1280][320] bf16, row' = j*4 + gate
// (j padded 300->320, K 300->320, zeros elsewhere). src row = gate*300 + j.
__global__ void k_padwhh2(const ushort_t* __restrict__ src, ushort_t* __restrict__ dst){
  int i = blockIdx.x*blockDim.x + threadIdx.x;
  if (i >= 1280*320) return;
  int r = i/320, k = i - r*320;
  int j = r>>2, gate = r&3;
  ushort_t v = 0;
  if (j<300 && k<300) v = src[(long)(gate*300+j)*300 + k];
  dst[i] = v;
}

// gate-packed bias: dst[j*4+gate] = bih[gate*300+j] + bhh[gate*300+j]
__global__ void k_biassum2(const ushort_t* __restrict__ a, const ushort_t* __restrict__ b,
                           float* __restrict__ dst){
  int i = blockIdx.x*blockDim.x + threadIdx.x;
  if (i>=1280) return;
  int j = i>>2, g = i&3;
  dst[i] = (j<300) ? (bf2f(a[g*300+j]) + bf2f(b[g*300+j])) : 0.f;
}

__global__ void k_biascvt(const ushort_t* __restrict__ a, float* __restrict__ dst, int n){
  int i = blockIdx.x*blockDim.x + threadIdx.x;
  if (i<n) dst[i] = bf2f(a[i]);
}

// ---------------------------------------------------------------------------
// generic bf16 MFMA GEMM: 128x128 tile, 4 waves (2x2), each 64x64 via 4x4
// frags of 16x16x32.  TB=1: C = A * B^T.  TB=0: C = A * B.
// MODE 1: bf16 store (opt bias/relu/rowscale)
// MODE 2: qk head-scatter bf16 store (bias), T=128, dk=100->104
// MODE 3: f32 store, *0.1 and nonpad column mask (attention scores)
// ---------------------------------------------------------------------------
template<int TB, int MODE>
__global__ __launch_bounds__(256) void gemm_k(
    int M, int N, int K,
    const ushort_t* __restrict__ A, long lda, long sAz,
    const ushort_t* __restrict__ B, long ldb, long sBz,
    float* __restrict__ Cf, ushort_t* __restrict__ Cb, long ldc, long sCz,
    const float* __restrict__ bias, int relu,
    const float* __restrict__ rowscale,
    const int* __restrict__ nonpad)
{
  __shared__ ushort_t As[128*40];
  __shared__ ushort_t Bs[128*40];
  const int tid = threadIdx.x;
  const int m0 = blockIdx.x*128, n0 = blockIdx.y*128;
  const int z = blockIdx.z;
  const ushort_t* Ap = A + (long)z*sAz;
  const ushort_t* Bp = B + (long)z*sBz;
  floatx4 acc[4][4];
  #pragma unroll
  for (int i=0;i<4;i++)
    #pragma unroll
    for (int j=0;j<4;j++){ acc[i][j][0]=0.f; acc[i][j][1]=0.f; acc[i][j][2]=0.f; acc[i][j][3]=0.f; }
  const int w = tid>>6, wm = w&1, wn = w>>1;
  const int lane = tid&63, lr = lane&15, lq = lane>>4;

  for (int k0=0;k0<K;k0+=32){
    #pragma unroll
    for (int c2=0;c2<2;c2++){
      int ch = tid + 256*c2;
      int row = ch>>2, kc = (ch&3)*8;
      int gr = m0+row, gk = k0+kc;
      uint4 v{};
      if (gr<M && gk<K) v = *(const uint4*)(Ap + (long)gr*lda + gk);
      *(uint4*)(&As[row*40+kc]) = v;
    }
    if (TB){
      #pragma unroll
      for (int c2=0;c2<2;c2++){
        int ch = tid + 256*c2;
        int row = ch>>2, kc = (ch&3)*8;
        int gn = n0+row, gk = k0+kc;
        uint4 v{};
        if (gn<N && gk<K) v = *(const uint4*)(Bp + (long)gn*ldb + gk);
        int sw = kc ^ (((row>>3)&3)<<3);
        *(uint4*)(&Bs[row*40+sw]) = v;
      }
    } else {
      #pragma unroll
      for (int c2=0;c2<2;c2++){
        int ch = tid + 256*c2;
        int kk = ch>>4, nc = (ch&15)*8;
        int gk = k0+kk, gn = n0+nc;
        uint4 v{};
        if (gk<K && gn<N) v = *(const uint4*)(Bp + (long)gk*ldb + gn);
        uint_t wsv[4] = {v.x, v.y, v.z, v.w};
        #pragma unroll
        for (int e=0;e<8;e++){
          ushort_t hv = (e&1) ? (ushort_t)(wsv[e>>1]>>16) : (ushort_t)(wsv[e>>1]&0xffffu);
          int n = nc+e;
          int sw = kk ^ (((n>>3)&3)<<3);
          Bs[n*40+sw] = hv;
        }
      }
    }
    __syncthreads();
    short8 af[4], bfv[4];
    #pragma unroll
    for (int i=0;i<4;i++) af[i] = *(const short8*)(&As[(wm*64+i*16+lr)*40 + lq*8]);
    #pragma unroll
    for (int j=0;j<4;j++){
      int n = wn*64+j*16+lr;
      int sw = (lq*8) ^ (((n>>3)&3)<<3);
      bfv[j] = *(const short8*)(&Bs[n*40+sw]);
    }
    #pragma unroll
    for (int i=0;i<4;i++)
      #pragma unroll
      for (int j=0;j<4;j++)
        acc[i][j] = __builtin_amdgcn_mfma_f32_16x16x32_bf16(af[i], bfv[j], acc[i][j], 0,0,0);
    __syncthreads();
  }

  #pragma unroll
  for (int i=0;i<4;i++){
    #pragma unroll
    for (int j=0;j<4;j++){
      #pragma unroll
      for (int r=0;r<4;r++){
        int row = m0 + wm*64 + i*16 + lq*4 + r;
        int col = n0 + wn*64 + j*16 + lr;
        if (row<M && col<N){
          float v = acc[i][j][r];
          if (rowscale) v *= rowscale[(long)z*M + row];
          if (bias) v += bias[col];
          if (relu && v<0.f) v = 0.f;
          if (MODE==1){
            Cb[(long)z*sCz + (long)row*ldc + col] = f2bf(v);
          } else if (MODE==2){
            int b = row>>7, t = row&127;
            int h = col/100, d = col - h*100;
            Cb[ ((long)((b*6+h)*128+t))*104 + d ] = f2bf(v);
          } else if (MODE==3){
            v *= 0.1f;
            if (!nonpad[(z/6)*128 + col]) v = NEGV;
            Cf[(long)z*sCz + (long)row*ldc + col] = v;
          }
        }
      }
    }
  }
}

// ---------------------------------------------------------------------------
// LDS-resident BiLSTM, fence-free cross-XCD h exchange.
// Grid: 40 blocks = 2 dirs x 10 j-slices(32 hidden) x 2 batch-halves(64).
// Block: 512 threads = 8 waves, wave grid 4M x 2N.
// ROUND-5 FIX: rounds 1-4 proved the register allocator will NOT keep the
// 80 loop-invariant Whh VGPRs live across the 128-step loop (it remats or
// scratch-spills them; VGPR_Count 148/180/104/104, per-step ~23k cy).
// So Whh lives in LDS instead: the block's 128-row x 320-col slice (80 KB,
// padded to 328 cols = 82 KB vs 160 KB available) is staged ONCE, and each
// wave ds_read_b128's its A-fragments just-in-time in the MFMA loop.
// Per block-step LDS A-traffic = 160 KB @ 128 B/cy ~ 1280 cy; +8-elem row
// pad makes the 16-row column read a 2-way (free) bank alias.
// Cell update lane-local (A rows packed j*4+gate); c,h persist in registers.
// h ping-pongs through global sc0|sc1 accesses; per-step 10-block barrier
// via agent-scope atomic; no __threadfence (no L2 wb/inv).
// ---------------------------------------------------------------------------
#define ALD 328   // padded LDS row stride (elements)

__global__ __launch_bounds__(512,2) void lstm2_k(
    const ushort_t* __restrict__ whh2f, const ushort_t* __restrict__ whh2b,
    const ushort_t* __restrict__ gipf, const ushort_t* __restrict__ gipb,
    ushort_t* __restrict__ hbuf,          // [2 dir][2 buf][128 b][320] bf16
    int* __restrict__ barr,               // [4 grp][128 step]
    ushort_t* __restrict__ text_out, const int* __restrict__ text_len)
{
  __shared__ ushort_t Alds[128*ALD];      // 82 KB

  const int bx = blockIdx.x;
  const int slice = bx % 10;
  const int grp   = bx / 10;              // 0..3 = (bh<<1)|dir
  const int dir = grp & 1, bh = grp >> 1;
  const ushort_t* __restrict__ whh = dir ? whh2b : whh2f;
  const ushort_t* __restrict__ gip = dir ? gipb : gipf;
  ushort_t* hb = hbuf + (long)dir * (2L*128*320);
  int* bar = barr + grp*128;

  const int tid = threadIdx.x;
  const int w = tid>>6, lane = tid&63, lr = lane&15, lq = lane>>4;
  const int wm = w&3, wn = w>>2;          // wave grid: 4 Mgroups x 2 Ngroups

  // ---- stage Whh slice -> LDS (once): 128 rows x 320 cols, coalesced ----
  for (int i = tid; i < 128*40; i += 512){
    int row = i/40, c = (i-row*40)*8;
    uint4 v = *(const uint4*)(whh + (long)(slice*128+row)*320 + c);
    *(uint4*)(&Alds[row*ALD + c]) = v;
  }

  // ---- lane-owned (jj, b) pairs ----
  int jj_[2], b_[2], tl_[2];
  #pragma unroll
  for (int mi=0;mi<2;mi++) jj_[mi] = slice*32 + wm*8 + mi*4 + lq;
  #pragma unroll
  for (int ni=0;ni<2;ni++){ b_[ni] = bh*64 + wn*32 + ni*16 + lr; tl_[ni] = text_len[b_[ni]]; }

  // LDS element offsets of this lane's two A-fragment rows (k-base lq*8)
  const int aoff0 = ((wm*2+0)*16+lr)*ALD + lq*8;
  const int aoff1 = ((wm*2+1)*16+lr)*ALD + lq*8;

  float    c_st[2][2];
  ushort_t h_st[2][2];
  #pragma unroll
  for (int mi=0;mi<2;mi++){ c_st[mi][0]=0.f; c_st[mi][1]=0.f; h_st[mi][0]=0; h_st[mi][1]=0; }

  __syncthreads();                        // Alds ready

  for (int s=0; s<128; s++){
    const int t = dir ? (127-s) : s;
    const ushort_t* rb = hb + (long)(s&1)*(128L*320);
    ushort_t*       wb = hb + (long)((s+1)&1)*(128L*320);

    // gi loads (plain; read-once stream); 8B per (jj,b)
    uint2 gp[2][2];
    #pragma unroll
    for (int mi=0;mi<2;mi++)
      #pragma unroll
      for (int ni=0;ni<2;ni++)
        gp[mi][ni] = *(const uint2*)(gip + ((long)(b_[ni]*128 + t))*1280 + jj_[mi]*4);

    // h B-fragments: coherent loads (bypass stale L1/L2, read L3)
    short8 bfr[2][10];
    {
      const ushort_t* pa0 = rb + (long)b_[0]*320 + lq*8;
      const ushort_t* pa1 = rb + (long)b_[1]*320 + lq*8;
      LD10C(bfr[0], pa0);
      LD10C(bfr[1], pa1);
    }
    asm volatile("s_waitcnt vmcnt(0)" ::: "memory");
    __builtin_amdgcn_sched_barrier(0);

    floatx4 acc[2][2];
    #pragma unroll
    for (int mi=0;mi<2;mi++)
      #pragma unroll
      for (int ni=0;ni<2;ni++){ acc[mi][ni][0]=0.f; acc[mi][ni][1]=0.f; acc[mi][ni][2]=0.f; acc[mi][ni][3]=0.f; }

    // MFMA loop: A fragments read just-in-time from LDS (compiler pipelines
    // the ds_read_b128s with lgkmcnt; low register pressure, no spill)
    #pragma unroll
    for (int kf=0;kf<10;kf++){
      short8 a0 = *(const short8*)(&Alds[aoff0 + kf*32]);
      short8 a1 = *(const short8*)(&Alds[aoff1 + kf*32]);
      acc[0][0] = __builtin_amdgcn_mfma_f32_16x16x32_bf16(a0, bfr[0][kf], acc[0][0], 0,0,0);
      acc[0][1] = __builtin_amdgcn_mfma_f32_16x16x32_bf16(a0, bfr[1][kf], acc[0][1], 0,0,0);
      acc[1][0] = __builtin_amdgcn_mfma_f32_16x16x32_bf16(a1, bfr[0][kf], acc[1][0], 0,0,0);
      acc[1][1] = __builtin_amdgcn_mfma_f32_16x16x32_bf16(a1, bfr[1][kf], acc[1][1], 0,0,0);
    }

    // lane-local cell update
    #pragma unroll
    for (int mi=0;mi<2;mi++){
      #pragma unroll
      for (int ni=0;ni<2;ni++){
        float g_i = acc[mi][ni][0] + bf2f((ushort_t)(gp[mi][ni].x & 0xffffu));
        float g_f = acc[mi][ni][1] + bf2f((ushort_t)(gp[mi][ni].x >> 16));
        float g_g = acc[mi][ni][2] + bf2f((ushort_t)(gp[mi][ni].y & 0xffffu));
        float g_o = acc[mi][ni][3] + bf2f((ushort_t)(gp[mi][ni].y >> 16));
        float ig = 1.f/(1.f+expf(-g_i));
        float fg = 1.f/(1.f+expf(-g_f));
        float gg = tanhf(g_g);
        float og = 1.f/(1.f+expf(-g_o));
        float cn = fg*c_st[mi][ni] + ig*gg;
        float hn = og*tanhf(cn);
        bool m = (t < tl_[ni]);
        if (m) c_st[mi][ni] = cn;
        ushort_t hv = m ? f2bf(hn) : h_st[mi][ni];
        h_st[mi][ni] = hv;
        if (jj_[mi] < 300){
          stg_b16_cohr(wb + (long)b_[ni]*320 + jj_[mi], hv);
          text_out[((long)(b_[ni]*128 + t))*600 + dir*300 + jj_[mi]] = m ? f2bf(hn) : (ushort_t)0;
        }
      }
    }

    // drain stores (sc1 -> visible at coherent point once vmcnt==0)
    asm volatile("s_waitcnt vmcnt(0)" ::: "memory");
    __syncthreads();
    if (tid==0){
      __hip_atomic_fetch_add(&bar[s], 1, __ATOMIC_RELAXED, __HIP_MEMORY_SCOPE_AGENT);
      while (__hip_atomic_load(&bar[s], __ATOMIC_RELAXED, __HIP_MEMORY_SCOPE_AGENT) < 10)
        __builtin_amdgcn_s_sleep(1);
    }
    __syncthreads();
  }
}

// ---------------------------------------------------------------------------
// entmax15 over rows of 128 (in-place on f32 scores). 1 wave per row.
// ---------------------------------------------------------------------------
__global__ __launch_bounds__(64) void k_entmax(float* __restrict__ p){
  long row = blockIdx.x;
  float* base = p + row*128;
  __shared__ float xo[128], xs[128], c1[128], c2[128];
  int t = threadIdx.x;
  float a = base[t]*0.5f, b = base[t+64]*0.5f;
  float m = wredmax(fmaxf(a,b));
  a -= m; b -= m;
  xo[t]=a; xo[t+64]=b; xs[t]=a; xs[t+64]=b;
  __syncthreads();
  for (int k2=2;k2<=128;k2<<=1){
    for (int j=k2>>1;j>0;j>>=1){
      int i = ((t & ~(j-1))<<1) | (t & (j-1));
      int ixj = i | j;
      float vi = xs[i], vj = xs[ixj];
      bool blk = (i & k2)==0;
      bool sw = blk ? (vi < vj) : (vi > vj);
      __syncthreads();
      if (sw){ xs[i]=vj; xs[ixj]=vi; }
      __syncthreads();
    }
  }
  c1[t]=xs[t];       c2[t]=xs[t]*xs[t];
  c1[t+64]=xs[t+64]; c2[t+64]=xs[t+64]*xs[t+64];
  __syncthreads();
  for (int d=1; d<128; d<<=1){
    float a1 = (t>=d)     ? c1[t-d]    : 0.f;
    float a2 = (t>=d)     ? c2[t-d]    : 0.f;
    float b1 = (t+64>=d)  ? c1[t+64-d] : 0.f;
    float b2 = (t+64>=d)  ? c2[t+64-d] : 0.f;
    float x1=c1[t], y1=c2[t], x2=c1[t+64], y2=c2[t+64];
    __syncthreads();
    c1[t]=x1+a1; c2[t]=y1+a2; c1[t+64]=x2+b1; c2[t+64]=y2+b2;
    __syncthreads();
  }
  float tau_a, tau_b; int cnt=0;
  {
    float rho = (float)(t+1);
    float mean = c1[t]/rho, msq = c2[t]/rho;
    float ss = rho*(msq-mean*mean);
    float delta = (1.f-ss)/rho;
    tau_a = mean - sqrtf(fmaxf(delta,0.f));
    cnt += (tau_a <= xs[t]) ? 1 : 0;
  }
  {
    float rho = (float)(t+65);
    float mean = c1[t+64]/rho, msq = c2[t+64]/rho;
    float ss = rho*(msq-mean*mean);
    float delta = (1.f-ss)/rho;
    tau_b = mean - sqrtf(fmaxf(delta,0.f));
    cnt += (tau_b <= xs[t+64]) ? 1 : 0;
  }
  __syncthreads();
  c1[t]=tau_a; c1[t+64]=tau_b;
  __syncthreads();
  int support = wredsumi(cnt);
  support = (support<1) ? 1 : ((support>128) ? 128 : support);
  float tau_star = c1[support-1];
  float oa = fmaxf(xo[t]-tau_star, 0.f);
  float ob = fmaxf(xo[t+64]-tau_star, 0.f);
  base[t] = oa*oa; base[t+64] = ob*ob;
}

// ---------------------------------------------------------------------------
__global__ void k_adjsem(const float* __restrict__ p, const int* __restrict__ nonpad,
                         ushort_t* __restrict__ adj_sem){
  int idx = blockIdx.x*blockDim.x + threadIdx.x;
  if (idx >= 128*128*128) return;
  int b = idx>>14, rem = idx&16383, i = rem>>7, j = rem&127;
  float s = 0.f;
  for (int h=0;h<6;h++) s += p[(long)b*98304 + h*16384 + i*128 + j];
  float v = s/6.0f;
  if (i==j) v = 1.0f;
  if (!nonpad[b*128+i]) v = 0.f;
  adj_sem[idx] = f2bf(v);
}

__global__ __launch_bounds__(64) void k_dn(const ushort_t* __restrict__ src, float* __restrict__ dnv){
  long row = blockIdx.x;
  int l = threadIdx.x;
  float s = bf2f(src[row*128+l]) + bf2f(src[row*128+l+64]);
  s = wredsum(s);
  if (l==0) dnv[row] = 1.0f/sqrtf(s+1.0f);
}

__global__ __launch_bounds__(64) void k_mean(const ushort_t* __restrict__ X, float* __restrict__ ymean){
  long row = blockIdx.x;
  float s=0.f;
  for (int d=threadIdx.x; d<600; d+=64) s += bf2f(X[row*600+d]);
  s = wredsum(s);
  if (threadIdx.x==0) ymean[row] = s/600.0f;
}

__global__ void k_senet(const float* __restrict__ ymean,
                        const ushort_t* __restrict__ w1, const ushort_t* __restrict__ b1,
                        const ushort_t* __restrict__ w2, const ushort_t* __restrict__ b2,
                        const int* __restrict__ nonpad, float* __restrict__ ysoft){
  int b = blockIdx.x, t = threadIdx.x;
  __shared__ float yv[128], z1[12], red[128];
  yv[t] = ymean[b*128+t];
  __syncthreads();
  if (t<12){
    float s = bf2f(b1[t]);
    for (int k2=0;k2<128;k2++) s += yv[k2]*bf2f(w1[t*128+k2]);
    z1[t] = fmaxf(s,0.f);
  }
  __syncthreads();
  float v = bf2f(b2[t]);
  for (int r=0;r<12;r++) v += z1[r]*bf2f(w2[t*12+r]);
  if (!nonpad[b*128+t]) v += NEGV;
  red[t]=v; __syncthreads();
  for (int s2=64;s2>0;s2>>=1){ if (t<s2) red[t]=fmaxf(red[t],red[t+s2]); __syncthreads(); }
  float mx = red[0]; __syncthreads();
  float e = expf(v-mx);
  red[t]=e; __syncthreads();
  for (int s2=64;s2>0;s2>>=1){ if (t<s2) red[t]+=red[t+s2]; __syncthreads(); }
  float sm = red[0];
  ysoft[b*128+t] = e/sm;
}

__global__ void k_scale2(const ushort_t* __restrict__ X, const float* __restrict__ ysoft,
                         const float* __restrict__ dnv, ushort_t* __restrict__ out){
  int i = blockIdx.x*blockDim.x + threadIdx.x;
  if (i >= 128*128*600) return;
  int row = i/600;
  out[i] = f2bf(bf2f(X[i])*ysoft[row]*dnv[row]);
}

__global__ void k_gather(const ushort_t* __restrict__ X, const int* __restrict__ left_len,
                         ushort_t* __restrict__ dst){
  int b = blockIdx.x;
  int lb = left_len[b];
  for (int d=threadIdx.x; d<600; d+=128)
    dst[b*600+d] = X[(long)(b*128+lb)*600+d];
}

__global__ __launch_bounds__(256) void k_pool(const ushort_t* __restrict__ g,
                                              const ushort_t* __restrict__ X,
                                              float* __restrict__ pooled, int poff){
  int b = blockIdx.x, tid = threadIdx.x;
  __shared__ float gs[600], sbuf[128], red[256];
  for (int d=tid; d<600; d+=256) gs[d] = bf2f(g[b*600+d]);
  __syncthreads();
  int wv = tid>>6, lane = tid&63;
  for (int jj=wv; jj<128; jj+=4){
    float s=0.f;
    for (int d=lane; d<600; d+=64) s += gs[d]*bf2f(X[(long)(b*128+jj)*600+d]);
    s = wredsum(s);
    if (lane==0) sbuf[jj]=s;
  }
  __syncthreads();
  float v = (tid<128) ? sbuf[tid] : -3.4e38f;
  red[tid]=v; __syncthreads();
  for (int s2=128;s2>0;s2>>=1){ if (tid<s2) red[tid]=fmaxf(red[tid],red[tid+s2]); __syncthreads(); }
  float mx = red[0]; __syncthreads();
  float e = (tid<128) ? expf(v-mx) : 0.f;
  red[tid]=e; __syncthreads();
  for (int s2=128;s2>0;s2>>=1){ if (tid<s2) red[tid]+=red[tid+s2]; __syncthreads(); }
  float sm = red[0]; __syncthreads();
  if (tid<128) sbuf[tid] = e/sm;
  __syncthreads();
  for (int d=tid; d<600; d+=256){
    float acc=0.f;
    for (int j=0;j<128;j++) acc += sbuf[j]*bf2f(X[(long)(b*128+j)*600+d]);
    pooled[(long)b*1200 + poff + d] = acc;
  }
}

__global__ __launch_bounds__(64) void k_final(const float* __restrict__ pooled,
                                              const ushort_t* __restrict__ fcw,
                                              const ushort_t* __restrict__ fcb,
                                              void* __restrict__ out,
                                              const ushort_t* __restrict__ probe_src){
  bool isbf = probe_is_bf16(probe_src);
  int b = blockIdx.x, lane = threadIdx.x;
  for (int p=0;p<3;p++){
    float s=0.f;
    for (int d=lane; d<1200; d+=64) s += pooled[(long)b*1200+d]*bf2f(fcw[d*3+p]);
    s = wredsum(s);
    if (lane==0){
      float r = s + bf2f(fcb[p]);
      if (isbf) ((ushort_t*)out)[b*3+p] = f2bf(r);
      else      ((float*)out)[b*3+p] = r;
    }
  }
}

// ---------------------------------------------------------------------------
extern "C" void kernel_launch(void* const* d_in, const int* in_sizes, int n_in,
                              void* d_out, int out_size, void* d_ws, size_t ws_size,
                              hipStream_t stream) {
  const int*      ti   = (const int*)d_in[0];
  const int*      ai   = (const int*)d_in[1];
  const int*      li   = (const int*)d_in[2];
  const int*      pi   = (const int*)d_in[3];
  const int*      aps  = (const int*)d_in[4];
  const ushort_t* probe = (const ushort_t*)d_in[7];

  char* w = (char*)d_ws; size_t off = 0;
  auto alloc = [&](size_t bytes)->char*{ char* p = w+off; off = (off+bytes+255)&~(size_t)255; return p; };

  int*   text_len = (int*)alloc(512);
  int*   left_len = (int*)alloc(512);
  int*   nonpad   = (int*)alloc(65536);
  float* asp_mean = (float*)alloc(153600);
  float* dn1      = (float*)alloc(65536);
  float* dn2      = (float*)alloc(65536);
  float* ymean    = (float*)alloc(65536);
  float* ysoft    = (float*)alloc(65536);
  ushort_t* wihpf = (ushort_t*)alloc(860160);   // [1280][336] row=j*4+gate
  ushort_t* wihpb = (ushort_t*)alloc(860160);
  ushort_t* whh2f = (ushort_t*)alloc(819200);   // [1280][320] row=j*4+gate
  ushort_t* whh2b = (ushort_t*)alloc(819200);
  ushort_t* hbuf  = (ushort_t*)alloc(327680);   // [2 dir][2 buf][128][320]
  int*      barr  = (int*)alloc(2048);          // [4][128]
  float* biasgf   = (float*)alloc(5120);        // [1280] gate-packed
  float* biasgb   = (float*)alloc(5120);
  float* bqf      = (float*)alloc(2400);
  float* bkf      = (float*)alloc(2400);
  float* gc1bf    = (float*)alloc(2400);
  float* gc2bf    = (float*)alloc(2400);
  ushort_t* g1    = (ushort_t*)alloc(153600);
  ushort_t* g2    = (ushort_t*)alloc(153600);
  ushort_t* xr    = (ushort_t*)alloc(153600);
  ushort_t* xsr   = (ushort_t*)alloc(153600);
  float* pooled   = (float*)alloc(614400);
  ushort_t* adj_c  = (ushort_t*)alloc(4194304);
  ushort_t* pe_c   = (ushort_t*)alloc(2048);
  ushort_t* wihf_c = (ushort_t*)alloc(792000);
  ushort_t* wihb_c = (ushort_t*)alloc(792000);
  ushort_t* whhf_c = (ushort_t*)alloc(720000);
  ushort_t* whhb_c = (ushort_t*)alloc(720000);
  ushort_t* bihf_c = (ushort_t*)alloc(2400);
  ushort_t* bhhf_c = (ushort_t*)alloc(2400);
  ushort_t* bihb_c = (ushort_t*)alloc(2400);
  ushort_t* bhhb_c = (ushort_t*)alloc(2400);
  ushort_t* wq_c   = (ushort_t*)alloc(720000);
  ushort_t* bq_c   = (ushort_t*)alloc(1200);
  ushort_t* wk_c   = (ushort_t*)alloc(720000);
  ushort_t* bk_c   = (ushort_t*)alloc(1200);
  ushort_t* sw1_c  = (ushort_t*)alloc(3072);
  ushort_t* sb1_c  = (ushort_t*)alloc(256);
  ushort_t* sw2_c  = (ushort_t*)alloc(3072);
  ushort_t* sb2_c  = (ushort_t*)alloc(256);
  ushort_t* g1w_c  = (ushort_t*)alloc(720000);
  ushort_t* g1b_c  = (ushort_t*)alloc(1200);
  ushort_t* g2w_c  = (ushort_t*)alloc(720000);
  ushort_t* g2b_c  = (ushort_t*)alloc(1200);
  ushort_t* af1_c  = (ushort_t*)alloc(720000);
  ushort_t* af2_c  = (ushort_t*)alloc(720000);
  ushort_t* fcw_c  = (ushort_t*)alloc(7200);
  ushort_t* fcb_c  = (ushort_t*)alloc(256);
  ushort_t* embs  = (ushort_t*)alloc(11010048);
  ushort_t* textout = (ushort_t*)alloc(19660800);
  char* R = alloc(95420416);
  ushort_t* em_c    = (ushort_t*)(R);            // 18 MB; dead after k_embs
  ushort_t* gip_f   = (ushort_t*)(R);            // 41.9 MB [b,t][1280] gate-packed
  ushort_t* gip_b   = (ushort_t*)(R+41943040);   // 41.9 MB; both dead after lstm2
  ushort_t* qh      = (ushort_t*)(R);
  ushort_t* kh      = (ushort_t*)(R+20447232);
  float*    scores  = (float*)(R+40894464);
  ushort_t* adj_sem = (ushort_t*)(R+91226112);
  ushort_t* se_x    = (ushort_t*)(R+40894464);
  ushort_t* Zb      = (ushort_t*)(R+60555264);
  ushort_t* x_sem   = (ushort_t*)(R);
  ushort_t* xb      = (ushort_t*)(R+20447232);
  (void)ws_size; (void)n_in; (void)in_sizes; (void)out_size;

  // --- normalize all float inputs to bf16 (cheap per-block probe, x8 vec) ---
  {
    const int idx[27] = {7,6, 8,9,13,10,14,11,12,15,16,17,18,19,20,21,22,23,24,25,26,27,28,29,30,31,32};
    ushort_t* dl[27] = {em_c,adj_c, pe_c,wihf_c,wihb_c,whhf_c,whhb_c,bihf_c,bhhf_c,bihb_c,bhhb_c,
                        wq_c,bq_c,wk_c,bk_c,sw1_c,sb1_c,sw2_c,sb2_c,
                        g1w_c,g1b_c,g2w_c,g2b_c,af1_c,af2_c,fcw_c,fcb_c};
    const long nl[27] = {9000000L,2097152L, 900,396000,396000,360000,360000,1200,1200,1200,1200,
                         360000,600,360000,600,1536,12,1536,128,
                         360000,600,360000,600,360000,360000,3600,3};
    for (int i=0;i<27;i++){
      long nb = ((nl[i]+7)/8 + 255)/256;
      k_cvt8<<<(int)nb,256,0,stream>>>(d_in[idx[i]], dl[i], nl[i], probe);
    }
  }

  // --- prep ---
  k_lens<<<128,128,0,stream>>>(ti, li, nonpad, text_len, left_len);
  k_aspmean<<<128,128,0,stream>>>(ai, em_c, asp_mean);
  k_embs<<<16384,128,0,stream>>>(ti, pi, aps, em_c, pe_c, asp_mean, embs);
  k_padwih2<<<(1280*336+255)/256,256,0,stream>>>(wihf_c, wihpf);
  k_padwih2<<<(1280*336+255)/256,256,0,stream>>>(wihb_c, wihpb);
  k_padwhh2<<<(1280*320+255)/256,256,0,stream>>>(whhf_c, whh2f);
  k_padwhh2<<<(1280*320+255)/256,256,0,stream>>>(whhb_c, whh2b);
  k_biassum2<<<(1280+255)/256,256,0,stream>>>(bihf_c, bhhf_c, biasgf);
  k_biassum2<<<(1280+255)/256,256,0,stream>>>(bihb_c, bhhb_c, biasgb);
  k_biascvt<<<3,256,0,stream>>>(bq_c, bqf, 600);
  k_biascvt<<<3,256,0,stream>>>(bk_c, bkf, 600);
  k_biascvt<<<3,256,0,stream>>>(g1b_c, gc1bf, 600);
  k_biascvt<<<3,256,0,stream>>>(g2b_c, gc2bf, 600);

  // --- input projections (embs @ Wih2^T + bias), gate-packed cols, MODE 1 ---
  gemm_k<1,1><<<dim3(128,10,1),256,0,stream>>>(16384,1280,336, embs,336,0, wihpf,336,0,
        nullptr, gip_f,1280,0, biasgf,0,nullptr,nullptr);
  gemm_k<1,1><<<dim3(128,10,1),256,0,stream>>>(16384,1280,336, embs,336,0, wihpb,336,0,
        nullptr, gip_b,1280,0, biasgb,0,nullptr,nullptr);

  // --- BiLSTM: LDS-resident Whh, fence-free coherent h exchange ---
  hipMemsetAsync(hbuf, 0, 327680, stream);
  hipMemsetAsync(barr, 0, 2048, stream);
  lstm2_k<<<40,512,0,stream>>>(whh2f, whh2b, gip_f, gip_b, hbuf, barr, textout, text_len);

  // --- q/k projections, head-scattered (dk padded 100->104) ---
  hipMemsetAsync(qh, 0, 20447232, stream);
  hipMemsetAsync(kh, 0, 20447232, stream);
  gemm_k<1,2><<<dim3(128,5,1),256,0,stream>>>(16384,600,600, textout,600,0, wq_c,600,0,
        nullptr, qh,0,0, bqf,0,nullptr,nullptr);
  gemm_k<1,2><<<dim3(128,5,1),256,0,stream>>>(16384,600,600, textout,600,0, wk_c,600,0,
        nullptr, kh,0,0, bkf,0,nullptr,nullptr);

  // --- attention scores + mask ---
  gemm_k<1,3><<<dim3(1,1,768),256,0,stream>>>(128,128,104, qh,104,13312, kh,104,13312,
        scores, nullptr, 128, 16384, nullptr,0,nullptr, nonpad);

  // --- entmax15 (in place) ---
  k_entmax<<<98304,64,0,stream>>>(scores);

  // --- adjacency: head-mean + eye + valid; degree norms ---
  k_adjsem<<<(2097152+255)/256,256,0,stream>>>(scores, nonpad, adj_sem);
  k_dn<<<16384,64,0,stream>>>(adj_sem, dn1);
  k_dn<<<16384,64,0,stream>>>(adj_c, dn2);

  // --- SE #1 + GCN #1 (norm folded: Z = D (A (D * se * X))) ---
  k_mean<<<16384,64,0,stream>>>(textout, ymean);
  k_senet<<<128,128,0,stream>>>(ymean, sw1_c,sb1_c,sw2_c,sb2_c, nonpad, ysoft);
  k_scale2<<<(9830400+255)/256,256,0,stream>>>(textout, ysoft, dn1, se_x);
  gemm_k<0,1><<<dim3(1,5,128),256,0,stream>>>(128,600,128, adj_sem,128,16384, se_x,600,76800,
        nullptr, Zb,600,76800, nullptr,0, dn1, nullptr);
  gemm_k<0,1><<<dim3(128,5,1),256,0,stream>>>(16384,600,600, Zb,600,0, g1w_c,600,0,
        nullptr, x_sem,600,0, gc1bf,1,nullptr,nullptr);

  // --- SE #2 + GCN #2 (uses input adj) ---
  k_mean<<<16384,64,0,stream>>>(x_sem, ymean);
  k_senet<<<128,128,0,stream>>>(ymean, sw1_c,sb1_c,sw2_c,sb2_c, nonpad, ysoft);
  k_scale2<<<(9830400+255)/256,256,0,stream>>>(x_sem, ysoft, dn2, se_x);
  gemm_k<0,1><<<dim3(1,5,128),256,0,stream>>>(128,600,128, adj_c,128,16384, se_x,600,76800,
        nullptr, Zb,600,76800, nullptr,0, dn2, nullptr);
  gemm_k<0,1><<<dim3(128,5,1),256,0,stream>>>(16384,600,600, Zb,600,0, g2w_c,600,0,
        nullptr, xb,600,0, gc2bf,1,nullptr,nullptr);

  // --- biaffine pooling (only row left_len[b] of A1/A2 is ever used) ---
  k_gather<<<128,128,0,stream>>>(xb, left_len, xr);
  k_gather<<<128,128,0,stream>>>(x_sem, left_len, xsr);
  gemm_k<0,1><<<dim3(1,5,1),256,0,stream>>>(128,600,600, xr,600,0, af1_c,600,0,
        nullptr, g1,600,0, nullptr,0,nullptr,nullptr);
  gemm_k<0,1><<<dim3(1,5,1),256,0,stream>>>(128,600,600, xsr,600,0, af2_c,600,0,
        nullptr, g2,600,0, nullptr,0,nullptr,nullptr);
  k_pool<<<128,256,0,stream>>>(g1, x_sem, pooled, 0);
  k_pool<<<128,256,0,stream>>>(g2, xb, pooled, 600);

  // --- final FC (dtype-adaptive output) ---
  k_final<<<128,64,0,stream>>>(pooled, fcw_c, fcb_c, d_out, probe);
}

// Round 7
// 1866.678 us; speedup vs baseline: 1.3165x; 1.2894x over previous
//
#include <hip/hip_runtime.h>

typedef unsigned short ushort_t;
typedef unsigned int   uint_t;
typedef __attribute__((ext_vector_type(8))) short short8;
typedef __attribute__((ext_vector_type(4))) float floatx4;

#define NEGV -1000000000.0f

__device__ __forceinline__ float bf2f(ushort_t h){ return __uint_as_float(((uint_t)h)<<16); }
__device__ __forceinline__ ushort_t f2bf(float f){
  uint_t u = __float_as_uint(f);
  uint_t r = u + 0x7fffu + ((u>>16)&1u);
  return (ushort_t)(r>>16);
}
__device__ __forceinline__ float wredsum(float v){ for(int o=32;o;o>>=1) v += __shfl_xor(v,o); return v; }
__device__ __forceinline__ float wredmax(float v){ for(int o=32;o;o>>=1) v = fmaxf(v,__shfl_xor(v,o)); return v; }
__device__ __forceinline__ int   wredsumi(int v){ for(int o=32;o;o>>=1) v += __shfl_xor(v,o); return v; }

// coherent (cross-XCD) 16B load: bypasses L1/L2 via sc0 sc1 -> reads L3/IF.
__device__ __forceinline__ short8 ldg_cohr(const ushort_t* p){
  short8 r;
  asm volatile("global_load_dwordx4 %0, %1, off sc0 sc1"
               : "=&v"(r) : "v"(p) : "memory");
  return r;
}
// coherent 16B store: write-through past the XCD L2 (sc0 sc1).
__device__ __forceinline__ void stg_b128_cohr(ushort_t* p, short8 v){
  asm volatile("global_store_dwordx4 %0, %1, off sc0 sc1" :: "v"(p), "v"(v) : "memory");
}

// fast transcendentals (error ~1e-6, far below the bf16 rounding in the loop)
__device__ __forceinline__ float fsig(float x){ return 1.f/(1.f+__expf(-x)); }
__device__ __forceinline__ float ftanh(float x){ return 1.f - 2.f/(1.f+__expf(2.f*x)); }

// ---------------------------------------------------------------------------
// dtype-adaptive conversion, vectorized x8. Probe once per block in wave 0.
// ---------------------------------------------------------------------------
__global__ void k_cvt8(const void* __restrict__ src, ushort_t* __restrict__ dst,
                       long n, const ushort_t* __restrict__ probe_src){
  __shared__ int sflag;
  if (threadIdx.x < 64){
    ushort_t u = probe_src[2*threadIdx.x];
    int e = (u>>7)&0xFF;
    int c = (e>=100 && e<=140) ? 1 : 0;
    c = wredsumi(c);
    if (threadIdx.x==0) sflag = (c>32) ? 1 : 0;
  }
  __syncthreads();
  bool isbf = (sflag!=0);
  long base = (blockIdx.x*256L + threadIdx.x)*8;
  if (base>=n) return;
  if (isbf){
    if (base+8<=n) *(uint4*)(dst+base) = *(const uint4*)((const ushort_t*)src+base);
    else for (long i=base;i<n;i++) dst[i]=((const ushort_t*)src)[i];
  } else {
    const float* s = (const float*)src;
    if (base+8<=n){
      float4 v0 = *(const float4*)(s+base);
      float4 v1 = *(const float4*)(s+base+4);
      ushort_t o[8] = {f2bf(v0.x),f2bf(v0.y),f2bf(v0.z),f2bf(v0.w),
                       f2bf(v1.x),f2bf(v1.y),f2bf(v1.z),f2bf(v1.w)};
      *(uint4*)(dst+base) = *(uint4*)o;
    } else {
      for (long i=base;i<n;i++) dst[i]=f2bf(s[i]);
    }
  }
}

__device__ __forceinline__ bool probe_is_bf16(const ushort_t* probe_src){
  int c=0;
  #pragma unroll 1
  for (int i=0;i<64;i++){
    ushort_t u = probe_src[2*i];
    int e = (u>>7)&0xFF;
    c += (e>=100 && e<=140) ? 1 : 0;
  }
  return c>32;
}

// ---------------------------------------------------------------------------
// small prep kernels
// ---------------------------------------------------------------------------
__global__ void k_lens(const int* __restrict__ ti, const int* __restrict__ li,
                       int* __restrict__ nonpad, int* __restrict__ text_len,
                       int* __restrict__ left_len){
  int b = blockIdx.x, t = threadIdx.x;
  nonpad[b*128+t] = (ti[b*128+t]!=0) ? 1 : 0;
  if (t==0){
    int c=0; for (int k2=0;k2<128;k2++) c += (ti[b*128+k2]!=0);
    text_len[b]=c;
    int l=0; for (int k2=0;k2<24;k2++) l += (li[b*24+k2]!=0);
    left_len[b]=l;
  }
}

__global__ void k_aspmean(const int* __restrict__ ai, const ushort_t* __restrict__ em,
                          float* __restrict__ asp_mean){
  int b = blockIdx.x;
  int idxs[5]; int cnt=0;
  for (int a=0;a<5;a++){ int ix=ai[b*5+a]; idxs[a]=ix; cnt += (ix!=0); }
  float inv = 1.0f/(float)cnt;
  for (int d=threadIdx.x; d<300; d+=128){
    float s=0.f;
    for (int a=0;a<5;a++) if (idxs[a]) s += bf2f(em[(long)idxs[a]*300+d]);
    asp_mean[b*300+d] = s*inv;
  }
}

__global__ void k_embs(const int* __restrict__ ti, const int* __restrict__ pi,
                       const int* __restrict__ asp_post,
                       const ushort_t* __restrict__ em, const ushort_t* __restrict__ pe,
                       const float* __restrict__ asp_mean, ushort_t* __restrict__ embs){
  int blk = blockIdx.x;
  int b = blk>>7, t = blk&127;
  int ap = asp_post[b];
  int tix = ti[b*128+t];
  int pix = pi[b*128+t];
  for (int col=threadIdx.x; col<336; col+=128){
    ushort_t v;
    if (col<300) v = (t==ap) ? f2bf(asp_mean[b*300+col]) : em[(long)tix*300+col];
    else if (col<330) v = pe[pix*30 + (col-300)];
    else v = 0;
    embs[(long)(b*128+t)*336 + col] = v;
  }
}

// Wih repack for gate-packed gi: dst[1280][336], row' = j*4+gate
__global__ void k_padwih2(const ushort_t* __restrict__ src, ushort_t* __restrict__ dst){
  int i = blockIdx.x*blockDim.x + threadIdx.x;
  if (i >= 1280*336) return;
  int r = i/336, k = i - r*336;
  int j = r>>2, gate = r&3;
  ushort_t v = 0;
  if (j<300 && k<330) v = src[(long)(gate*300+j)*330 + k];
  dst[i] = v;
}

// Whh repack: dst[1280][320] bf16, row' = j*4 + gate
__global__ void k_padwhh2(const ushort_t* __restrict__ src, ushort_t* __restrict__ dst){
  int i = blockIdx.x*blockDim.x + threadIdx.x;
  if (i >= 1280*320) return;
  int r = i/320, k = i - r*320;
  int j = r>>2, gate = r&3;
  ushort_t v = 0;
  if (j<300 && k<300) v = src[(long)(gate*300+j)*300 + k];
  dst[i] = v;
}

// gate-packed bias: dst[j*4+gate] = bih[gate*300+j] + bhh[gate*300+j]
__global__ void k_biassum2(const ushort_t* __restrict__ a, const ushort_t* __restrict__ b,
                           float* __restrict__ dst){
  int i = blockIdx.x*blockDim.x + threadIdx.x;
  if (i>=1280) return;
  int j = i>>2, g = i&3;
  dst[i] = (j<300) ? (bf2f(a[g*300+j]) + bf2f(b[g*300+j])) : 0.f;
}

__global__ void k_biascvt(const ushort_t* __restrict__ a, float* __restrict__ dst, int n){
  int i = blockIdx.x*blockDim.x + threadIdx.x;
  if (i<n) dst[i] = bf2f(a[i]);
}

// ---------------------------------------------------------------------------
// generic bf16 MFMA GEMM: 128x128 tile, 4 waves (2x2), each 64x64 via 4x4
// frags of 16x16x32.  TB=1: C = A * B^T.  TB=0: C = A * B.
// MODE 1: bf16 store (opt bias/relu/rowscale)
// MODE 2: qk head-scatter bf16 store (bias), T=128, dk=100->104
// MODE 3: f32 store, *0.1 and nonpad column mask (attention scores)
// ---------------------------------------------------------------------------
template<int TB, int MODE>
__global__ __launch_bounds__(256) void gemm_k(
    int M, int N, int K,
    const ushort_t* __restrict__ A, long lda, long sAz,
    const ushort_t* __restrict__ B, long ldb, long sBz,
    float* __restrict__ Cf, ushort_t* __restrict__ Cb, long ldc, long sCz,
    const float* __restrict__ bias, int relu,
    const float* __restrict__ rowscale,
    const int* __restrict__ nonpad)
{
  __shared__ ushort_t As[128*40];
  __shared__ ushort_t Bs[128*40];
  const int tid = threadIdx.x;
  const int m0 = blockIdx.x*128, n0 = blockIdx.y*128;
  const int z = blockIdx.z;
  const ushort_t* Ap = A + (long)z*sAz;
  const ushort_t* Bp = B + (long)z*sBz;
  floatx4 acc[4][4];
  #pragma unroll
  for (int i=0;i<4;i++)
    #pragma unroll
    for (int j=0;j<4;j++){ acc[i][j][0]=0.f; acc[i][j][1]=0.f; acc[i][j][2]=0.f; acc[i][j][3]=0.f; }
  const int w = tid>>6, wm = w&1, wn = w>>1;
  const int lane = tid&63, lr = lane&15, lq = lane>>4;

  for (int k0=0;k0<K;k0+=32){
    #pragma unroll
    for (int c2=0;c2<2;c2++){
      int ch = tid + 256*c2;
      int row = ch>>2, kc = (ch&3)*8;
      int gr = m0+row, gk = k0+kc;
      uint4 v{};
      if (gr<M && gk<K) v = *(const uint4*)(Ap + (long)gr*lda + gk);
      *(uint4*)(&As[row*40+kc]) = v;
    }
    if (TB){
      #pragma unroll
      for (int c2=0;c2<2;c2++){
        int ch = tid + 256*c2;
        int row = ch>>2, kc = (ch&3)*8;
        int gn = n0+row, gk = k0+kc;
        uint4 v{};
        if (gn<N && gk<K) v = *(const uint4*)(Bp + (long)gn*ldb + gk);
        int sw = kc ^ (((row>>3)&3)<<3);
        *(uint4*)(&Bs[row*40+sw]) = v;
      }
    } else {
      #pragma unroll
      for (int c2=0;c2<2;c2++){
        int ch = tid + 256*c2;
        int kk = ch>>4, nc = (ch&15)*8;
        int gk = k0+kk, gn = n0+nc;
        uint4 v{};
        if (gk<K && gn<N) v = *(const uint4*)(Bp + (long)gk*ldb + gn);
        uint_t wsv[4] = {v.x, v.y, v.z, v.w};
        #pragma unroll
        for (int e=0;e<8;e++){
          ushort_t hv = (e&1) ? (ushort_t)(wsv[e>>1]>>16) : (ushort_t)(wsv[e>>1]&0xffffu);
          int n = nc+e;
          int sw = kk ^ (((n>>3)&3)<<3);
          Bs[n*40+sw] = hv;
        }
      }
    }
    __syncthreads();
    short8 af[4], bfv[4];
    #pragma unroll
    for (int i=0;i<4;i++) af[i] = *(const short8*)(&As[(wm*64+i*16+lr)*40 + lq*8]);
    #pragma unroll
    for (int j=0;j<4;j++){
      int n = wn*64+j*16+lr;
      int sw = (lq*8) ^ (((n>>3)&3)<<3);
      bfv[j] = *(const short8*)(&Bs[n*40+sw]);
    }
    #pragma unroll
    for (int i=0;i<4;i++)
      #pragma unroll
      for (int j=0;j<4;j++)
        acc[i][j] = __builtin_amdgcn_mfma_f32_16x16x32_bf16(af[i], bfv[j], acc[i][j], 0,0,0);
    __syncthreads();
  }

  #pragma unroll
  for (int i=0;i<4;i++){
    #pragma unroll
    for (int j=0;j<4;j++){
      #pragma unroll
      for (int r=0;r<4;r++){
        int row = m0 + wm*64 + i*16 + lq*4 + r;
        int col = n0 + wn*64 + j*16 + lr;
        if (row<M && col<N){
          float v = acc[i][j][r];
          if (rowscale) v *= rowscale[(long)z*M + row];
          if (bias) v += bias[col];
          if (relu && v<0.f) v = 0.f;
          if (MODE==1){
            Cb[(long)z*sCz + (long)row*ldc + col] = f2bf(v);
          } else if (MODE==2){
            int b = row>>7, t = row&127;
            int h = col/100, d = col - h*100;
            Cb[ ((long)((b*6+h)*128+t))*104 + d ] = f2bf(v);
          } else if (MODE==3){
            v *= 0.1f;
            if (!nonpad[(z/6)*128 + col]) v = NEGV;
            Cf[(long)z*sCz + (long)row*ldc + col] = v;
          }
        }
      }
    }
  }
}

// ---------------------------------------------------------------------------
// LDS-resident BiLSTM, transaction-minimal cross-XCD h exchange.
// Grid: 40 blocks = 2 dirs x 10 j-slices(32 hidden) x 2 batch-halves(64).
// Block: 512 threads = 8 waves, wave grid 4M x 2N.
// (resubmit of round-6 kernel — container-level infra failure, no data)
//  (1) h stores: epilogue writes the 64x32 h-tile to LDS (hx), then 256
//      threads emit ONE coherent 16B store each (vs 2048 scattered 2B).
//  (2) B loads: stage the unique 40KB h-block ONCE into Blds via coalesced
//      coherent 16B loads; MFMA reads B from LDS (4x less fabric traffic).
// LDS: A 82KB + B 41KB + hx 5KB = 128KB. Barrier: per-step 10-block
// agent-scope atomic (proven rounds 2-5).
// ---------------------------------------------------------------------------
#define ALD 328   // padded LDS row stride for A/B tiles (elements)
#define HXD 40    // padded hx row stride (elements)

__global__ __launch_bounds__(512,1) void lstm2_k(
    const ushort_t* __restrict__ whh2f, const ushort_t* __restrict__ whh2b,
    const ushort_t* __restrict__ gipf, const ushort_t* __restrict__ gipb,
    ushort_t* __restrict__ hbuf,          // [2 dir][2 buf][128 b][320] bf16
    int* __restrict__ barr,               // [4 grp][128 step]
    ushort_t* __restrict__ text_out, const int* __restrict__ text_len)
{
  __shared__ ushort_t Alds[128*ALD];      // 82 KB  (Whh slice)
  __shared__ ushort_t Blds[64*ALD];       // 41 KB  (h of this batch-half)
  __shared__ ushort_t hx[64*HXD];         // 5 KB   (new h tile, gather buf)

  const int bx = blockIdx.x;
  const int slice = bx % 10;
  const int grp   = bx / 10;              // 0..3 = (bh<<1)|dir
  const int dir = grp & 1, bh = grp >> 1;
  const ushort_t* __restrict__ whh = dir ? whh2b : whh2f;
  const ushort_t* __restrict__ gip = dir ? gipb : gipf;
  ushort_t* hb = hbuf + (long)dir * (2L*128*320);
  int* bar = barr + grp*128;

  const int tid = threadIdx.x;
  const int w = tid>>6, lane = tid&63, lr = lane&15, lq = lane>>4;
  const int wm = w&3, wn = w>>2;          // wave grid: 4 Mgroups x 2 Ngroups

  // ---- stage Whh slice -> LDS (once) ----
  for (int i = tid; i < 128*40; i += 512){
    int row = i/40, c = (i-row*40)*8;
    uint4 v = *(const uint4*)(whh + (long)(slice*128+row)*320 + c);
    *(uint4*)(&Alds[row*ALD + c]) = v;
  }

  // ---- lane-owned (jj, b) pairs ----
  int jj_[2], b_[2], bl_[2], tl_[2];
  #pragma unroll
  for (int mi=0;mi<2;mi++) jj_[mi] = slice*32 + wm*8 + mi*4 + lq;
  #pragma unroll
  for (int ni=0;ni<2;ni++){
    bl_[ni] = wn*32 + ni*16 + lr;
    b_[ni]  = bh*64 + bl_[ni];
    tl_[ni] = text_len[b_[ni]];
  }

  const int aoff0 = ((wm*2+0)*16+lr)*ALD + lq*8;
  const int aoff1 = ((wm*2+1)*16+lr)*ALD + lq*8;
  const int boff0 = (wn*32+   lr)*ALD + lq*8;
  const int boff1 = (wn*32+16+lr)*ALD + lq*8;

  float    c_st[2][2];
  ushort_t h_st[2][2];
  #pragma unroll
  for (int mi=0;mi<2;mi++){ c_st[mi][0]=0.f; c_st[mi][1]=0.f; h_st[mi][0]=0; h_st[mi][1]=0; }

  __syncthreads();                        // Alds ready

  for (int s=0; s<128; s++){
    const int t = dir ? (127-s) : s;
    const ushort_t* rb = hb + (long)(s&1)*(128L*320);
    ushort_t*       wb = hb + (long)((s+1)&1)*(128L*320);

    // gi loads (plain; read-once stream); 8B per (jj,b)
    uint2 gp[2][2];
    #pragma unroll
    for (int mi=0;mi<2;mi++)
      #pragma unroll
      for (int ni=0;ni<2;ni++)
        gp[mi][ni] = *(const uint2*)(gip + ((long)(b_[ni]*128 + t))*1280 + jj_[mi]*4);

    // stage h (64 rows x 320 cols = 40KB, contiguous) -> Blds, coherent
    short8 tmp[5]; int ro_[5], ch_[5];
    #pragma unroll
    for (int k=0;k<5;k++){
      int c = tid + k*512;
      int row = c/40, ch = c - row*40;
      ro_[k]=row; ch_[k]=ch;
      tmp[k] = ldg_cohr(rb + (long)(bh*64+row)*320 + ch*8);
    }
    asm volatile("s_waitcnt vmcnt(0)" ::: "memory");
    __builtin_amdgcn_sched_barrier(0);
    #pragma unroll
    for (int k=0;k<5;k++)
      *(short8*)(&Blds[ro_[k]*ALD + ch_[k]*8]) = tmp[k];
    __syncthreads();                      // Blds ready

    // MFMA: A and B fragments from LDS (plain reads; compiler pipelines)
    floatx4 acc[2][2];
    #pragma unroll
    for (int mi=0;mi<2;mi++)
      #pragma unroll
      for (int ni=0;ni<2;ni++){ acc[mi][ni][0]=0.f; acc[mi][ni][1]=0.f; acc[mi][ni][2]=0.f; acc[mi][ni][3]=0.f; }
    #pragma unroll
    for (int kf=0;kf<10;kf++){
      short8 a0 = *(const short8*)(&Alds[aoff0 + kf*32]);
      short8 a1 = *(const short8*)(&Alds[aoff1 + kf*32]);
      short8 b0 = *(const short8*)(&Blds[boff0 + kf*32]);
      short8 b1 = *(const short8*)(&Blds[boff1 + kf*32]);
      acc[0][0] = __builtin_amdgcn_mfma_f32_16x16x32_bf16(a0, b0, acc[0][0], 0,0,0);
      acc[0][1] = __builtin_amdgcn_mfma_f32_16x16x32_bf16(a0, b1, acc[0][1], 0,0,0);
      acc[1][0] = __builtin_amdgcn_mfma_f32_16x16x32_bf16(a1, b0, acc[1][0], 0,0,0);
      acc[1][1] = __builtin_amdgcn_mfma_f32_16x16x32_bf16(a1, b1, acc[1][1], 0,0,0);
    }

    // lane-local cell update; new h tile -> hx (LDS); text_out plain store
    #pragma unroll
    for (int mi=0;mi<2;mi++){
      #pragma unroll
      for (int ni=0;ni<2;ni++){
        float g_i = acc[mi][ni][0] + bf2f((ushort_t)(gp[mi][ni].x & 0xffffu));
        float g_f = acc[mi][ni][1] + bf2f((ushort_t)(gp[mi][ni].x >> 16));
        float g_g = acc[mi][ni][2] + bf2f((ushort_t)(gp[mi][ni].y & 0xffffu));
        float g_o = acc[mi][ni][3] + bf2f((ushort_t)(gp[mi][ni].y >> 16));
        float ig = fsig(g_i);
        float fg = fsig(g_f);
        float gg = ftanh(g_g);
        float og = fsig(g_o);
        float cn = fg*c_st[mi][ni] + ig*gg;
        float hn = og*ftanh(cn);
        bool m = (t < tl_[ni]);
        if (m) c_st[mi][ni] = cn;
        ushort_t hv = m ? f2bf(hn) : h_st[mi][ni];
        h_st[mi][ni] = hv;
        hx[bl_[ni]*HXD + wm*8 + mi*4 + lq] = hv;
        if (jj_[mi] < 300)
          text_out[((long)(b_[ni]*128 + t))*600 + dir*300 + jj_[mi]] = m ? f2bf(hn) : (ushort_t)0;
      }
    }
    __syncthreads();                      // hx complete

    // wide coherent h store: 256 x 16B transactions (vs 2048 x 2B before)
    if (tid < 256){
      int row = tid>>2, jj8 = (tid&3)*8;
      short8 hvv = *(const short8*)(&hx[row*HXD + jj8]);
      stg_b128_cohr(wb + (long)(bh*64+row)*320 + slice*32 + jj8, hvv);
    }
    asm volatile("s_waitcnt vmcnt(0)" ::: "memory");
    __syncthreads();
    if (tid==0){
      __hip_atomic_fetch_add(&bar[s], 1, __ATOMIC_RELAXED, __HIP_MEMORY_SCOPE_AGENT);
      while (__hip_atomic_load(&bar[s], __ATOMIC_RELAXED, __HIP_MEMORY_SCOPE_AGENT) < 10)
        __builtin_amdgcn_s_sleep(1);
    }
    __syncthreads();
  }
}

// ---------------------------------------------------------------------------
// entmax15 over rows of 128 (in-place on f32 scores). 1 wave per row.
// ---------------------------------------------------------------------------
__global__ __launch_bounds__(64) void k_entmax(float* __restrict__ p){
  long row = blockIdx.x;
  float* base = p + row*128;
  __shared__ float xo[128], xs[128], c1[128], c2[128];
  int t = threadIdx.x;
  float a = base[t]*0.5f, b = base[t+64]*0.5f;
  float m = wredmax(fmaxf(a,b));
  a -= m; b -= m;
  xo[t]=a; xo[t+64]=b; xs[t]=a; xs[t+64]=b;
  __syncthreads();
  for (int k2=2;k2<=128;k2<<=1){
    for (int j=k2>>1;j>0;j>>=1){
      int i = ((t & ~(j-1))<<1) | (t & (j-1));
      int ixj = i | j;
      float vi = xs[i], vj = xs[ixj];
      bool blk = (i & k2)==0;
      bool sw = blk ? (vi < vj) : (vi > vj);
      __syncthreads();
      if (sw){ xs[i]=vj; xs[ixj]=vi; }
      __syncthreads();
    }
  }
  c1[t]=xs[t];       c2[t]=xs[t]*xs[t];
  c1[t+64]=xs[t+64]; c2[t+64]=xs[t+64]*xs[t+64];
  __syncthreads();
  for (int d=1; d<128; d<<=1){
    float a1 = (t>=d)     ? c1[t-d]    : 0.f;
    float a2 = (t>=d)     ? c2[t-d]    : 0.f;
    float b1 = (t+64>=d)  ? c1[t+64-d] : 0.f;
    float b2 = (t+64>=d)  ? c2[t+64-d] : 0.f;
    float x1=c1[t], y1=c2[t], x2=c1[t+64], y2=c2[t+64];
    __syncthreads();
    c1[t]=x1+a1; c2[t]=y1+a2; c1[t+64]=x2+b1; c2[t+64]=y2+b2;
    __syncthreads();
  }
  float tau_a, tau_b; int cnt=0;
  {
    float rho = (float)(t+1);
    float mean = c1[t]/rho, msq = c2[t]/rho;
    float ss = rho*(msq-mean*mean);
    float delta = (1.f-ss)/rho;
    tau_a = mean - sqrtf(fmaxf(delta,0.f));
    cnt += (tau_a <= xs[t]) ? 1 : 0;
  }
  {
    float rho = (float)(t+65);
    float mean = c1[t+64]/rho, msq = c2[t+64]/rho;
    float ss = rho*(msq-mean*mean);
    float delta = (1.f-ss)/rho;
    tau_b = mean - sqrtf(fmaxf(delta,0.f));
    cnt += (tau_b <= xs[t+64]) ? 1 : 0;
  }
  __syncthreads();
  c1[t]=tau_a; c1[t+64]=tau_b;
  __syncthreads();
  int support = wredsumi(cnt);
  support = (support<1) ? 1 : ((support>128) ? 128 : support);
  float tau_star = c1[support-1];
  float oa = fmaxf(xo[t]-tau_star, 0.f);
  float ob = fmaxf(xo[t+64]-tau_star, 0.f);
  base[t] = oa*oa; base[t+64] = ob*ob;
}

// ---------------------------------------------------------------------------
__global__ void k_adjsem(const float* __restrict__ p, const int* __restrict__ nonpad,
                         ushort_t* __restrict__ adj_sem){
  int idx = blockIdx.x*blockDim.x + threadIdx.x;
  if (idx >= 128*128*128) return;
  int b = idx>>14, rem = idx&16383, i = rem>>7, j = rem&127;
  float s = 0.f;
  for (int h=0;h<6;h++) s += p[(long)b*98304 + h*16384 + i*128 + j];
  float v = s/6.0f;
  if (i==j) v = 1.0f;
  if (!nonpad[b*128+i]) v = 0.f;
  adj_sem[idx] = f2bf(v);
}

__global__ __launch_bounds__(64) void k_dn(const ushort_t* __restrict__ src, float* __restrict__ dnv){
  long row = blockIdx.x;
  int l = threadIdx.x;
  float s = bf2f(src[row*128+l]) + bf2f(src[row*128+l+64]);
  s = wredsum(s);
  if (l==0) dnv[row] = 1.0f/sqrtf(s+1.0f);
}

__global__ __launch_bounds__(64) void k_mean(const ushort_t* __restrict__ X, float* __restrict__ ymean){
  long row = blockIdx.x;
  float s=0.f;
  for (int d=threadIdx.x; d<600; d+=64) s += bf2f(X[row*600+d]);
  s = wredsum(s);
  if (threadIdx.x==0) ymean[row] = s/600.0f;
}

__global__ void k_senet(const float* __restrict__ ymean,
                        const ushort_t* __restrict__ w1, const ushort_t* __restrict__ b1,
                        const ushort_t* __restrict__ w2, const ushort_t* __restrict__ b2,
                        const int* __restrict__ nonpad, float* __restrict__ ysoft){
  int b = blockIdx.x, t = threadIdx.x;
  __shared__ float yv[128], z1[12], red[128];
  yv[t] = ymean[b*128+t];
  __syncthreads();
  if (t<12){
    float s = bf2f(b1[t]);
    for (int k2=0;k2<128;k2++) s += yv[k2]*bf2f(w1[t*128+k2]);
    z1[t] = fmaxf(s,0.f);
  }
  __syncthreads();
  float v = bf2f(b2[t]);
  for (int r=0;r<12;r++) v += z1[r]*bf2f(w2[t*12+r]);
  if (!nonpad[b*128+t]) v += NEGV;
  red[t]=v; __syncthreads();
  for (int s2=64;s2>0;s2>>=1){ if (t<s2) red[t]=fmaxf(red[t],red[t+s2]); __syncthreads(); }
  float mx = red[0]; __syncthreads();
  float e = expf(v-mx);
  red[t]=e; __syncthreads();
  for (int s2=64;s2>0;s2>>=1){ if (t<s2) red[t]+=red[t+s2]; __syncthreads(); }
  float sm = red[0];
  ysoft[b*128+t] = e/sm;
}

__global__ void k_scale2(const ushort_t* __restrict__ X, const float* __restrict__ ysoft,
                         const float* __restrict__ dnv, ushort_t* __restrict__ out){
  int i = blockIdx.x*blockDim.x + threadIdx.x;
  if (i >= 128*128*600) return;
  int row = i/600;
  out[i] = f2bf(bf2f(X[i])*ysoft[row]*dnv[row]);
}

__global__ void k_gather(const ushort_t* __restrict__ X, const int* __restrict__ left_len,
                         ushort_t* __restrict__ dst){
  int b = blockIdx.x;
  int lb = left_len[b];
  for (int d=threadIdx.x; d<600; d+=128)
    dst[b*600+d] = X[(long)(b*128+lb)*600+d];
}

__global__ __launch_bounds__(256) void k_pool(const ushort_t* __restrict__ g,
                                              const ushort_t* __restrict__ X,
                                              float* __restrict__ pooled, int poff){
  int b = blockIdx.x, tid = threadIdx.x;
  __shared__ float gs[600], sbuf[128], red[256];
  for (int d=tid; d<600; d+=256) gs[d] = bf2f(g[b*600+d]);
  __syncthreads();
  int wv = tid>>6, lane = tid&63;
  for (int jj=wv; jj<128; jj+=4){
    float s=0.f;
    for (int d=lane; d<600; d+=64) s += gs[d]*bf2f(X[(long)(b*128+jj)*600+d]);
    s = wredsum(s);
    if (lane==0) sbuf[jj]=s;
  }
  __syncthreads();
  float v = (tid<128) ? sbuf[tid] : -3.4e38f;
  red[tid]=v; __syncthreads();
  for (int s2=128;s2>0;s2>>=1){ if (tid<s2) red[tid]=fmaxf(red[tid],red[tid+s2]); __syncthreads(); }
  float mx = red[0]; __syncthreads();
  float e = (tid<128) ? expf(v-mx) : 0.f;
  red[tid]=e; __syncthreads();
  for (int s2=128;s2>0;s2>>=1){ if (tid<s2) red[tid]+=red[tid+s2]; __syncthreads(); }
  float sm = red[0]; __syncthreads();
  if (tid<128) sbuf[tid] = e/sm;
  __syncthreads();
  for (int d=tid; d<600; d+=256){
    float acc=0.f;
    for (int j=0;j<128;j++) acc += sbuf[j]*bf2f(X[(long)(b*128+j)*600+d]);
    pooled[(long)b*1200 + poff + d] = acc;
  }
}

__global__ __launch_bounds__(64) void k_final(const float* __restrict__ pooled,
                                              const ushort_t* __restrict__ fcw,
                                              const ushort_t* __restrict__ fcb,
                                              void* __restrict__ out,
                                              const ushort_t* __restrict__ probe_src){
  bool isbf = probe_is_bf16(probe_src);
  int b = blockIdx.x, lane = threadIdx.x;
  for (int p=0;p<3;p++){
    float s=0.f;
    for (int d=lane; d<1200; d+=64) s += pooled[(long)b*1200+d]*bf2f(fcw[d*3+p]);
    s = wredsum(s);
    if (lane==0){
      float r = s + bf2f(fcb[p]);
      if (isbf) ((ushort_t*)out)[b*3+p] = f2bf(r);
      else      ((float*)out)[b*3+p] = r;
    }
  }
}

// ---------------------------------------------------------------------------
extern "C" void kernel_launch(void* const* d_in, const int* in_sizes, int n_in,
                              void* d_out, int out_size, void* d_ws, size_t ws_size,
                              hipStream_t stream) {
  const int*      ti   = (const int*)d_in[0];
  const int*      ai   = (const int*)d_in[1];
  const int*      li   = (const int*)d_in[2];
  const int*      pi   = (const int*)d_in[3];
  const int*      aps  = (const int*)d_in[4];
  const ushort_t* probe = (const ushort_t*)d_in[7];

  char* w = (char*)d_ws; size_t off = 0;
  auto alloc = [&](size_t bytes)->char*{ char* p = w+off; off = (off+bytes+255)&~(size_t)255; return p; };

  int*   text_len = (int*)alloc(512);
  int*   left_len = (int*)alloc(512);
  int*   nonpad   = (int*)alloc(65536);
  float* asp_mean = (float*)alloc(153600);
  float* dn1      = (float*)alloc(65536);
  float* dn2      = (float*)alloc(65536);
  float* ymean    = (float*)alloc(65536);
  float* ysoft    = (float*)alloc(65536);
  ushort_t* wihpf = (ushort_t*)alloc(860160);   // [1280][336] row=j*4+gate
  ushort_t* wihpb = (ushort_t*)alloc(860160);
  ushort_t* whh2f = (ushort_t*)alloc(819200);   // [1280][320] row=j*4+gate
  ushort_t* whh2b = (ushort_t*)alloc(819200);
  ushort_t* hbuf  = (ushort_t*)alloc(327680);   // [2 dir][2 buf][128][320]
  int*      barr  = (int*)alloc(2048);          // [4][128]
  float* biasgf   = (float*)alloc(5120);        // [1280] gate-packed
  float* biasgb   = (float*)alloc(5120);
  float* bqf      = (float*)alloc(2400);
  float* bkf      = (float*)alloc(2400);
  float* gc1bf    = (float*)alloc(2400);
  float* gc2bf    = (float*)alloc(2400);
  ushort_t* g1    = (ushort_t*)alloc(153600);
  ushort_t* g2    = (ushort_t*)alloc(153600);
  ushort_t* xr    = (ushort_t*)alloc(153600);
  ushort_t* xsr   = (ushort_t*)alloc(153600);
  float* pooled   = (float*)alloc(614400);
  ushort_t* adj_c  = (ushort_t*)alloc(4194304);
  ushort_t* pe_c   = (ushort_t*)alloc(2048);
  ushort_t* wihf_c = (ushort_t*)alloc(792000);
  ushort_t* wihb_c = (ushort_t*)alloc(792000);
  ushort_t* whhf_c = (ushort_t*)alloc(720000);
  ushort_t* whhb_c = (ushort_t*)alloc(720000);
  ushort_t* bihf_c = (ushort_t*)alloc(2400);
  ushort_t* bhhf_c = (ushort_t*)alloc(2400);
  ushort_t* bihb_c = (ushort_t*)alloc(2400);
  ushort_t* bhhb_c = (ushort_t*)alloc(2400);
  ushort_t* wq_c   = (ushort_t*)alloc(720000);
  ushort_t* bq_c   = (ushort_t*)alloc(1200);
  ushort_t* wk_c   = (ushort_t*)alloc(720000);
  ushort_t* bk_c   = (ushort_t*)alloc(1200);
  ushort_t* sw1_c  = (ushort_t*)alloc(3072);
  ushort_t* sb1_c  = (ushort_t*)alloc(256);
  ushort_t* sw2_c  = (ushort_t*)alloc(3072);
  ushort_t* sb2_c  = (ushort_t*)alloc(256);
  ushort_t* g1w_c  = (ushort_t*)alloc(720000);
  ushort_t* g1b_c  = (ushort_t*)alloc(1200);
  ushort_t* g2w_c  = (ushort_t*)alloc(720000);
  ushort_t* g2b_c  = (ushort_t*)alloc(1200);
  ushort_t* af1_c  = (ushort_t*)alloc(720000);
  ushort_t* af2_c  = (ushort_t*)alloc(720000);
  ushort_t* fcw_c  = (ushort_t*)alloc(7200);
  ushort_t* fcb_c  = (ushort_t*)alloc(256);
  ushort_t* embs  = (ushort_t*)alloc(11010048);
  ushort_t* textout = (ushort_t*)alloc(19660800);
  char* R = alloc(95420416);
  ushort_t* em_c    = (ushort_t*)(R);            // 18 MB; dead after k_embs
  ushort_t* gip_f   = (ushort_t*)(R);            // 41.9 MB [b,t][1280] gate-packed
  ushort_t* gip_b   = (ushort_t*)(R+41943040);   // 41.9 MB; both dead after lstm2
  ushort_t* qh      = (ushort_t*)(R);
  ushort_t* kh      = (ushort_t*)(R+20447232);
  float*    scores  = (float*)(R+40894464);
  ushort_t* adj_sem = (ushort_t*)(R+91226112);
  ushort_t* se_x    = (ushort_t*)(R+40894464);
  ushort_t* Zb      = (ushort_t*)(R+60555264);
  ushort_t* x_sem   = (ushort_t*)(R);
  ushort_t* xb      = (ushort_t*)(R+20447232);
  (void)ws_size; (void)n_in; (void)in_sizes; (void)out_size;

  // --- normalize all float inputs to bf16 (cheap per-block probe, x8 vec) ---
  {
    const int idx[27] = {7,6, 8,9,13,10,14,11,12,15,16,17,18,19,20,21,22,23,24,25,26,27,28,29,30,31,32};
    ushort_t* dl[27] = {em_c,adj_c, pe_c,wihf_c,wihb_c,whhf_c,whhb_c,bihf_c,bhhf_c,bihb_c,bhhb_c,
                        wq_c,bq_c,wk_c,bk_c,sw1_c,sb1_c,sw2_c,sb2_c,
                        g1w_c,g1b_c,g2w_c,g2b_c,af1_c,af2_c,fcw_c,fcb_c};
    const long nl[27] = {9000000L,2097152L, 900,396000,396000,360000,360000,1200,1200,1200,1200,
                         360000,600,360000,600,1536,12,1536,128,
                         360000,600,360000,600,360000,360000,3600,3};
    for (int i=0;i<27;i++){
      long nb = ((nl[i]+7)/8 + 255)/256;
      k_cvt8<<<(int)nb,256,0,stream>>>(d_in[idx[i]], dl[i], nl[i], probe);
    }
  }

  // --- prep ---
  k_lens<<<128,128,0,stream>>>(ti, li, nonpad, text_len, left_len);
  k_aspmean<<<128,128,0,stream>>>(ai, em_c, asp_mean);
  k_embs<<<16384,128,0,stream>>>(ti, pi, aps, em_c, pe_c, asp_mean, embs);
  k_padwih2<<<(1280*336+255)/256,256,0,stream>>>(wihf_c, wihpf);
  k_padwih2<<<(1280*336+255)/256,256,0,stream>>>(wihb_c, wihpb);
  k_padwhh2<<<(1280*320+255)/256,256,0,stream>>>(whhf_c, whh2f);
  k_padwhh2<<<(1280*320+255)/256,256,0,stream>>>(whhb_c, whh2b);
  k_biassum2<<<(1280+255)/256,256,0,stream>>>(bihf_c, bhhf_c, biasgf);
  k_biassum2<<<(1280+255)/256,256,0,stream>>>(bihb_c, bhhb_c, biasgb);
  k_biascvt<<<3,256,0,stream>>>(bq_c, bqf, 600);
  k_biascvt<<<3,256,0,stream>>>(bk_c, bkf, 600);
  k_biascvt<<<3,256,0,stream>>>(g1b_c, gc1bf, 600);
  k_biascvt<<<3,256,0,stream>>>(g2b_c, gc2bf, 600);

  // --- input projections (embs @ Wih2^T + bias), gate-packed cols, MODE 1 ---
  gemm_k<1,1><<<dim3(128,10,1),256,0,stream>>>(16384,1280,336, embs,336,0, wihpf,336,0,
        nullptr, gip_f,1280,0, biasgf,0,nullptr,nullptr);
  gemm_k<1,1><<<dim3(128,10,1),256,0,stream>>>(16384,1280,336, embs,336,0, wihpb,336,0,
        nullptr, gip_b,1280,0, biasgb,0,nullptr,nullptr);

  // --- BiLSTM: LDS-resident Whh, transaction-minimal h exchange ---
  hipMemsetAsync(hbuf, 0, 327680, stream);
  hipMemsetAsync(barr, 0, 2048, stream);
  lstm2_k<<<40,512,0,stream>>>(whh2f, whh2b, gip_f, gip_b, hbuf, barr, textout, text_len);

  // --- q/k projections, head-scattered (dk padded 100->104) ---
  hipMemsetAsync(qh, 0, 20447232, stream);
  hipMemsetAsync(kh, 0, 20447232, stream);
  gemm_k<1,2><<<dim3(128,5,1),256,0,stream>>>(16384,600,600, textout,600,0, wq_c,600,0,
        nullptr, qh,0,0, bqf,0,nullptr,nullptr);
  gemm_k<1,2><<<dim3(128,5,1),256,0,stream>>>(16384,600,600, textout,600,0, wk_c,600,0,
        nullptr, kh,0,0, bkf,0,nullptr,nullptr);

  // --- attention scores + mask ---
  gemm_k<1,3><<<dim3(1,1,768),256,0,stream>>>(128,128,104, qh,104,13312, kh,104,13312,
        scores, nullptr, 128, 16384, nullptr,0,nullptr, nonpad);

  // --- entmax15 (in place) ---
  k_entmax<<<98304,64,0,stream>>>(scores);

  // --- adjacency: head-mean + eye + valid; degree norms ---
  k_adjsem<<<(2097152+255)/256,256,0,stream>>>(scores, nonpad, adj_sem);
  k_dn<<<16384,64,0,stream>>>(adj_sem, dn1);
  k_dn<<<16384,64,0,stream>>>(adj_c, dn2);

  // --- SE #1 + GCN #1 (norm folded: Z = D (A (D * se * X))) ---
  k_mean<<<16384,64,0,stream>>>(textout, ymean);
  k_senet<<<128,128,0,stream>>>(ymean, sw1_c,sb1_c,sw2_c,sb2_c, nonpad, ysoft);
  k_scale2<<<(9830400+255)/256,256,0,stream>>>(textout, ysoft, dn1, se_x);
  gemm_k<0,1><<<dim3(1,5,128),256,0,stream>>>(128,600,128, adj_sem,128,16384, se_x,600,76800,
        nullptr, Zb,600,76800, nullptr,0, dn1, nullptr);
  gemm_k<0,1><<<dim3(128,5,1),256,0,stream>>>(16384,600,600, Zb,600,0, g1w_c,600,0,
        nullptr, x_sem,600,0, gc1bf,1,nullptr,nullptr);

  // --- SE #2 + GCN #2 (uses input adj) ---
  k_mean<<<16384,64,0,stream>>>(x_sem, ymean);
  k_senet<<<128,128,0,stream>>>(ymean, sw1_c,sb1_c,sw2_c,sb2_c, nonpad, ysoft);
  k_scale2<<<(9830400+255)/256,256,0,stream>>>(x_sem, ysoft, dn2, se_x);
  gemm_k<0,1><<<dim3(1,5,128),256,0,stream>>>(128,600,128, adj_c,128,16384, se_x,600,76800,
        nullptr, Zb,600,76800, nullptr,0, dn2, nullptr);
  gemm_k<0,1><<<dim3(128,5,1),256,0,stream>>>(16384,600,600, Zb,600,0, g2w_c,600,0,
        nullptr, xb,600,0, gc2bf,1,nullptr,nullptr);

  // --- biaffine pooling (only row left_len[b] of A1/A2 is ever used) ---
  k_gather<<<128,128,0,stream>>>(xb, left_len, xr);
  k_gather<<<128,128,0,stream>>>(x_sem, left_len, xsr);
  gemm_k<0,1><<<dim3(1,5,1),256,0,stream>>>(128,600,600, xr,600,0, af1_c,600,0,
        nullptr, g1,600,0, nullptr,0,nullptr,nullptr);
  gemm_k<0,1><<<dim3(1,5,1),256,0,stream>>>(128,600,600, xsr,600,0, af2_c,600,0,
        nullptr, g2,600,0, nullptr,0,nullptr,nullptr);
  k_pool<<<128,256,0,stream>>>(g1, x_sem, pooled, 0);
  k_pool<<<128,256,0,stream>>>(g2, xb, pooled, 600);

  // --- final FC (dtype-adaptive output) ---
  k_final<<<128,64,0,stream>>>(pooled, fcw_c, fcb_c, d_out, probe);
}

// Round 8
// 1864.750 us; speedup vs baseline: 1.3179x; 1.0010x over previous
//
#include <hip/hip_runtime.h>

typedef unsigned short ushort_t;
typedef unsigned int   uint_t;
typedef __attribute__((ext_vector_type(8))) short short8;
typedef __attribute__((ext_vector_type(4))) float floatx4;

#define NEGV -1000000000.0f

__device__ __forceinline__ float bf2f(ushort_t h){ return __uint_as_float(((uint_t)h)<<16); }
__device__ __forceinline__ ushort_t f2bf(float f){
  uint_t u = __float_as_uint(f);
  uint_t r = u + 0x7fffu + ((u>>16)&1u);
  return (ushort_t)(r>>16);
}
__device__ __forceinline__ float wredsum(float v){ for(int o=32;o;o>>=1) v += __shfl_xor(v,o); return v; }
__device__ __forceinline__ float wredmax(float v){ for(int o=32;o;o>>=1) v = fmaxf(v,__shfl_xor(v,o)); return v; }
__device__ __forceinline__ int   wredsumi(int v){ for(int o=32;o;o>>=1) v += __shfl_xor(v,o); return v; }

// coherent (cross-XCD) 16B load: bypasses L1/L2 via sc0 sc1 -> reads L3/IF.
__device__ __forceinline__ short8 ldg_cohr(const ushort_t* p){
  short8 r;
  asm volatile("global_load_dwordx4 %0, %1, off sc0 sc1"
               : "=&v"(r) : "v"(p) : "memory");
  return r;
}
// coherent 16B store: write-through past the XCD L2 (sc0 sc1).
__device__ __forceinline__ void stg_b128_cohr(ushort_t* p, short8 v){
  asm volatile("global_store_dwordx4 %0, %1, off sc0 sc1" :: "v"(p), "v"(v) : "memory");
}

// fast transcendentals (error ~1e-6, far below the bf16 rounding in the loop)
__device__ __forceinline__ float fsig(float x){ return 1.f/(1.f+__expf(-x)); }
__device__ __forceinline__ float ftanh(float x){ return 1.f - 2.f/(1.f+__expf(2.f*x)); }

// ---------------------------------------------------------------------------
// dtype-adaptive conversion, vectorized x8. Probe once per block in wave 0.
// ---------------------------------------------------------------------------
__global__ void k_cvt8(const void* __restrict__ src, ushort_t* __restrict__ dst,
                       long n, const ushort_t* __restrict__ probe_src){
  __shared__ int sflag;
  if (threadIdx.x < 64){
    ushort_t u = probe_src[2*threadIdx.x];
    int e = (u>>7)&0xFF;
    int c = (e>=100 && e<=140) ? 1 : 0;
    c = wredsumi(c);
    if (threadIdx.x==0) sflag = (c>32) ? 1 : 0;
  }
  __syncthreads();
  bool isbf = (sflag!=0);
  long base = (blockIdx.x*256L + threadIdx.x)*8;
  if (base>=n) return;
  if (isbf){
    if (base+8<=n) *(uint4*)(dst+base) = *(const uint4*)((const ushort_t*)src+base);
    else for (long i=base;i<n;i++) dst[i]=((const ushort_t*)src)[i];
  } else {
    const float* s = (const float*)src;
    if (base+8<=n){
      float4 v0 = *(const float4*)(s+base);
      float4 v1 = *(const float4*)(s+base+4);
      ushort_t o[8] = {f2bf(v0.x),f2bf(v0.y),f2bf(v0.z),f2bf(v0.w),
                       f2bf(v1.x),f2bf(v1.y),f2bf(v1.z),f2bf(v1.w)};
      *(uint4*)(dst+base) = *(uint4*)o;
    } else {
      for (long i=base;i<n;i++) dst[i]=f2bf(s[i]);
    }
  }
}

__device__ __forceinline__ bool probe_is_bf16(const ushort_t* probe_src){
  int c=0;
  #pragma unroll 1
  for (int i=0;i<64;i++){
    ushort_t u = probe_src[2*i];
    int e = (u>>7)&0xFF;
    c += (e>=100 && e<=140) ? 1 : 0;
  }
  return c>32;
}

// ---------------------------------------------------------------------------
// small prep kernels
// ---------------------------------------------------------------------------
__global__ void k_lens(const int* __restrict__ ti, const int* __restrict__ li,
                       int* __restrict__ nonpad, int* __restrict__ text_len,
                       int* __restrict__ left_len){
  int b = blockIdx.x, t = threadIdx.x;
  nonpad[b*128+t] = (ti[b*128+t]!=0) ? 1 : 0;
  if (t==0){
    int c=0; for (int k2=0;k2<128;k2++) c += (ti[b*128+k2]!=0);
    text_len[b]=c;
    int l=0; for (int k2=0;k2<24;k2++) l += (li[b*24+k2]!=0);
    left_len[b]=l;
  }
}

__global__ void k_aspmean(const int* __restrict__ ai, const ushort_t* __restrict__ em,
                          float* __restrict__ asp_mean){
  int b = blockIdx.x;
  int idxs[5]; int cnt=0;
  for (int a=0;a<5;a++){ int ix=ai[b*5+a]; idxs[a]=ix; cnt += (ix!=0); }
  float inv = 1.0f/(float)cnt;
  for (int d=threadIdx.x; d<300; d+=128){
    float s=0.f;
    for (int a=0;a<5;a++) if (idxs[a]) s += bf2f(em[(long)idxs[a]*300+d]);
    asp_mean[b*300+d] = s*inv;
  }
}

__global__ void k_embs(const int* __restrict__ ti, const int* __restrict__ pi,
                       const int* __restrict__ asp_post,
                       const ushort_t* __restrict__ em, const ushort_t* __restrict__ pe,
                       const float* __restrict__ asp_mean, ushort_t* __restrict__ embs){
  int blk = blockIdx.x;
  int b = blk>>7, t = blk&127;
  int ap = asp_post[b];
  int tix = ti[b*128+t];
  int pix = pi[b*128+t];
  for (int col=threadIdx.x; col<336; col+=128){
    ushort_t v;
    if (col<300) v = (t==ap) ? f2bf(asp_mean[b*300+col]) : em[(long)tix*300+col];
    else if (col<330) v = pe[pix*30 + (col-300)];
    else v = 0;
    embs[(long)(b*128+t)*336 + col] = v;
  }
}

// Wih repack for gate-packed gi: dst[1280][336], row' = j*4+gate
__global__ void k_padwih2(const ushort_t* __restrict__ src, ushort_t* __restrict__ dst){
  int i = blockIdx.x*blockDim.x + threadIdx.x;
  if (i >= 1280*336) return;
  int r = i/336, k = i - r*336;
  int j = r>>2, gate = r&3;
  ushort_t v = 0;
  if (j<300 && k<330) v = src[(long)(gate*300+j)*330 + k];
  dst[i] = v;
}

// Whh repack: dst[1280][320] bf16, row' = j*4 + gate
__global__ void k_padwhh2(const ushort_t* __restrict__ src, ushort_t* __restrict__ dst){
  int i = blockIdx.x*blockDim.x + threadIdx.x;
  if (i >= 1280*320) return;
  int r = i/320, k = i - r*320;
  int j = r>>2, gate = r&3;
  ushort_t v = 0;
  if (j<300 && k<300) v = src[(long)(gate*300+j)*300 + k];
  dst[i] = v;
}

// gate-packed bias: dst[j*4+gate] = bih[gate*300+j] + bhh[gate*300+j]
__global__ void k_biassum2(const ushort_t* __restrict__ a, const ushort_t* __restrict__ b,
                           float* __restrict__ dst){
  int i = blockIdx.x*blockDim.x + threadIdx.x;
  if (i>=1280) return;
  int j = i>>2, g = i&3;
  dst[i] = (j<300) ? (bf2f(a[g*300+j]) + bf2f(b[g*300+j])) : 0.f;
}

__global__ void k_biascvt(const ushort_t* __restrict__ a, float* __restrict__ dst, int n){
  int i = blockIdx.x*blockDim.x + threadIdx.x;
  if (i<n) dst[i] = bf2f(a[i]);
}

// ---------------------------------------------------------------------------
// generic bf16 MFMA GEMM: 128x128 tile, 4 waves (2x2), each 64x64 via 4x4
// frags of 16x16x32.  TB=1: C = A * B^T.  TB=0: C = A * B.
// MODE 1: bf16 store (opt bias/relu/rowscale)
// MODE 2: qk head-scatter bf16 store (bias), T=128, dk=100->104
// MODE 3: f32 store, *0.1 and nonpad column mask (attention scores)
// ---------------------------------------------------------------------------
template<int TB, int MODE>
__global__ __launch_bounds__(256) void gemm_k(
    int M, int N, int K,
    const ushort_t* __restrict__ A, long lda, long sAz,
    const ushort_t* __restrict__ B, long ldb, long sBz,
    float* __restrict__ Cf, ushort_t* __restrict__ Cb, long ldc, long sCz,
    const float* __restrict__ bias, int relu,
    const float* __restrict__ rowscale,
    const int* __restrict__ nonpad)
{
  __shared__ ushort_t As[128*40];
  __shared__ ushort_t Bs[128*40];
  const int tid = threadIdx.x;
  const int m0 = blockIdx.x*128, n0 = blockIdx.y*128;
  const int z = blockIdx.z;
  const ushort_t* Ap = A + (long)z*sAz;
  const ushort_t* Bp = B + (long)z*sBz;
  floatx4 acc[4][4];
  #pragma unroll
  for (int i=0;i<4;i++)
    #pragma unroll
    for (int j=0;j<4;j++){ acc[i][j][0]=0.f; acc[i][j][1]=0.f; acc[i][j][2]=0.f; acc[i][j][3]=0.f; }
  const int w = tid>>6, wm = w&1, wn = w>>1;
  const int lane = tid&63, lr = lane&15, lq = lane>>4;

  for (int k0=0;k0<K;k0+=32){
    #pragma unroll
    for (int c2=0;c2<2;c2++){
      int ch = tid + 256*c2;
      int row = ch>>2, kc = (ch&3)*8;
      int gr = m0+row, gk = k0+kc;
      uint4 v{};
      if (gr<M && gk<K) v = *(const uint4*)(Ap + (long)gr*lda + gk);
      *(uint4*)(&As[row*40+kc]) = v;
    }
    if (TB){
      #pragma unroll
      for (int c2=0;c2<2;c2++){
        int ch = tid + 256*c2;
        int row = ch>>2, kc = (ch&3)*8;
        int gn = n0+row, gk = k0+kc;
        uint4 v{};
        if (gn<N && gk<K) v = *(const uint4*)(Bp + (long)gn*ldb + gk);
        int sw = kc ^ (((row>>3)&3)<<3);
        *(uint4*)(&Bs[row*40+sw]) = v;
      }
    } else {
      #pragma unroll
      for (int c2=0;c2<2;c2++){
        int ch = tid + 256*c2;
        int kk = ch>>4, nc = (ch&15)*8;
        int gk = k0+kk, gn = n0+nc;
        uint4 v{};
        if (gk<K && gn<N) v = *(const uint4*)(Bp + (long)gk*ldb + gn);
        uint_t wsv[4] = {v.x, v.y, v.z, v.w};
        #pragma unroll
        for (int e=0;e<8;e++){
          ushort_t hv = (e&1) ? (ushort_t)(wsv[e>>1]>>16) : (ushort_t)(wsv[e>>1]&0xffffu);
          int n = nc+e;
          int sw = kk ^ (((n>>3)&3)<<3);
          Bs[n*40+sw] = hv;
        }
      }
    }
    __syncthreads();
    short8 af[4], bfv[4];
    #pragma unroll
    for (int i=0;i<4;i++) af[i] = *(const short8*)(&As[(wm*64+i*16+lr)*40 + lq*8]);
    #pragma unroll
    for (int j=0;j<4;j++){
      int n = wn*64+j*16+lr;
      int sw = (lq*8) ^ (((n>>3)&3)<<3);
      bfv[j] = *(const short8*)(&Bs[n*40+sw]);
    }
    #pragma unroll
    for (int i=0;i<4;i++)
      #pragma unroll
      for (int j=0;j<4;j++)
        acc[i][j] = __builtin_amdgcn_mfma_f32_16x16x32_bf16(af[i], bfv[j], acc[i][j], 0,0,0);
    __syncthreads();
  }

  #pragma unroll
  for (int i=0;i<4;i++){
    #pragma unroll
    for (int j=0;j<4;j++){
      #pragma unroll
      for (int r=0;r<4;r++){
        int row = m0 + wm*64 + i*16 + lq*4 + r;
        int col = n0 + wn*64 + j*16 + lr;
        if (row<M && col<N){
          float v = acc[i][j][r];
          if (rowscale) v *= rowscale[(long)z*M + row];
          if (bias) v += bias[col];
          if (relu && v<0.f) v = 0.f;
          if (MODE==1){
            Cb[(long)z*sCz + (long)row*ldc + col] = f2bf(v);
          } else if (MODE==2){
            int b = row>>7, t = row&127;
            int h = col/100, d = col - h*100;
            Cb[ ((long)((b*6+h)*128+t))*104 + d ] = f2bf(v);
          } else if (MODE==3){
            v *= 0.1f;
            if (!nonpad[(z/6)*128 + col]) v = NEGV;
            Cf[(long)z*sCz + (long)row*ldc + col] = v;
          }
        }
      }
    }
  }
}

// ---------------------------------------------------------------------------
// BiLSTM: A (Whh slice) register-resident + pinned; B (h) staged to LDS;
// software-pipelined gi; counted pre-barrier drain.
// Grid: 40 blocks = 2 dirs x 10 j-slices(32 hidden) x 2 batch-halves(64).
// Block: 512 threads = 8 waves, wave grid 4M x 2N.
// ROUND-8 CHANGES (on top of r7's 706us):
//  (1) A in VGPRs, pinned with asm("+v"): demand is now only ~150 regs
//      (B is in LDS, not asm-pinned 80 regs as in r2-4) -> no spill, no
//      remat. Cuts LDS read traffic in half and kills the Alds bank
//      conflicts (7.0M in r7).
//  (2) gi prefetch for step s+1 issued BEFORE the barrier; the stage-phase
//      vmcnt(0) at s+1 finds them retired -> gi HBM latency off the chain.
//  (3) pre-barrier drain is COUNTED: issue h-store FIRST, then 4 text_out
//      (made unconditional via dump buffer), then 4 gi loads ->
//      s_waitcnt vmcnt(8) retires only the h-store; text_out stores and
//      gi loads stay in flight across the barrier.
// LDS: B 42KB + hx 5KB = 47KB. Barrier: per-step 10-block agent atomic.
// ---------------------------------------------------------------------------
#define BLD 328   // padded LDS row stride for B tile (elements)
#define HXD 40    // padded hx row stride (elements)

__global__ __launch_bounds__(512,1) void lstm2_k(
    const ushort_t* __restrict__ whh2f, const ushort_t* __restrict__ whh2b,
    const ushort_t* __restrict__ gipf, const ushort_t* __restrict__ gipb,
    ushort_t* __restrict__ hbuf,          // [2 dir][2 buf][128 b][320] bf16
    int* __restrict__ barr,               // [4 grp][128 step]
    ushort_t* __restrict__ text_out, const int* __restrict__ text_len,
    ushort_t* __restrict__ dumpb)         // 4KB sink for pad-row stores
{
  __shared__ ushort_t Blds[64*BLD];       // 42 KB  (h of this batch-half)
  __shared__ ushort_t hx[64*HXD];         // 5 KB   (new h tile, gather buf)

  const int bx = blockIdx.x;
  const int slice = bx % 10;
  const int grp   = bx / 10;              // 0..3 = (bh<<1)|dir
  const int dir = grp & 1, bh = grp >> 1;
  const ushort_t* __restrict__ whh = dir ? whh2b : whh2f;
  const ushort_t* __restrict__ gip = dir ? gipb : gipf;
  ushort_t* hb = hbuf + (long)dir * (2L*128*320);
  int* bar = barr + grp*128;

  const int tid = threadIdx.x;
  const int w = tid>>6, lane = tid&63, lr = lane&15, lq = lane>>4;
  const int wm = w&3, wn = w>>2;          // wave grid: 4 Mgroups x 2 Ngroups

  // ---- Whh slice -> registers (once), pinned against remat/evict ----
  short8 a[2][10];
  #pragma unroll
  for (int mi=0;mi<2;mi++){
    const ushort_t* ar = whh + (long)(slice*128 + (wm*2+mi)*16 + lr)*320 + lq*8;
    #pragma unroll
    for (int kf=0;kf<10;kf++) a[mi][kf] = *(const short8*)(ar + kf*32);
  }
  #pragma unroll
  for (int mi=0;mi<2;mi++)
    #pragma unroll
    for (int kf=0;kf<10;kf++)
      asm volatile("" : "+v"(a[mi][kf]));

  // ---- lane-owned (jj, b) pairs ----
  int jj_[2], b_[2], bl_[2], tl_[2];
  #pragma unroll
  for (int mi=0;mi<2;mi++) jj_[mi] = slice*32 + wm*8 + mi*4 + lq;
  #pragma unroll
  for (int ni=0;ni<2;ni++){
    bl_[ni] = wn*32 + ni*16 + lr;
    b_[ni]  = bh*64 + bl_[ni];
    tl_[ni] = text_len[b_[ni]];
  }

  const int boff0 = (wn*32+   lr)*BLD + lq*8;
  const int boff1 = (wn*32+16+lr)*BLD + lq*8;

  float    c_st[2][2];
  ushort_t h_st[2][2];
  #pragma unroll
  for (int mi=0;mi<2;mi++){ c_st[mi][0]=0.f; c_st[mi][1]=0.f; h_st[mi][0]=0; h_st[mi][1]=0; }

  // ---- gi prefetch for step 0 ----
  uint2 gp[2][2];
  {
    int t0 = dir ? 127 : 0;
    #pragma unroll
    for (int mi=0;mi<2;mi++)
      #pragma unroll
      for (int ni=0;ni<2;ni++)
        gp[mi][ni] = *(const uint2*)(gip + ((long)(b_[ni]*128 + t0))*1280 + jj_[mi]*4);
  }

  for (int s=0; s<128; s++){
    const int t = dir ? (127-s) : s;
    const ushort_t* rb = hb + (long)(s&1)*(128L*320);
    ushort_t*       wb = hb + (long)((s+1)&1)*(128L*320);

    // stage h (64 rows x 320 cols = 40KB, contiguous) -> Blds, coherent.
    // The vmcnt(0) here also retires the previous step's text_out stores
    // and this step's gi prefetch (both issued pre-barrier, long done).
    short8 tmp[5]; int ro_[5], ch_[5];
    #pragma unroll
    for (int k=0;k<5;k++){
      int c = tid + k*512;
      int row = c/40, ch = c - row*40;
      ro_[k]=row; ch_[k]=ch;
      tmp[k] = ldg_cohr(rb + (long)(bh*64+row)*320 + ch*8);
    }
    asm volatile("s_waitcnt vmcnt(0)" ::: "memory");
    __builtin_amdgcn_sched_barrier(0);
    #pragma unroll
    for (int k=0;k<5;k++)
      *(short8*)(&Blds[ro_[k]*BLD + ch_[k]*8]) = tmp[k];
    __syncthreads();                      // Blds ready

    // MFMA: A from registers, B from LDS
    floatx4 acc[2][2];
    #pragma unroll
    for (int mi=0;mi<2;mi++)
      #pragma unroll
      for (int ni=0;ni<2;ni++){ acc[mi][ni][0]=0.f; acc[mi][ni][1]=0.f; acc[mi][ni][2]=0.f; acc[mi][ni][3]=0.f; }
    #pragma unroll
    for (int kf=0;kf<10;kf++){
      short8 b0 = *(const short8*)(&Blds[boff0 + kf*32]);
      short8 b1 = *(const short8*)(&Blds[boff1 + kf*32]);
      acc[0][0] = __builtin_amdgcn_mfma_f32_16x16x32_bf16(a[0][kf], b0, acc[0][0], 0,0,0);
      acc[0][1] = __builtin_amdgcn_mfma_f32_16x16x32_bf16(a[0][kf], b1, acc[0][1], 0,0,0);
      acc[1][0] = __builtin_amdgcn_mfma_f32_16x16x32_bf16(a[1][kf], b0, acc[1][0], 0,0,0);
      acc[1][1] = __builtin_amdgcn_mfma_f32_16x16x32_bf16(a[1][kf], b1, acc[1][1], 0,0,0);
    }

    // lane-local cell update; new h -> hx (LDS); stash text_out values
    ushort_t tov[2][2];
    #pragma unroll
    for (int mi=0;mi<2;mi++){
      #pragma unroll
      for (int ni=0;ni<2;ni++){
        float g_i = acc[mi][ni][0] + bf2f((ushort_t)(gp[mi][ni].x & 0xffffu));
        float g_f = acc[mi][ni][1] + bf2f((ushort_t)(gp[mi][ni].x >> 16));
        float g_g = acc[mi][ni][2] + bf2f((ushort_t)(gp[mi][ni].y & 0xffffu));
        float g_o = acc[mi][ni][3] + bf2f((ushort_t)(gp[mi][ni].y >> 16));
        float ig = fsig(g_i);
        float fg = fsig(g_f);
        float gg = ftanh(g_g);
        float og = fsig(g_o);
        float cn = fg*c_st[mi][ni] + ig*gg;
        float hn = og*ftanh(cn);
        bool m = (t < tl_[ni]);
        if (m) c_st[mi][ni] = cn;
        ushort_t hv = m ? f2bf(hn) : h_st[mi][ni];
        h_st[mi][ni] = hv;
        hx[bl_[ni]*HXD + wm*8 + mi*4 + lq] = hv;
        tov[mi][ni] = m ? f2bf(hn) : (ushort_t)0;
      }
    }
    __syncthreads();                      // hx complete

    // (a) h-store FIRST: 256 x 16B coherent transactions
    if (tid < 256){
      int row = tid>>2, jj8 = (tid&3)*8;
      short8 hvv = *(const short8*)(&hx[row*HXD + jj8]);
      stg_b128_cohr(wb + (long)(bh*64+row)*320 + slice*32 + jj8, hvv);
    }
    // (b) text_out stores (uniform count: pad rows go to dump sink)
    #pragma unroll
    for (int mi=0;mi<2;mi++)
      #pragma unroll
      for (int ni=0;ni<2;ni++){
        ushort_t* toa = (jj_[mi] < 300)
          ? &text_out[((long)(b_[ni]*128 + t))*600 + dir*300 + jj_[mi]]
          : &dumpb[tid*4 + mi*2 + ni];
        *toa = tov[mi][ni];
      }
    // (c) gi prefetch for next step
    {
      int tn = dir ? ((s<127) ? (126-s) : 127) : ((s<127) ? (s+1) : 0);
      #pragma unroll
      for (int mi=0;mi<2;mi++)
        #pragma unroll
        for (int ni=0;ni<2;ni++)
          gp[mi][ni] = *(const uint2*)(gip + ((long)(b_[ni]*128 + tn))*1280 + jj_[mi]*4);
    }
    // counted drain: 9 outstanding for tid<256 (h oldest) -> h retired;
    // text_out + gi stay in flight across the barrier.
    asm volatile("s_waitcnt vmcnt(8)" ::: "memory");
    __syncthreads();
    if (tid==0){
      __hip_atomic_fetch_add(&bar[s], 1, __ATOMIC_RELAXED, __HIP_MEMORY_SCOPE_AGENT);
      while (__hip_atomic_load(&bar[s], __ATOMIC_RELAXED, __HIP_MEMORY_SCOPE_AGENT) < 10)
        __builtin_amdgcn_s_sleep(1);
    }
    __syncthreads();
  }
}

// ---------------------------------------------------------------------------
// entmax15 over rows of 128 (in-place on f32 scores). 1 wave per row.
// ---------------------------------------------------------------------------
__global__ __launch_bounds__(64) void k_entmax(float* __restrict__ p){
  long row = blockIdx.x;
  float* base = p + row*128;
  __shared__ float xo[128], xs[128], c1[128], c2[128];
  int t = threadIdx.x;
  float a = base[t]*0.5f, b = base[t+64]*0.5f;
  float m = wredmax(fmaxf(a,b));
  a -= m; b -= m;
  xo[t]=a; xo[t+64]=b; xs[t]=a; xs[t+64]=b;
  __syncthreads();
  for (int k2=2;k2<=128;k2<<=1){
    for (int j=k2>>1;j>0;j>>=1){
      int i = ((t & ~(j-1))<<1) | (t & (j-1));
      int ixj = i | j;
      float vi = xs[i], vj = xs[ixj];
      bool blk = (i & k2)==0;
      bool sw = blk ? (vi < vj) : (vi > vj);
      __syncthreads();
      if (sw){ xs[i]=vj; xs[ixj]=vi; }
      __syncthreads();
    }
  }
  c1[t]=xs[t];       c2[t]=xs[t]*xs[t];
  c1[t+64]=xs[t+64]; c2[t+64]=xs[t+64]*xs[t+64];
  __syncthreads();
  for (int d=1; d<128; d<<=1){
    float a1 = (t>=d)     ? c1[t-d]    : 0.f;
    float a2 = (t>=d)     ? c2[t-d]    : 0.f;
    float b1 = (t+64>=d)  ? c1[t+64-d] : 0.f;
    float b2 = (t+64>=d)  ? c2[t+64-d] : 0.f;
    float x1=c1[t], y1=c2[t], x2=c1[t+64], y2=c2[t+64];
    __syncthreads();
    c1[t]=x1+a1; c2[t]=y1+a2; c1[t+64]=x2+b1; c2[t+64]=y2+b2;
    __syncthreads();
  }
  float tau_a, tau_b; int cnt=0;
  {
    float rho = (float)(t+1);
    float mean = c1[t]/rho, msq = c2[t]/rho;
    float ss = rho*(msq-mean*mean);
    float delta = (1.f-ss)/rho;
    tau_a = mean - sqrtf(fmaxf(delta,0.f));
    cnt += (tau_a <= xs[t]) ? 1 : 0;
  }
  {
    float rho = (float)(t+65);
    float mean = c1[t+64]/rho, msq = c2[t+64]/rho;
    float ss = rho*(msq-mean*mean);
    float delta = (1.f-ss)/rho;
    tau_b = mean - sqrtf(fmaxf(delta,0.f));
    cnt += (tau_b <= xs[t+64]) ? 1 : 0;
  }
  __syncthreads();
  c1[t]=tau_a; c1[t+64]=tau_b;
  __syncthreads();
  int support = wredsumi(cnt);
  support = (support<1) ? 1 : ((support>128) ? 128 : support);
  float tau_star = c1[support-1];
  float oa = fmaxf(xo[t]-tau_star, 0.f);
  float ob = fmaxf(xo[t+64]-tau_star, 0.f);
  base[t] = oa*oa; base[t+64] = ob*ob;
}

// ---------------------------------------------------------------------------
__global__ void k_adjsem(const float* __restrict__ p, const int* __restrict__ nonpad,
                         ushort_t* __restrict__ adj_sem){
  int idx = blockIdx.x*blockDim.x + threadIdx.x;
  if (idx >= 128*128*128) return;
  int b = idx>>14, rem = idx&16383, i = rem>>7, j = rem&127;
  float s = 0.f;
  for (int h=0;h<6;h++) s += p[(long)b*98304 + h*16384 + i*128 + j];
  float v = s/6.0f;
  if (i==j) v = 1.0f;
  if (!nonpad[b*128+i]) v = 0.f;
  adj_sem[idx] = f2bf(v);
}

__global__ __launch_bounds__(64) void k_dn(const ushort_t* __restrict__ src, float* __restrict__ dnv){
  long row = blockIdx.x;
  int l = threadIdx.x;
  float s = bf2f(src[row*128+l]) + bf2f(src[row*128+l+64]);
  s = wredsum(s);
  if (l==0) dnv[row] = 1.0f/sqrtf(s+1.0f);
}

__global__ __launch_bounds__(64) void k_mean(const ushort_t* __restrict__ X, float* __restrict__ ymean){
  long row = blockIdx.x;
  float s=0.f;
  for (int d=threadIdx.x; d<600; d+=64) s += bf2f(X[row*600+d]);
  s = wredsum(s);
  if (threadIdx.x==0) ymean[row] = s/600.0f;
}

__global__ void k_senet(const float* __restrict__ ymean,
                        const ushort_t* __restrict__ w1, const ushort_t* __restrict__ b1,
                        const ushort_t* __restrict__ w2, const ushort_t* __restrict__ b2,
                        const int* __restrict__ nonpad, float* __restrict__ ysoft){
  int b = blockIdx.x, t = threadIdx.x;
  __shared__ float yv[128], z1[12], red[128];
  yv[t] = ymean[b*128+t];
  __syncthreads();
  if (t<12){
    float s = bf2f(b1[t]);
    for (int k2=0;k2<128;k2++) s += yv[k2]*bf2f(w1[t*128+k2]);
    z1[t] = fmaxf(s,0.f);
  }
  __syncthreads();
  float v = bf2f(b2[t]);
  for (int r=0;r<12;r++) v += z1[r]*bf2f(w2[t*12+r]);
  if (!nonpad[b*128+t]) v += NEGV;
  red[t]=v; __syncthreads();
  for (int s2=64;s2>0;s2>>=1){ if (t<s2) red[t]=fmaxf(red[t],red[t+s2]); __syncthreads(); }
  float mx = red[0]; __syncthreads();
  float e = expf(v-mx);
  red[t]=e; __syncthreads();
  for (int s2=64;s2>0;s2>>=1){ if (t<s2) red[t]+=red[t+s2]; __syncthreads(); }
  float sm = red[0];
  ysoft[b*128+t] = e/sm;
}

__global__ void k_scale2(const ushort_t* __restrict__ X, const float* __restrict__ ysoft,
                         const float* __restrict__ dnv, ushort_t* __restrict__ out){
  int i = blockIdx.x*blockDim.x + threadIdx.x;
  if (i >= 128*128*600) return;
  int row = i/600;
  out[i] = f2bf(bf2f(X[i])*ysoft[row]*dnv[row]);
}

__global__ void k_gather(const ushort_t* __restrict__ X, const int* __restrict__ left_len,
                         ushort_t* __restrict__ dst){
  int b = blockIdx.x;
  int lb = left_len[b];
  for (int d=threadIdx.x; d<600; d+=128)
    dst[b*600+d] = X[(long)(b*128+lb)*600+d];
}

__global__ __launch_bounds__(256) void k_pool(const ushort_t* __restrict__ g,
                                              const ushort_t* __restrict__ X,
                                              float* __restrict__ pooled, int poff){
  int b = blockIdx.x, tid = threadIdx.x;
  __shared__ float gs[600], sbuf[128], red[256];
  for (int d=tid; d<600; d+=256) gs[d] = bf2f(g[b*600+d]);
  __syncthreads();
  int wv = tid>>6, lane = tid&63;
  for (int jj=wv; jj<128; jj+=4){
    float s=0.f;
    for (int d=lane; d<600; d+=64) s += gs[d]*bf2f(X[(long)(b*128+jj)*600+d]);
    s = wredsum(s);
    if (lane==0) sbuf[jj]=s;
  }
  __syncthreads();
  float v = (tid<128) ? sbuf[tid] : -3.4e38f;
  red[tid]=v; __syncthreads();
  for (int s2=128;s2>0;s2>>=1){ if (tid<s2) red[tid]=fmaxf(red[tid],red[tid+s2]); __syncthreads(); }
  float mx = red[0]; __syncthreads();
  float e = (tid<128) ? expf(v-mx) : 0.f;
  red[tid]=e; __syncthreads();
  for (int s2=128;s2>0;s2>>=1){ if (tid<s2) red[tid]+=red[tid+s2]; __syncthreads(); }
  float sm = red[0]; __syncthreads();
  if (tid<128) sbuf[tid] = e/sm;
  __syncthreads();
  for (int d=tid; d<600; d+=256){
    float acc=0.f;
    for (int j=0;j<128;j++) acc += sbuf[j]*bf2f(X[(long)(b*128+j)*600+d]);
    pooled[(long)b*1200 + poff + d] = acc;
  }
}

__global__ __launch_bounds__(64) void k_final(const float* __restrict__ pooled,
                                              const ushort_t* __restrict__ fcw,
                                              const ushort_t* __restrict__ fcb,
                                              void* __restrict__ out,
                                              const ushort_t* __restrict__ probe_src){
  bool isbf = probe_is_bf16(probe_src);
  int b = blockIdx.x, lane = threadIdx.x;
  for (int p=0;p<3;p++){
    float s=0.f;
    for (int d=lane; d<1200; d+=64) s += pooled[(long)b*1200+d]*bf2f(fcw[d*3+p]);
    s = wredsum(s);
    if (lane==0){
      float r = s + bf2f(fcb[p]);
      if (isbf) ((ushort_t*)out)[b*3+p] = f2bf(r);
      else      ((float*)out)[b*3+p] = r;
    }
  }
}

// ---------------------------------------------------------------------------
extern "C" void kernel_launch(void* const* d_in, const int* in_sizes, int n_in,
                              void* d_out, int out_size, void* d_ws, size_t ws_size,
                              hipStream_t stream) {
  const int*      ti   = (const int*)d_in[0];
  const int*      ai   = (const int*)d_in[1];
  const int*      li   = (const int*)d_in[2];
  const int*      pi   = (const int*)d_in[3];
  const int*      aps  = (const int*)d_in[4];
  const ushort_t* probe = (const ushort_t*)d_in[7];

  char* w = (char*)d_ws; size_t off = 0;
  auto alloc = [&](size_t bytes)->char*{ char* p = w+off; off = (off+bytes+255)&~(size_t)255; return p; };

  int*   text_len = (int*)alloc(512);
  int*   left_len = (int*)alloc(512);
  int*   nonpad   = (int*)alloc(65536);
  float* asp_mean = (float*)alloc(153600);
  float* dn1      = (float*)alloc(65536);
  float* dn2      = (float*)alloc(65536);
  float* ymean    = (float*)alloc(65536);
  float* ysoft    = (float*)alloc(65536);
  ushort_t* wihpf = (ushort_t*)alloc(860160);   // [1280][336] row=j*4+gate
  ushort_t* wihpb = (ushort_t*)alloc(860160);
  ushort_t* whh2f = (ushort_t*)alloc(819200);   // [1280][320] row=j*4+gate
  ushort_t* whh2b = (ushort_t*)alloc(819200);
  ushort_t* hbuf  = (ushort_t*)alloc(327680);   // [2 dir][2 buf][128][320]
  int*      barr  = (int*)alloc(2048);          // [4][128]
  ushort_t* dumpb = (ushort_t*)alloc(4096);     // pad-row store sink
  float* biasgf   = (float*)alloc(5120);        // [1280] gate-packed
  float* biasgb   = (float*)alloc(5120);
  float* bqf      = (float*)alloc(2400);
  float* bkf      = (float*)alloc(2400);
  float* gc1bf    = (float*)alloc(2400);
  float* gc2bf    = (float*)alloc(2400);
  ushort_t* g1    = (ushort_t*)alloc(153600);
  ushort_t* g2    = (ushort_t*)alloc(153600);
  ushort_t* xr    = (ushort_t*)alloc(153600);
  ushort_t* xsr   = (ushort_t*)alloc(153600);
  float* pooled   = (float*)alloc(614400);
  ushort_t* adj_c  = (ushort_t*)alloc(4194304);
  ushort_t* pe_c   = (ushort_t*)alloc(2048);
  ushort_t* wihf_c = (ushort_t*)alloc(792000);
  ushort_t* wihb_c = (ushort_t*)alloc(792000);
  ushort_t* whhf_c = (ushort_t*)alloc(720000);
  ushort_t* whhb_c = (ushort_t*)alloc(720000);
  ushort_t* bihf_c = (ushort_t*)alloc(2400);
  ushort_t* bhhf_c = (ushort_t*)alloc(2400);
  ushort_t* bihb_c = (ushort_t*)alloc(2400);
  ushort_t* bhhb_c = (ushort_t*)alloc(2400);
  ushort_t* wq_c   = (ushort_t*)alloc(720000);
  ushort_t* bq_c   = (ushort_t*)alloc(1200);
  ushort_t* wk_c   = (ushort_t*)alloc(720000);
  ushort_t* bk_c   = (ushort_t*)alloc(1200);
  ushort_t* sw1_c  = (ushort_t*)alloc(3072);
  ushort_t* sb1_c  = (ushort_t*)alloc(256);
  ushort_t* sw2_c  = (ushort_t*)alloc(3072);
  ushort_t* sb2_c  = (ushort_t*)alloc(256);
  ushort_t* g1w_c  = (ushort_t*)alloc(720000);
  ushort_t* g1b_c  = (ushort_t*)alloc(1200);
  ushort_t* g2w_c  = (ushort_t*)alloc(720000);
  ushort_t* g2b_c  = (ushort_t*)alloc(1200);
  ushort_t* af1_c  = (ushort_t*)alloc(720000);
  ushort_t* af2_c  = (ushort_t*)alloc(720000);
  ushort_t* fcw_c  = (ushort_t*)alloc(7200);
  ushort_t* fcb_c  = (ushort_t*)alloc(256);
  ushort_t* embs  = (ushort_t*)alloc(11010048);
  ushort_t* textout = (ushort_t*)alloc(19660800);
  char* R = alloc(95420416);
  ushort_t* em_c    = (ushort_t*)(R);            // 18 MB; dead after k_embs
  ushort_t* gip_f   = (ushort_t*)(R);            // 41.9 MB [b,t][1280] gate-packed
  ushort_t* gip_b   = (ushort_t*)(R+41943040);   // 41.9 MB; both dead after lstm2
  ushort_t* qh      = (ushort_t*)(R);
  ushort_t* kh      = (ushort_t*)(R+20447232);
  float*    scores  = (float*)(R+40894464);
  ushort_t* adj_sem = (ushort_t*)(R+91226112);
  ushort_t* se_x    = (ushort_t*)(R+40894464);
  ushort_t* Zb      = (ushort_t*)(R+60555264);
  ushort_t* x_sem   = (ushort_t*)(R);
  ushort_t* xb      = (ushort_t*)(R+20447232);
  (void)ws_size; (void)n_in; (void)in_sizes; (void)out_size;

  // --- normalize all float inputs to bf16 (cheap per-block probe, x8 vec) ---
  {
    const int idx[27] = {7,6, 8,9,13,10,14,11,12,15,16,17,18,19,20,21,22,23,24,25,26,27,28,29,30,31,32};
    ushort_t* dl[27] = {em_c,adj_c, pe_c,wihf_c,wihb_c,whhf_c,whhb_c,bihf_c,bhhf_c,bihb_c,bhhb_c,
                        wq_c,bq_c,wk_c,bk_c,sw1_c,sb1_c,sw2_c,sb2_c,
                        g1w_c,g1b_c,g2w_c,g2b_c,af1_c,af2_c,fcw_c,fcb_c};
    const long nl[27] = {9000000L,2097152L, 900,396000,396000,360000,360000,1200,1200,1200,1200,
                         360000,600,360000,600,1536,12,1536,128,
                         360000,600,360000,600,360000,360000,3600,3};
    for (int i=0;i<27;i++){
      long nb = ((nl[i]+7)/8 + 255)/256;
      k_cvt8<<<(int)nb,256,0,stream>>>(d_in[idx[i]], dl[i], nl[i], probe);
    }
  }

  // --- prep ---
  k_lens<<<128,128,0,stream>>>(ti, li, nonpad, text_len, left_len);
  k_aspmean<<<128,128,0,stream>>>(ai, em_c, asp_mean);
  k_embs<<<16384,128,0,stream>>>(ti, pi, aps, em_c, pe_c, asp_mean, embs);
  k_padwih2<<<(1280*336+255)/256,256,0,stream>>>(wihf_c, wihpf);
  k_padwih2<<<(1280*336+255)/256,256,0,stream>>>(wihb_c, wihpb);
  k_padwhh2<<<(1280*320+255)/256,256,0,stream>>>(whhf_c, whh2f);
  k_padwhh2<<<(1280*320+255)/256,256,0,stream>>>(whhb_c, whh2b);
  k_biassum2<<<(1280+255)/256,256,0,stream>>>(bihf_c, bhhf_c, biasgf);
  k_biassum2<<<(1280+255)/256,256,0,stream>>>(bihb_c, bhhb_c, biasgb);
  k_biascvt<<<3,256,0,stream>>>(bq_c, bqf, 600);
  k_biascvt<<<3,256,0,stream>>>(bk_c, bkf, 600);
  k_biascvt<<<3,256,0,stream>>>(g1b_c, gc1bf, 600);
  k_biascvt<<<3,256,0,stream>>>(g2b_c, gc2bf, 600);

  // --- input projections (embs @ Wih2^T + bias), gate-packed cols, MODE 1 ---
  gemm_k<1,1><<<dim3(128,10,1),256,0,stream>>>(16384,1280,336, embs,336,0, wihpf,336,0,
        nullptr, gip_f,1280,0, biasgf,0,nullptr,nullptr);
  gemm_k<1,1><<<dim3(128,10,1),256,0,stream>>>(16384,1280,336, embs,336,0, wihpb,336,0,
        nullptr, gip_b,1280,0, biasgb,0,nullptr,nullptr);

  // --- BiLSTM: reg-A + LDS-B, pipelined gi, counted drain ---
  hipMemsetAsync(hbuf, 0, 327680, stream);
  hipMemsetAsync(barr, 0, 2048, stream);
  lstm2_k<<<40,512,0,stream>>>(whh2f, whh2b, gip_f, gip_b, hbuf, barr, textout, text_len, dumpb);

  // --- q/k projections, head-scattered (dk padded 100->104) ---
  hipMemsetAsync(qh, 0, 20447232, stream);
  hipMemsetAsync(kh, 0, 20447232, stream);
  gemm_k<1,2><<<dim3(128,5,1),256,0,stream>>>(16384,600,600, textout,600,0, wq_c,600,0,
        nullptr, qh,0,0, bqf,0,nullptr,nullptr);
  gemm_k<1,2><<<dim3(128,5,1),256,0,stream>>>(16384,600,600, textout,600,0, wk_c,600,0,
        nullptr, kh,0,0, bkf,0,nullptr,nullptr);

  // --- attention scores + mask ---
  gemm_k<1,3><<<dim3(1,1,768),256,0,stream>>>(128,128,104, qh,104,13312, kh,104,13312,
        scores, nullptr, 128, 16384, nullptr,0,nullptr, nonpad);

  // --- entmax15 (in place) ---
  k_entmax<<<98304,64,0,stream>>>(scores);

  // --- adjacency: head-mean + eye + valid; degree norms ---
  k_adjsem<<<(2097152+255)/256,256,0,stream>>>(scores, nonpad, adj_sem);
  k_dn<<<16384,64,0,stream>>>(adj_sem, dn1);
  k_dn<<<16384,64,0,stream>>>(adj_c, dn2);

  // --- SE #1 + GCN #1 (norm folded: Z = D (A (D * se * X))) ---
  k_mean<<<16384,64,0,stream>>>(textout, ymean);
  k_senet<<<128,128,0,stream>>>(ymean, sw1_c,sb1_c,sw2_c,sb2_c, nonpad, ysoft);
  k_scale2<<<(9830400+255)/256,256,0,stream>>>(textout, ysoft, dn1, se_x);
  gemm_k<0,1><<<dim3(1,5,128),256,0,stream>>>(128,600,128, adj_sem,128,16384, se_x,600,76800,
        nullptr, Zb,600,76800, nullptr,0, dn1, nullptr);
  gemm_k<0,1><<<dim3(128,5,1),256,0,stream>>>(16384,600,600, Zb,600,0, g1w_c,600,0,
        nullptr, x_sem,600,0, gc1bf,1,nullptr,nullptr);

  // --- SE #2 + GCN #2 (uses input adj) ---
  k_mean<<<16384,64,0,stream>>>(x_sem, ymean);
  k_senet<<<128,128,0,stream>>>(ymean, sw1_c,sb1_c,sw2_c,sb2_c, nonpad, ysoft);
  k_scale2<<<(9830400+255)/256,256,0,stream>>>(x_sem, ysoft, dn2, se_x);
  gemm_k<0,1><<<dim3(1,5,128),256,0,stream>>>(128,600,128, adj_c,128,16384, se_x,600,76800,
        nullptr, Zb,600,76800, nullptr,0, dn2, nullptr);
  gemm_k<0,1><<<dim3(128,5,1),256,0,stream>>>(16384,600,600, Zb,600,0, g2w_c,600,0,
        nullptr, xb,600,0, gc2bf,1,nullptr,nullptr);

  // --- biaffine pooling (only row left_len[b] of A1/A2 is ever used) ---
  k_gather<<<128,128,0,stream>>>(xb, left_len, xr);
  k_gather<<<128,128,0,stream>>>(x_sem, left_len, xsr);
  gemm_k<0,1><<<dim3(1,5,1),256,0,stream>>>(128,600,600, xr,600,0, af1_c,600,0,
        nullptr, g1,600,0, nullptr,0,nullptr,nullptr);
  gemm_k<0,1><<<dim3(1,5,1),256,0,stream>>>(128,600,600, xsr,600,0, af2_c,600,0,
        nullptr, g2,600,0, nullptr,0,nullptr,nullptr);
  k_pool<<<128,256,0,stream>>>(g1, x_sem, pooled, 0);
  k_pool<<<128,256,0,stream>>>(g2, xb, pooled, 600);

  // --- final FC (dtype-adaptive output) ---
  k_final<<<128,64,0,stream>>>(pooled, fcw_c, fcb_c, d_out, probe);
}

// Round 9
// 1792.861 us; speedup vs baseline: 1.3707x; 1.0401x over previous
//
#include <hip/hip_runtime.h>

typedef unsigned short ushort_t;
typedef unsigned int   uint_t;
typedef __attribute__((ext_vector_type(8))) short short8;
typedef __attribute__((ext_vector_type(4))) float floatx4;

#define NEGV -1000000000.0f

__device__ __forceinline__ float bf2f(ushort_t h){ return __uint_as_float(((uint_t)h)<<16); }
__device__ __forceinline__ ushort_t f2bf(float f){
  uint_t u = __float_as_uint(f);
  uint_t r = u + 0x7fffu + ((u>>16)&1u);
  return (ushort_t)(r>>16);
}
__device__ __forceinline__ float wredsum(float v){ for(int o=32;o;o>>=1) v += __shfl_xor(v,o); return v; }
__device__ __forceinline__ float wredmax(float v){ for(int o=32;o;o>>=1) v = fmaxf(v,__shfl_xor(v,o)); return v; }
__device__ __forceinline__ int   wredsumi(int v){ for(int o=32;o;o>>=1) v += __shfl_xor(v,o); return v; }

// coherent (cross-XCD) 16B load: bypasses L1/L2 via sc0 sc1 -> reads L3/IF.
__device__ __forceinline__ short8 ldg_cohr(const ushort_t* p){
  short8 r;
  asm volatile("global_load_dwordx4 %0, %1, off sc0 sc1"
               : "=&v"(r) : "v"(p) : "memory");
  return r;
}
// coherent 16B store: write-through past the XCD L2 (sc0 sc1).
__device__ __forceinline__ void stg_b128_cohr(ushort_t* p, short8 v){
  asm volatile("global_store_dwordx4 %0, %1, off sc0 sc1" :: "v"(p), "v"(v) : "memory");
}

// fast transcendentals (error ~1e-6, far below the bf16 rounding in the loop)
__device__ __forceinline__ float fsig(float x){ return 1.f/(1.f+__expf(-x)); }
__device__ __forceinline__ float ftanh(float x){ return 1.f - 2.f/(1.f+__expf(2.f*x)); }

// ---------------------------------------------------------------------------
// dtype-adaptive conversion, vectorized x8. Probe once per block in wave 0.
// ---------------------------------------------------------------------------
__global__ void k_cvt8(const void* __restrict__ src, ushort_t* __restrict__ dst,
                       long n, const ushort_t* __restrict__ probe_src){
  __shared__ int sflag;
  if (threadIdx.x < 64){
    ushort_t u = probe_src[2*threadIdx.x];
    int e = (u>>7)&0xFF;
    int c = (e>=100 && e<=140) ? 1 : 0;
    c = wredsumi(c);
    if (threadIdx.x==0) sflag = (c>32) ? 1 : 0;
  }
  __syncthreads();
  bool isbf = (sflag!=0);
  long base = (blockIdx.x*256L + threadIdx.x)*8;
  if (base>=n) return;
  if (isbf){
    if (base+8<=n) *(uint4*)(dst+base) = *(const uint4*)((const ushort_t*)src+base);
    else for (long i=base;i<n;i++) dst[i]=((const ushort_t*)src)[i];
  } else {
    const float* s = (const float*)src;
    if (base+8<=n){
      float4 v0 = *(const float4*)(s+base);
      float4 v1 = *(const float4*)(s+base+4);
      ushort_t o[8] = {f2bf(v0.x),f2bf(v0.y),f2bf(v0.z),f2bf(v0.w),
                       f2bf(v1.x),f2bf(v1.y),f2bf(v1.z),f2bf(v1.w)};
      *(uint4*)(dst+base) = *(uint4*)o;
    } else {
      for (long i=base;i<n;i++) dst[i]=f2bf(s[i]);
    }
  }
}

// fused multi-array cvt: 25 small arrays in ONE launch (was 25 launches).
struct CvtTab { const void* src[25]; ushort_t* dst[25]; long n[25]; };

__global__ void k_cvt8_multi(CvtTab tab, const ushort_t* __restrict__ probe_src){
  __shared__ int sflag;
  if (threadIdx.x < 64){
    ushort_t u = probe_src[2*threadIdx.x];
    int e = (u>>7)&0xFF;
    int c = (e>=100 && e<=140) ? 1 : 0;
    c = wredsumi(c);
    if (threadIdx.x==0) sflag = (c>32) ? 1 : 0;
  }
  __syncthreads();
  bool isbf = (sflag!=0);
  int ix = blockIdx.y;
  long n = tab.n[ix];
  long base = (blockIdx.x*256L + threadIdx.x)*8;
  if (base>=n) return;
  const void* src = tab.src[ix];
  ushort_t* dst = tab.dst[ix];
  if (isbf){
    if (base+8<=n) *(uint4*)(dst+base) = *(const uint4*)((const ushort_t*)src+base);
    else for (long i=base;i<n;i++) dst[i]=((const ushort_t*)src)[i];
  } else {
    const float* s = (const float*)src;
    if (base+8<=n){
      float4 v0 = *(const float4*)(s+base);
      float4 v1 = *(const float4*)(s+base+4);
      ushort_t o[8] = {f2bf(v0.x),f2bf(v0.y),f2bf(v0.z),f2bf(v0.w),
                       f2bf(v1.x),f2bf(v1.y),f2bf(v1.z),f2bf(v1.w)};
      *(uint4*)(dst+base) = *(uint4*)o;
    } else {
      for (long i=base;i<n;i++) dst[i]=f2bf(s[i]);
    }
  }
}

__device__ __forceinline__ bool probe_is_bf16(const ushort_t* probe_src){
  int c=0;
  #pragma unroll 1
  for (int i=0;i<64;i++){
    ushort_t u = probe_src[2*i];
    int e = (u>>7)&0xFF;
    c += (e>=100 && e<=140) ? 1 : 0;
  }
  return c>32;
}

// ---------------------------------------------------------------------------
// small prep kernels
// ---------------------------------------------------------------------------
__global__ void k_lens(const int* __restrict__ ti, const int* __restrict__ li,
                       int* __restrict__ nonpad, int* __restrict__ text_len,
                       int* __restrict__ left_len){
  int b = blockIdx.x, t = threadIdx.x;
  nonpad[b*128+t] = (ti[b*128+t]!=0) ? 1 : 0;
  if (t==0){
    int c=0; for (int k2=0;k2<128;k2++) c += (ti[b*128+k2]!=0);
    text_len[b]=c;
    int l=0; for (int k2=0;k2<24;k2++) l += (li[b*24+k2]!=0);
    left_len[b]=l;
  }
}

__global__ void k_aspmean(const int* __restrict__ ai, const ushort_t* __restrict__ em,
                          float* __restrict__ asp_mean){
  int b = blockIdx.x;
  int idxs[5]; int cnt=0;
  for (int a=0;a<5;a++){ int ix=ai[b*5+a]; idxs[a]=ix; cnt += (ix!=0); }
  float inv = 1.0f/(float)cnt;
  for (int d=threadIdx.x; d<300; d+=128){
    float s=0.f;
    for (int a=0;a<5;a++) if (idxs[a]) s += bf2f(em[(long)idxs[a]*300+d]);
    asp_mean[b*300+d] = s*inv;
  }
}

__global__ void k_embs(const int* __restrict__ ti, const int* __restrict__ pi,
                       const int* __restrict__ asp_post,
                       const ushort_t* __restrict__ em, const ushort_t* __restrict__ pe,
                       const float* __restrict__ asp_mean, ushort_t* __restrict__ embs){
  int blk = blockIdx.x;
  int b = blk>>7, t = blk&127;
  int ap = asp_post[b];
  int tix = ti[b*128+t];
  int pix = pi[b*128+t];
  for (int col=threadIdx.x; col<336; col+=128){
    ushort_t v;
    if (col<300) v = (t==ap) ? f2bf(asp_mean[b*300+col]) : em[(long)tix*300+col];
    else if (col<330) v = pe[pix*30 + (col-300)];
    else v = 0;
    embs[(long)(b*128+t)*336 + col] = v;
  }
}

// Wih repack for gate-packed gi: dst[1280][336], row' = j*4+gate
__global__ void k_padwih2(const ushort_t* __restrict__ src, ushort_t* __restrict__ dst){
  int i = blockIdx.x*blockDim.x + threadIdx.x;
  if (i >= 1280*336) return;
  int r = i/336, k = i - r*336;
  int j = r>>2, gate = r&3;
  ushort_t v = 0;
  if (j<300 && k<330) v = src[(long)(gate*300+j)*330 + k];
  dst[i] = v;
}

// Whh repack: dst[1280][320] bf16, row' = j*4 + gate
__global__ void k_padwhh2(const ushort_t* __restrict__ src, ushort_t* __restrict__ dst){
  int i = blockIdx.x*blockDim.x + threadIdx.x;
  if (i >= 1280*320) return;
  int r = i/320, k = i - r*320;
  int j = r>>2, gate = r&3;
  ushort_t v = 0;
  if (j<300 && k<300) v = src[(long)(gate*300+j)*300 + k];
  dst[i] = v;
}

// gate-packed bias: dst[j*4+gate] = bih[gate*300+j] + bhh[gate*300+j]
__global__ void k_biassum2(const ushort_t* __restrict__ a, const ushort_t* __restrict__ b,
                           float* __restrict__ dst){
  int i = blockIdx.x*blockDim.x + threadIdx.x;
  if (i>=1280) return;
  int j = i>>2, g = i&3;
  dst[i] = (j<300) ? (bf2f(a[g*300+j]) + bf2f(b[g*300+j])) : 0.f;
}

__global__ void k_biascvt(const ushort_t* __restrict__ a, float* __restrict__ dst, int n){
  int i = blockIdx.x*blockDim.x + threadIdx.x;
  if (i<n) dst[i] = bf2f(a[i]);
}

// zero the pad columns (d=100..103) of qh/kh instead of 40MB of memset
__global__ void k_padzero(ushort_t* __restrict__ qh, ushort_t* __restrict__ kh){
  int i = blockIdx.x*blockDim.x + threadIdx.x;
  if (i >= 98304*4*2) return;
  int half = (i >= 98304*4) ? 1 : 0;
  int j = i - half*98304*4;
  int row = j>>2, c = 100 + (j&3);
  (half ? kh : qh)[(long)row*104 + c] = 0;
}

// ---------------------------------------------------------------------------
// generic bf16 MFMA GEMM: 128x128 tile, 4 waves (2x2), each 64x64 via 4x4
// frags of 16x16x32.  TB=1: C = A * B^T.  TB=0: C = A * B.
// MODE 1: bf16 store (opt bias/relu/rowscale)
// MODE 2: qk head-scatter bf16 store (bias), T=128, dk=100->104
// MODE 3: f32 store, *0.1 and nonpad column mask (attention scores)
// ---------------------------------------------------------------------------
template<int TB, int MODE>
__global__ __launch_bounds__(256) void gemm_k(
    int M, int N, int K,
    const ushort_t* __restrict__ A, long lda, long sAz,
    const ushort_t* __restrict__ B, long ldb, long sBz,
    float* __restrict__ Cf, ushort_t* __restrict__ Cb, long ldc, long sCz,
    const float* __restrict__ bias, int relu,
    const float* __restrict__ rowscale,
    const int* __restrict__ nonpad)
{
  __shared__ ushort_t As[128*40];
  __shared__ ushort_t Bs[128*40];
  const int tid = threadIdx.x;
  const int m0 = blockIdx.x*128, n0 = blockIdx.y*128;
  const int z = blockIdx.z;
  const ushort_t* Ap = A + (long)z*sAz;
  const ushort_t* Bp = B + (long)z*sBz;
  floatx4 acc[4][4];
  #pragma unroll
  for (int i=0;i<4;i++)
    #pragma unroll
    for (int j=0;j<4;j++){ acc[i][j][0]=0.f; acc[i][j][1]=0.f; acc[i][j][2]=0.f; acc[i][j][3]=0.f; }
  const int w = tid>>6, wm = w&1, wn = w>>1;
  const int lane = tid&63, lr = lane&15, lq = lane>>4;

  for (int k0=0;k0<K;k0+=32){
    #pragma unroll
    for (int c2=0;c2<2;c2++){
      int ch = tid + 256*c2;
      int row = ch>>2, kc = (ch&3)*8;
      int gr = m0+row, gk = k0+kc;
      uint4 v{};
      if (gr<M && gk<K) v = *(const uint4*)(Ap + (long)gr*lda + gk);
      *(uint4*)(&As[row*40+kc]) = v;
    }
    if (TB){
      #pragma unroll
      for (int c2=0;c2<2;c2++){
        int ch = tid + 256*c2;
        int row = ch>>2, kc = (ch&3)*8;
        int gn = n0+row, gk = k0+kc;
        uint4 v{};
        if (gn<N && gk<K) v = *(const uint4*)(Bp + (long)gn*ldb + gk);
        int sw = kc ^ (((row>>3)&3)<<3);
        *(uint4*)(&Bs[row*40+sw]) = v;
      }
    } else {
      #pragma unroll
      for (int c2=0;c2<2;c2++){
        int ch = tid + 256*c2;
        int kk = ch>>4, nc = (ch&15)*8;
        int gk = k0+kk, gn = n0+nc;
        uint4 v{};
        if (gk<K && gn<N) v = *(const uint4*)(Bp + (long)gk*ldb + gn);
        uint_t wsv[4] = {v.x, v.y, v.z, v.w};
        #pragma unroll
        for (int e=0;e<8;e++){
          ushort_t hv = (e&1) ? (ushort_t)(wsv[e>>1]>>16) : (ushort_t)(wsv[e>>1]&0xffffu);
          int n = nc+e;
          int sw = kk ^ (((n>>3)&3)<<3);
          Bs[n*40+sw] = hv;
        }
      }
    }
    __syncthreads();
    short8 af[4], bfv[4];
    #pragma unroll
    for (int i=0;i<4;i++) af[i] = *(const short8*)(&As[(wm*64+i*16+lr)*40 + lq*8]);
    #pragma unroll
    for (int j=0;j<4;j++){
      int n = wn*64+j*16+lr;
      int sw = (lq*8) ^ (((n>>3)&3)<<3);
      bfv[j] = *(const short8*)(&Bs[n*40+sw]);
    }
    #pragma unroll
    for (int i=0;i<4;i++)
      #pragma unroll
      for (int j=0;j<4;j++)
        acc[i][j] = __builtin_amdgcn_mfma_f32_16x16x32_bf16(af[i], bfv[j], acc[i][j], 0,0,0);
    __syncthreads();
  }

  #pragma unroll
  for (int i=0;i<4;i++){
    #pragma unroll
    for (int j=0;j<4;j++){
      #pragma unroll
      for (int r=0;r<4;r++){
        int row = m0 + wm*64 + i*16 + lq*4 + r;
        int col = n0 + wn*64 + j*16 + lr;
        if (row<M && col<N){
          float v = acc[i][j][r];
          if (rowscale) v *= rowscale[(long)z*M + row];
          if (bias) v += bias[col];
          if (relu && v<0.f) v = 0.f;
          if (MODE==1){
            Cb[(long)z*sCz + (long)row*ldc + col] = f2bf(v);
          } else if (MODE==2){
            int b = row>>7, t = row&127;
            int h = col/100, d = col - h*100;
            Cb[ ((long)((b*6+h)*128+t))*104 + d ] = f2bf(v);
          } else if (MODE==3){
            v *= 0.1f;
            if (!nonpad[(z/6)*128 + col]) v = NEGV;
            Cf[(long)z*sCz + (long)row*ldc + col] = v;
          }
        }
      }
    }
  }
}

// ---------------------------------------------------------------------------
// BiLSTM: B (h) staged to LDS; software-pipelined gi; counted drain;
// PARALLEL-ARRIVAL flag barrier.
// Grid: 40 blocks = 2 dirs x 10 j-slices(32 hidden) x 2 batch-halves(64).
// Block: 512 threads = 8 waves, wave grid 4M x 2N.
// ROUND-9 CHANGE (r8 null on compute-phase changes -> the invariant 13k
// cy/step must be the barrier ARRIVAL: 10 atomicAdds to ONE dword
// serialize at the coherent point, ~10x RT per step):
//  (1) per-block flag on its OWN 64B cacheline, plain agent-scope store
//      -> arrivals are parallel, no RMW serialization.
//  (2) ALL waves spin on the 10 flags (lanes 0-9, one RT per poll round,
//      __all) -> no tid0-discovery + __syncthreads wake hop; the trailing
//      __syncthreads is dropped (B-stage loads are program-ordered after
//      each wave's own spin exit; intra-block LDS hazards are covered by
//      the pre-flag __syncthreads).
// LDS: B 42KB + hx 5KB = 47KB.
// ---------------------------------------------------------------------------
#define BLD 328   // padded LDS row stride for B tile (elements)
#define HXD 40    // padded hx row stride (elements)

__global__ __launch_bounds__(512,1) void lstm2_k(
    const ushort_t* __restrict__ whh2f, const ushort_t* __restrict__ whh2b,
    const ushort_t* __restrict__ gipf, const ushort_t* __restrict__ gipb,
    ushort_t* __restrict__ hbuf,          // [2 dir][2 buf][128 b][320] bf16
    int* __restrict__ barr,               // [4 grp][10 blk x 16 ints] flags
    ushort_t* __restrict__ text_out, const int* __restrict__ text_len,
    ushort_t* __restrict__ dumpb)         // 4KB sink for pad-row stores
{
  __shared__ ushort_t Blds[64*BLD];       // 42 KB  (h of this batch-half)
  __shared__ ushort_t hx[64*HXD];         // 5 KB   (new h tile, gather buf)

  const int bx = blockIdx.x;
  const int slice = bx % 10;
  const int grp   = bx / 10;              // 0..3 = (bh<<1)|dir
  const int dir = grp & 1, bh = grp >> 1;
  const ushort_t* __restrict__ whh = dir ? whh2b : whh2f;
  const ushort_t* __restrict__ gip = dir ? gipb : gipf;
  ushort_t* hb = hbuf + (long)dir * (2L*128*320);
  int* flg = barr + grp*160;              // 10 flags x 16-int stride (64B)

  const int tid = threadIdx.x;
  const int w = tid>>6, lane = tid&63, lr = lane&15, lq = lane>>4;
  const int wm = w&3, wn = w>>2;          // wave grid: 4 Mgroups x 2 Ngroups

  // ---- Whh slice -> registers (once), pinned against remat/evict ----
  short8 a[2][10];
  #pragma unroll
  for (int mi=0;mi<2;mi++){
    const ushort_t* ar = whh + (long)(slice*128 + (wm*2+mi)*16 + lr)*320 + lq*8;
    #pragma unroll
    for (int kf=0;kf<10;kf++) a[mi][kf] = *(const short8*)(ar + kf*32);
  }
  #pragma unroll
  for (int mi=0;mi<2;mi++)
    #pragma unroll
    for (int kf=0;kf<10;kf++)
      asm volatile("" : "+v"(a[mi][kf]));

  // ---- lane-owned (jj, b) pairs ----
  int jj_[2], b_[2], bl_[2], tl_[2];
  #pragma unroll
  for (int mi=0;mi<2;mi++) jj_[mi] = slice*32 + wm*8 + mi*4 + lq;
  #pragma unroll
  for (int ni=0;ni<2;ni++){
    bl_[ni] = wn*32 + ni*16 + lr;
    b_[ni]  = bh*64 + bl_[ni];
    tl_[ni] = text_len[b_[ni]];
  }

  const int boff0 = (wn*32+   lr)*BLD + lq*8;
  const int boff1 = (wn*32+16+lr)*BLD + lq*8;

  float    c_st[2][2];
  ushort_t h_st[2][2];
  #pragma unroll
  for (int mi=0;mi<2;mi++){ c_st[mi][0]=0.f; c_st[mi][1]=0.f; h_st[mi][0]=0; h_st[mi][1]=0; }

  // ---- gi prefetch for step 0 ----
  uint2 gp[2][2];
  {
    int t0 = dir ? 127 : 0;
    #pragma unroll
    for (int mi=0;mi<2;mi++)
      #pragma unroll
      for (int ni=0;ni<2;ni++)
        gp[mi][ni] = *(const uint2*)(gip + ((long)(b_[ni]*128 + t0))*1280 + jj_[mi]*4);
  }

  for (int s=0; s<128; s++){
    const int t = dir ? (127-s) : s;
    const ushort_t* rb = hb + (long)(s&1)*(128L*320);
    ushort_t*       wb = hb + (long)((s+1)&1)*(128L*320);

    // stage h (64 rows x 320 cols = 40KB, contiguous) -> Blds, coherent.
    short8 tmp[5]; int ro_[5], ch_[5];
    #pragma unroll
    for (int k=0;k<5;k++){
      int c = tid + k*512;
      int row = c/40, ch = c - row*40;
      ro_[k]=row; ch_[k]=ch;
      tmp[k] = ldg_cohr(rb + (long)(bh*64+row)*320 + ch*8);
    }
    asm volatile("s_waitcnt vmcnt(0)" ::: "memory");
    __builtin_amdgcn_sched_barrier(0);
    #pragma unroll
    for (int k=0;k<5;k++)
      *(short8*)(&Blds[ro_[k]*BLD + ch_[k]*8]) = tmp[k];
    __syncthreads();                      // Blds ready

    // MFMA: A from registers, B from LDS
    floatx4 acc[2][2];
    #pragma unroll
    for (int mi=0;mi<2;mi++)
      #pragma unroll
      for (int ni=0;ni<2;ni++){ acc[mi][ni][0]=0.f; acc[mi][ni][1]=0.f; acc[mi][ni][2]=0.f; acc[mi][ni][3]=0.f; }
    #pragma unroll
    for (int kf=0;kf<10;kf++){
      short8 b0 = *(const short8*)(&Blds[boff0 + kf*32]);
      short8 b1 = *(const short8*)(&Blds[boff1 + kf*32]);
      acc[0][0] = __builtin_amdgcn_mfma_f32_16x16x32_bf16(a[0][kf], b0, acc[0][0], 0,0,0);
      acc[0][1] = __builtin_amdgcn_mfma_f32_16x16x32_bf16(a[0][kf], b1, acc[0][1], 0,0,0);
      acc[1][0] = __builtin_amdgcn_mfma_f32_16x16x32_bf16(a[1][kf], b0, acc[1][0], 0,0,0);
      acc[1][1] = __builtin_amdgcn_mfma_f32_16x16x32_bf16(a[1][kf], b1, acc[1][1], 0,0,0);
    }

    // lane-local cell update; new h -> hx (LDS); stash text_out values
    ushort_t tov[2][2];
    #pragma unroll
    for (int mi=0;mi<2;mi++){
      #pragma unroll
      for (int ni=0;ni<2;ni++){
        float g_i = acc[mi][ni][0] + bf2f((ushort_t)(gp[mi][ni].x & 0xffffu));
        float g_f = acc[mi][ni][1] + bf2f((ushort_t)(gp[mi][ni].x >> 16));
        float g_g = acc[mi][ni][2] + bf2f((ushort_t)(gp[mi][ni].y & 0xffffu));
        float g_o = acc[mi][ni][3] + bf2f((ushort_t)(gp[mi][ni].y >> 16));
        float ig = fsig(g_i);
        float fg = fsig(g_f);
        float gg = ftanh(g_g);
        float og = fsig(g_o);
        float cn = fg*c_st[mi][ni] + ig*gg;
        float hn = og*ftanh(cn);
        bool m = (t < tl_[ni]);
        if (m) c_st[mi][ni] = cn;
        ushort_t hv = m ? f2bf(hn) : h_st[mi][ni];
        h_st[mi][ni] = hv;
        hx[bl_[ni]*HXD + wm*8 + mi*4 + lq] = hv;
        tov[mi][ni] = m ? f2bf(hn) : (ushort_t)0;
      }
    }
    __syncthreads();                      // hx complete

    // (a) h-store FIRST: 256 x 16B coherent transactions
    if (tid < 256){
      int row = tid>>2, jj8 = (tid&3)*8;
      short8 hvv = *(const short8*)(&hx[row*HXD + jj8]);
      stg_b128_cohr(wb + (long)(bh*64+row)*320 + slice*32 + jj8, hvv);
    }
    // (b) text_out stores (uniform count: pad rows go to dump sink)
    #pragma unroll
    for (int mi=0;mi<2;mi++)
      #pragma unroll
      for (int ni=0;ni<2;ni++){
        ushort_t* toa = (jj_[mi] < 300)
          ? &text_out[((long)(b_[ni]*128 + t))*600 + dir*300 + jj_[mi]]
          : &dumpb[tid*4 + mi*2 + ni];
        *toa = tov[mi][ni];
      }
    // (c) gi prefetch for next step
    {
      int tn = dir ? ((s<127) ? (126-s) : 127) : ((s<127) ? (s+1) : 0);
      #pragma unroll
      for (int mi=0;mi<2;mi++)
        #pragma unroll
        for (int ni=0;ni<2;ni++)
          gp[mi][ni] = *(const uint2*)(gip + ((long)(b_[ni]*128 + tn))*1280 + jj_[mi]*4);
    }
    // counted drain: h-store (oldest) retired; text_out+gi stay in flight
    asm volatile("s_waitcnt vmcnt(8)" ::: "memory");
    __syncthreads();                      // all h-stores drained

    // parallel arrival: per-block flag, own cacheline, plain agent store
    if (tid==0)
      __hip_atomic_store(&flg[slice*16], s+1, __ATOMIC_RELAXED, __HIP_MEMORY_SCOPE_AGENT);
    // all-wave spin; no trailing __syncthreads (see header comment)
    {
      bool done = false;
      do {
        int f = 0x7fffffff;
        if (lane < 10)
          f = __hip_atomic_load(&flg[lane*16], __ATOMIC_RELAXED, __HIP_MEMORY_SCOPE_AGENT);
        done = (bool)__all(f >= s+1);
        if (!done) __builtin_amdgcn_s_sleep(1);
      } while(!done);
    }
  }
}

// ---------------------------------------------------------------------------
// entmax15 over rows of 128 (in-place on f32 scores). 1 wave per row.
// ---------------------------------------------------------------------------
__global__ __launch_bounds__(64) void k_entmax(float* __restrict__ p){
  long row = blockIdx.x;
  float* base = p + row*128;
  __shared__ float xo[128], xs[128], c1[128], c2[128];
  int t = threadIdx.x;
  float a = base[t]*0.5f, b = base[t+64]*0.5f;
  float m = wredmax(fmaxf(a,b));
  a -= m; b -= m;
  xo[t]=a; xo[t+64]=b; xs[t]=a; xs[t+64]=b;
  __syncthreads();
  for (int k2=2;k2<=128;k2<<=1){
    for (int j=k2>>1;j>0;j>>=1){
      int i = ((t & ~(j-1))<<1) | (t & (j-1));
      int ixj = i | j;
      float vi = xs[i], vj = xs[ixj];
      bool blk = (i & k2)==0;
      bool sw = blk ? (vi < vj) : (vi > vj);
      __syncthreads();
      if (sw){ xs[i]=vj; xs[ixj]=vi; }
      __syncthreads();
    }
  }
  c1[t]=xs[t];       c2[t]=xs[t]*xs[t];
  c1[t+64]=xs[t+64]; c2[t+64]=xs[t+64]*xs[t+64];
  __syncthreads();
  for (int d=1; d<128; d<<=1){
    float a1 = (t>=d)     ? c1[t-d]    : 0.f;
    float a2 = (t>=d)     ? c2[t-d]    : 0.f;
    float b1 = (t+64>=d)  ? c1[t+64-d] : 0.f;
    float b2 = (t+64>=d)  ? c2[t+64-d] : 0.f;
    float x1=c1[t], y1=c2[t], x2=c1[t+64], y2=c2[t+64];
    __syncthreads();
    c1[t]=x1+a1; c2[t]=y1+a2; c1[t+64]=x2+b1; c2[t+64]=y2+b2;
    __syncthreads();
  }
  float tau_a, tau_b; int cnt=0;
  {
    float rho = (float)(t+1);
    float mean = c1[t]/rho, msq = c2[t]/rho;
    float ss = rho*(msq-mean*mean);
    float delta = (1.f-ss)/rho;
    tau_a = mean - sqrtf(fmaxf(delta,0.f));
    cnt += (tau_a <= xs[t]) ? 1 : 0;
  }
  {
    float rho = (float)(t+65);
    float mean = c1[t+64]/rho, msq = c2[t+64]/rho;
    float ss = rho*(msq-mean*mean);
    float delta = (1.f-ss)/rho;
    tau_b = mean - sqrtf(fmaxf(delta,0.f));
    cnt += (tau_b <= xs[t+64]) ? 1 : 0;
  }
  __syncthreads();
  c1[t]=tau_a; c1[t+64]=tau_b;
  __syncthreads();
  int support = wredsumi(cnt);
  support = (support<1) ? 1 : ((support>128) ? 128 : support);
  float tau_star = c1[support-1];
  float oa = fmaxf(xo[t]-tau_star, 0.f);
  float ob = fmaxf(xo[t+64]-tau_star, 0.f);
  base[t] = oa*oa; base[t+64] = ob*ob;
}

// ---------------------------------------------------------------------------
__global__ void k_adjsem(const float* __restrict__ p, const int* __restrict__ nonpad,
                         ushort_t* __restrict__ adj_sem){
  int idx = blockIdx.x*blockDim.x + threadIdx.x;
  if (idx >= 128*128*128) return;
  int b = idx>>14, rem = idx&16383, i = rem>>7, j = rem&127;
  float s = 0.f;
  for (int h=0;h<6;h++) s += p[(long)b*98304 + h*16384 + i*128 + j];
  float v = s/6.0f;
  if (i==j) v = 1.0f;
  if (!nonpad[b*128+i]) v = 0.f;
  adj_sem[idx] = f2bf(v);
}

__global__ __launch_bounds__(64) void k_dn(const ushort_t* __restrict__ src, float* __restrict__ dnv){
  long row = blockIdx.x;
  int l = threadIdx.x;
  float s = bf2f(src[row*128+l]) + bf2f(src[row*128+l+64]);
  s = wredsum(s);
  if (l==0) dnv[row] = 1.0f/sqrtf(s+1.0f);
}

__global__ __launch_bounds__(64) void k_mean(const ushort_t* __restrict__ X, float* __restrict__ ymean){
  long row = blockIdx.x;
  float s=0.f;
  for (int d=threadIdx.x; d<600; d+=64) s += bf2f(X[row*600+d]);
  s = wredsum(s);
  if (threadIdx.x==0) ymean[row] = s/600.0f;
}

__global__ void k_senet(const float* __restrict__ ymean,
                        const ushort_t* __restrict__ w1, const ushort_t* __restrict__ b1,
                        const ushort_t* __restrict__ w2, const ushort_t* __restrict__ b2,
                        const int* __restrict__ nonpad, float* __restrict__ ysoft){
  int b = blockIdx.x, t = threadIdx.x;
  __shared__ float yv[128], z1[12], red[128];
  yv[t] = ymean[b*128+t];
  __syncthreads();
  if (t<12){
    float s = bf2f(b1[t]);
    for (int k2=0;k2<128;k2++) s += yv[k2]*bf2f(w1[t*128+k2]);
    z1[t] = fmaxf(s,0.f);
  }
  __syncthreads();
  float v = bf2f(b2[t]);
  for (int r=0;r<12;r++) v += z1[r]*bf2f(w2[t*12+r]);
  if (!nonpad[b*128+t]) v += NEGV;
  red[t]=v; __syncthreads();
  for (int s2=64;s2>0;s2>>=1){ if (t<s2) red[t]=fmaxf(red[t],red[t+s2]); __syncthreads(); }
  float mx = red[0]; __syncthreads();
  float e = expf(v-mx);
  red[t]=e; __syncthreads();
  for (int s2=64;s2>0;s2>>=1){ if (t<s2) red[t]+=red[t+s2]; __syncthreads(); }
  float sm = red[0];
  ysoft[b*128+t] = e/sm;
}

__global__ void k_scale2(const ushort_t* __restrict__ X, const float* __restrict__ ysoft,
                         const float* __restrict__ dnv, ushort_t* __restrict__ out){
  int i = blockIdx.x*blockDim.x + threadIdx.x;
  if (i >= 128*128*600) return;
  int row = i/600;
  out[i] = f2bf(bf2f(X[i])*ysoft[row]*dnv[row]);
}

__global__ void k_gather(const ushort_t* __restrict__ X, const int* __restrict__ left_len,
                         ushort_t* __restrict__ dst){
  int b = blockIdx.x;
  int lb = left_len[b];
  for (int d=threadIdx.x; d<600; d+=128)
    dst[b*600+d] = X[(long)(b*128+lb)*600+d];
}

__global__ __launch_bounds__(256) void k_pool(const ushort_t* __restrict__ g,
                                              const ushort_t* __restrict__ X,
                                              float* __restrict__ pooled, int poff){
  int b = blockIdx.x, tid = threadIdx.x;
  __shared__ float gs[600], sbuf[128], red[256];
  for (int d=tid; d<600; d+=256) gs[d] = bf2f(g[b*600+d]);
  __syncthreads();
  int wv = tid>>6, lane = tid&63;
  for (int jj=wv; jj<128; jj+=4){
    float s=0.f;
    for (int d=lane; d<600; d+=64) s += gs[d]*bf2f(X[(long)(b*128+jj)*600+d]);
    s = wredsum(s);
    if (lane==0) sbuf[jj]=s;
  }
  __syncthreads();
  float v = (tid<128) ? sbuf[tid] : -3.4e38f;
  red[tid]=v; __syncthreads();
  for (int s2=128;s2>0;s2>>=1){ if (tid<s2) red[tid]=fmaxf(red[tid],red[tid+s2]); __syncthreads(); }
  float mx = red[0]; __syncthreads();
  float e = (tid<128) ? expf(v-mx) : 0.f;
  red[tid]=e; __syncthreads();
  for (int s2=128;s2>0;s2>>=1){ if (tid<s2) red[tid]+=red[tid+s2]; __syncthreads(); }
  float sm = red[0]; __syncthreads();
  if (tid<128) sbuf[tid] = e/sm;
  __syncthreads();
  for (int d=tid; d<600; d+=256){
    float acc=0.f;
    for (int j=0;j<128;j++) acc += sbuf[j]*bf2f(X[(long)(b*128+j)*600+d]);
    pooled[(long)b*1200 + poff + d] = acc;
  }
}

__global__ __launch_bounds__(64) void k_final(const float* __restrict__ pooled,
                                              const ushort_t* __restrict__ fcw,
                                              const ushort_t* __restrict__ fcb,
                                              void* __restrict__ out,
                                              const ushort_t* __restrict__ probe_src){
  bool isbf = probe_is_bf16(probe_src);
  int b = blockIdx.x, lane = threadIdx.x;
  for (int p=0;p<3;p++){
    float s=0.f;
    for (int d=lane; d<1200; d+=64) s += pooled[(long)b*1200+d]*bf2f(fcw[d*3+p]);
    s = wredsum(s);
    if (lane==0){
      float r = s + bf2f(fcb[p]);
      if (isbf) ((ushort_t*)out)[b*3+p] = f2bf(r);
      else      ((float*)out)[b*3+p] = r;
    }
  }
}

// ---------------------------------------------------------------------------
extern "C" void kernel_launch(void* const* d_in, const int* in_sizes, int n_in,
                              void* d_out, int out_size, void* d_ws, size_t ws_size,
                              hipStream_t stream) {
  const int*      ti   = (const int*)d_in[0];
  const int*      ai   = (const int*)d_in[1];
  const int*      li   = (const int*)d_in[2];
  const int*      pi   = (const int*)d_in[3];
  const int*      aps  = (const int*)d_in[4];
  const ushort_t* probe = (const ushort_t*)d_in[7];

  char* w = (char*)d_ws; size_t off = 0;
  auto alloc = [&](size_t bytes)->char*{ char* p = w+off; off = (off+bytes+255)&~(size_t)255; return p; };

  int*   text_len = (int*)alloc(512);
  int*   left_len = (int*)alloc(512);
  int*   nonpad   = (int*)alloc(65536);
  float* asp_mean = (float*)alloc(153600);
  float* dn1      = (float*)alloc(65536);
  float* dn2      = (float*)alloc(65536);
  float* ymean    = (float*)alloc(65536);
  float* ysoft    = (float*)alloc(65536);
  ushort_t* wihpf = (ushort_t*)alloc(860160);   // [1280][336] row=j*4+gate
  ushort_t* wihpb = (ushort_t*)alloc(860160);
  ushort_t* whh2f = (ushort_t*)alloc(819200);   // [1280][320] row=j*4+gate
  ushort_t* whh2b = (ushort_t*)alloc(819200);
  ushort_t* hbuf  = (ushort_t*)alloc(327680);   // [2 dir][2 buf][128][320]
  int*      barr  = (int*)alloc(4096);          // [4 grp][10 x 16-int] flags
  ushort_t* dumpb = (ushort_t*)alloc(4096);     // pad-row store sink
  float* biasgf   = (float*)alloc(5120);        // [1280] gate-packed
  float* biasgb   = (float*)alloc(5120);
  float* bqf      = (float*)alloc(2400);
  float* bkf      = (float*)alloc(2400);
  float* gc1bf    = (float*)alloc(2400);
  float* gc2bf    = (float*)alloc(2400);
  ushort_t* g1    = (ushort_t*)alloc(153600);
  ushort_t* g2    = (ushort_t*)alloc(153600);
  ushort_t* xr    = (ushort_t*)alloc(153600);
  ushort_t* xsr   = (ushort_t*)alloc(153600);
  float* pooled   = (float*)alloc(614400);
  ushort_t* adj_c  = (ushort_t*)alloc(4194304);
  ushort_t* pe_c   = (ushort_t*)alloc(2048);
  ushort_t* wihf_c = (ushort_t*)alloc(792000);
  ushort_t* wihb_c = (ushort_t*)alloc(792000);
  ushort_t* whhf_c = (ushort_t*)alloc(720000);
  ushort_t* whhb_c = (ushort_t*)alloc(720000);
  ushort_t* bihf_c = (ushort_t*)alloc(2400);
  ushort_t* bhhf_c = (ushort_t*)alloc(2400);
  ushort_t* bihb_c = (ushort_t*)alloc(2400);
  ushort_t* bhhb_c = (ushort_t*)alloc(2400);
  ushort_t* wq_c   = (ushort_t*)alloc(720000);
  ushort_t* bq_c   = (ushort_t*)alloc(1200);
  ushort_t* wk_c   = (ushort_t*)alloc(720000);
  ushort_t* bk_c   = (ushort_t*)alloc(1200);
  ushort_t* sw1_c  = (ushort_t*)alloc(3072);
  ushort_t* sb1_c  = (ushort_t*)alloc(256);
  ushort_t* sw2_c  = (ushort_t*)alloc(3072);
  ushort_t* sb2_c  = (ushort_t*)alloc(256);
  ushort_t* g1w_c  = (ushort_t*)alloc(720000);
  ushort_t* g1b_c  = (ushort_t*)alloc(1200);
  ushort_t* g2w_c  = (ushort_t*)alloc(720000);
  ushort_t* g2b_c  = (ushort_t*)alloc(1200);
  ushort_t* af1_c  = (ushort_t*)alloc(720000);
  ushort_t* af2_c  = (ushort_t*)alloc(720000);
  ushort_t* fcw_c  = (ushort_t*)alloc(7200);
  ushort_t* fcb_c  = (ushort_t*)alloc(256);
  ushort_t* embs  = (ushort_t*)alloc(11010048);
  ushort_t* textout = (ushort_t*)alloc(19660800);
  char* R = alloc(95420416);
  ushort_t* em_c    = (ushort_t*)(R);            // 18 MB; dead after k_embs
  ushort_t* gip_f   = (ushort_t*)(R);            // 41.9 MB [b,t][1280] gate-packed
  ushort_t* gip_b   = (ushort_t*)(R+41943040);   // 41.9 MB; both dead after lstm2
  ushort_t* qh      = (ushort_t*)(R);
  ushort_t* kh      = (ushort_t*)(R+20447232);
  float*    scores  = (float*)(R+40894464);
  ushort_t* adj_sem = (ushort_t*)(R+91226112);
  ushort_t* se_x    = (ushort_t*)(R+40894464);
  ushort_t* Zb      = (ushort_t*)(R+60555264);
  ushort_t* x_sem   = (ushort_t*)(R);
  ushort_t* xb      = (ushort_t*)(R+20447232);
  (void)ws_size; (void)n_in; (void)in_sizes; (void)out_size;

  // --- normalize float inputs to bf16: 2 big launches + 1 fused launch ---
  k_cvt8<<<(9000000/8+255)/256,256,0,stream>>>(d_in[7], em_c, 9000000L, probe);
  k_cvt8<<<(2097152/8+255)/256,256,0,stream>>>(d_in[6], adj_c, 2097152L, probe);
  {
    CvtTab tab;
    const int idx[25] = {8,9,13,10,14,11,12,15,16,17,18,19,20,21,22,23,24,25,26,27,28,29,30,31,32};
    ushort_t* dl[25] = {pe_c,wihf_c,wihb_c,whhf_c,whhb_c,bihf_c,bhhf_c,bihb_c,bhhb_c,
                        wq_c,bq_c,wk_c,bk_c,sw1_c,sb1_c,sw2_c,sb2_c,
                        g1w_c,g1b_c,g2w_c,g2b_c,af1_c,af2_c,fcw_c,fcb_c};
    const long nl[25] = {900,396000,396000,360000,360000,1200,1200,1200,1200,
                         360000,600,360000,600,1536,12,1536,128,
                         360000,600,360000,600,360000,360000,3600,3};
    for (int i=0;i<25;i++){ tab.src[i]=d_in[idx[i]]; tab.dst[i]=dl[i]; tab.n[i]=nl[i]; }
    k_cvt8_multi<<<dim3(194,25),256,0,stream>>>(tab, probe);
  }

  // --- prep ---
  k_lens<<<128,128,0,stream>>>(ti, li, nonpad, text_len, left_len);
  k_aspmean<<<128,128,0,stream>>>(ai, em_c, asp_mean);
  k_embs<<<16384,128,0,stream>>>(ti, pi, aps, em_c, pe_c, asp_mean, embs);
  k_padwih2<<<(1280*336+255)/256,256,0,stream>>>(wihf_c, wihpf);
  k_padwih2<<<(1280*336+255)/256,256,0,stream>>>(wihb_c, wihpb);
  k_padwhh2<<<(1280*320+255)/256,256,0,stream>>>(whhf_c, whh2f);
  k_padwhh2<<<(1280*320+255)/256,256,0,stream>>>(whhb_c, whh2b);
  k_biassum2<<<(1280+255)/256,256,0,stream>>>(bihf_c, bhhf_c, biasgf);
  k_biassum2<<<(1280+255)/256,256,0,stream>>>(bihb_c, bhhb_c, biasgb);
  k_biascvt<<<3,256,0,stream>>>(bq_c, bqf, 600);
  k_biascvt<<<3,256,0,stream>>>(bk_c, bkf, 600);
  k_biascvt<<<3,256,0,stream>>>(g1b_c, gc1bf, 600);
  k_biascvt<<<3,256,0,stream>>>(g2b_c, gc2bf, 600);

  // --- input projections (embs @ Wih2^T + bias), gate-packed cols, MODE 1 ---
  gemm_k<1,1><<<dim3(128,10,1),256,0,stream>>>(16384,1280,336, embs,336,0, wihpf,336,0,
        nullptr, gip_f,1280,0, biasgf,0,nullptr,nullptr);
  gemm_k<1,1><<<dim3(128,10,1),256,0,stream>>>(16384,1280,336, embs,336,0, wihpb,336,0,
        nullptr, gip_b,1280,0, biasgb,0,nullptr,nullptr);

  // --- BiLSTM: reg-A + LDS-B, pipelined gi, parallel-arrival flag barrier ---
  hipMemsetAsync(hbuf, 0, 327680, stream);
  hipMemsetAsync(barr, 0, 4096, stream);
  lstm2_k<<<40,512,0,stream>>>(whh2f, whh2b, gip_f, gip_b, hbuf, barr, textout, text_len, dumpb);

  // --- q/k projections, head-scattered (dk padded 100->104) ---
  k_padzero<<<(98304*4*2+255)/256,256,0,stream>>>(qh, kh);
  gemm_k<1,2><<<dim3(128,5,1),256,0,stream>>>(16384,600,600, textout,600,0, wq_c,600,0,
        nullptr, qh,0,0, bqf,0,nullptr,nullptr);
  gemm_k<1,2><<<dim3(128,5,1),256,0,stream>>>(16384,600,600, textout,600,0, wk_c,600,0,
        nullptr, kh,0,0, bkf,0,nullptr,nullptr);

  // --- attention scores + mask ---
  gemm_k<1,3><<<dim3(1,1,768),256,0,stream>>>(128,128,104, qh,104,13312, kh,104,13312,
        scores, nullptr, 128, 16384, nullptr,0,nullptr, nonpad);

  // --- entmax15 (in place) ---
  k_entmax<<<98304,64,0,stream>>>(scores);

  // --- adjacency: head-mean + eye + valid; degree norms ---
  k_adjsem<<<(2097152+255)/256,256,0,stream>>>(scores, nonpad, adj_sem);
  k_dn<<<16384,64,0,stream>>>(adj_sem, dn1);
  k_dn<<<16384,64,0,stream>>>(adj_c, dn2);

  // --- SE #1 + GCN #1 (norm folded: Z = D (A (D * se * X))) ---
  k_mean<<<16384,64,0,stream>>>(textout, ymean);
  k_senet<<<128,128,0,stream>>>(ymean, sw1_c,sb1_c,sw2_c,sb2_c, nonpad, ysoft);
  k_scale2<<<(9830400+255)/256,256,0,stream>>>(textout, ysoft, dn1, se_x);
  gemm_k<0,1><<<dim3(1,5,128),256,0,stream>>>(128,600,128, adj_sem,128,16384, se_x,600,76800,
        nullptr, Zb,600,76800, nullptr,0, dn1, nullptr);
  gemm_k<0,1><<<dim3(128,5,1),256,0,stream>>>(16384,600,600, Zb,600,0, g1w_c,600,0,
        nullptr, x_sem,600,0, gc1bf,1,nullptr,nullptr);

  // --- SE #2 + GCN #2 (uses input adj) ---
  k_mean<<<16384,64,0,stream>>>(x_sem, ymean);
  k_senet<<<128,128,0,stream>>>(ymean, sw1_c,sb1_c,sw2_c,sb2_c, nonpad, ysoft);
  k_scale2<<<(9830400+255)/256,256,0,stream>>>(x_sem, ysoft, dn2, se_x);
  gemm_k<0,1><<<dim3(1,5,128),256,0,stream>>>(128,600,128, adj_c,128,16384, se_x,600,76800,
        nullptr, Zb,600,76800, nullptr,0, dn2, nullptr);
  gemm_k<0,1><<<dim3(128,5,1),256,0,stream>>>(16384,600,600, Zb,600,0, g2w_c,600,0,
        nullptr, xb,600,0, gc2bf,1,nullptr,nullptr);

  // --- biaffine pooling (only row left_len[b] of A1/A2 is ever used) ---
  k_gather<<<128,128,0,stream>>>(xb, left_len, xr);
  k_gather<<<128,128,0,stream>>>(x_sem, left_len, xsr);
  gemm_k<0,1><<<dim3(1,5,1),256,0,stream>>>(128,600,600, xr,600,0, af1_c,600,0,
        nullptr, g1,600,0, nullptr,0,nullptr,nullptr);
  gemm_k<0,1><<<dim3(1,5,1),256,0,stream>>>(128,600,600, xsr,600,0, af2_c,600,0,
        nullptr, g2,600,0, nullptr,0,nullptr,nullptr);
  k_pool<<<128,256,0,stream>>>(g1, x_sem, pooled, 0);
  k_pool<<<128,256,0,stream>>>(g2, xb, pooled, 600);

  // --- final FC (dtype-adaptive output) ---
  k_final<<<128,64,0,stream>>>(pooled, fcw_c, fcb_c, d_out, probe);
}